// Round 1
// 721.451 us; speedup vs baseline: 1.8755x; 1.8755x over previous
//
#include <hip/hip_runtime.h>
#include <hip/hip_bf16.h>

// GLA forward for MI355X. Inputs fp32, OUTPUT fp32. Pipeline:
//  1) gemm_mfma_k: q,k (QKT ws), v,g (bf16 ws) projections from fp32 x/W
//     -> NOW on matrix cores (v_mfma_f32_16x16x32_f16, fp32 accum; fp16
//        operand rounding ~2^-11, far below existing bf16 storage noise)
//  2) gate_k: gk = log_sigmoid((x@Wgk1)@Wgk2 + b)/16  (GKT ws)
//  3) chunk_state_k: per-(b,h,chunk=64) local state sum S and decay D
//  4) scan_k: affine scan over chunks -> chunk-start states H_n (in place)
//  5) chunk_out_k: o = q*e^B @ H  +  causal-decayed intra attention @ V,
//     fused per-head LayerNorm + silu(g) gate -> OL (bf16, aliases G buffer)
//  6) gemm_mfma_k: out = OL @ Wo (fp32 to d_out)

typedef __hip_bfloat16 bf16;
typedef _Float16 f16;
typedef _Float16 half8 __attribute__((ext_vector_type(8)));
typedef _Float16 half4 __attribute__((ext_vector_type(4)));
typedef float f32x4 __attribute__((ext_vector_type(4)));

#define DEV static __device__ __forceinline__

DEV float b2f(bf16 v) { return __bfloat162float(v); }
DEV bf16 f2b(float v) { return __float2bfloat16(v); }
DEV float bits2f(unsigned int u16) {
    union { unsigned int u; float f; } c; c.u = u16 << 16; return c.f;
}

DEV float ldf(const float* p) { return *p; }
DEV float ldf(const bf16* p) { return b2f(*p); }
DEV void stf(float* p, float v) { *p = v; }
DEV void stf(bf16* p, float v) { *p = f2b(v); }

// 4-element vector load, fp32 (16B) or bf16 (8B) source
DEV float4 ld4(const float* p) { return *(const float4*)p; }
DEV float4 ld4(const bf16* p) {
    const uint2 r = *(const uint2*)p;
    return make_float4(bits2f(r.x & 0xffffu), bits2f(r.x >> 16),
                       bits2f(r.y & 0xffffu), bits2f(r.y >> 16));
}

// ---------------------------------------------------------------------------
// MFMA GEMM: C[M,N] = scale * A[M,K] @ B[K,N]. A: float|bf16, B: float.
// fp32->fp16 conversion in LDS staging; fp32 accumulate in AGPRs.
// 256 threads = 4 waves (2x2), tile 128x128, BK=32. Each wave: 64x64 out
// = 4x4 fragments of 16x16 via v_mfma_f32_16x16x32_f16.
// LDS rows padded to 40 f16 (80B) -> fragment ds_read_b128 ~2-way (free).
// A/B fragments use the SAME per-lane k permutation (8 consecutive k per
// 16-lane group), so the contraction is correct independent of the HW's
// internal k ordering. C/D layout: col=lane&15, row=4*(lane>>4)+reg (HW-
// verified, dtype-independent).
// Requires M%128==0, N%128==0, K%32==0 (holds for all call sites).
// ---------------------------------------------------------------------------
template <typename AT, typename OutT>
__global__ __launch_bounds__(256) void gemm_mfma_k(
    const AT* __restrict__ A, const float* __restrict__ B,
    OutT* __restrict__ C, int M, int N, int K, float scale)
{
    __shared__ __align__(16) f16 As[128][40];   // [m][k], padded
    __shared__ __align__(16) f16 Bs[128][40];   // [n][k] (B transposed), padded
    const int bm = blockIdx.x * 128;
    const int bn = blockIdx.y * 128;
    const int tid = threadIdx.x;
    const int lane = tid & 63;
    const int wid = tid >> 6;
    const int wr = wid >> 1, wc = wid & 1;      // wave grid 2x2
    const int al = lane & 15;                   // fragment row/col
    const int kg = lane >> 4;                   // k-group 0..3

    f32x4 acc[4][4];
#pragma unroll
    for (int m = 0; m < 4; ++m)
#pragma unroll
        for (int n = 0; n < 4; ++n)
#pragma unroll
            for (int r = 0; r < 4; ++r) acc[m][n][r] = 0.f;

    // staging thread mapping
    const int ar = tid >> 1;             // A row 0..127 (2 threads/row)
    const int ac = (tid & 1) * 16;       // A k base (16 elems each)
    const int bkg = tid >> 5;            // B k-group 0..7 (4 k-rows each)
    const int bcg = tid & 31;            // B col-group 0..31 (4 cols each)

    for (int k0 = 0; k0 < K; k0 += 32) {
        {   // stage A: 128x32, fp32/bf16 -> fp16
            const AT* ap = A + (size_t)(bm + ar) * K + k0 + ac;
            const float4 a0 = ld4(ap), a1 = ld4(ap + 4);
            const float4 a2 = ld4(ap + 8), a3 = ld4(ap + 12);
            half8 h0, h1;
            h0[0] = (f16)a0.x; h0[1] = (f16)a0.y; h0[2] = (f16)a0.z; h0[3] = (f16)a0.w;
            h0[4] = (f16)a1.x; h0[5] = (f16)a1.y; h0[6] = (f16)a1.z; h0[7] = (f16)a1.w;
            h1[0] = (f16)a2.x; h1[1] = (f16)a2.y; h1[2] = (f16)a2.z; h1[3] = (f16)a2.w;
            h1[4] = (f16)a3.x; h1[5] = (f16)a3.y; h1[6] = (f16)a3.z; h1[7] = (f16)a3.w;
            *(half8*)&As[ar][ac] = h0;
            *(half8*)&As[ar][ac + 8] = h1;
        }
        {   // stage B: 32x128, 4x4 micro-transpose -> Bs[n][k]
            const float* bp = B + (size_t)(k0 + bkg * 4) * N + bn + bcg * 4;
            const float4 r0 = ld4(bp);
            const float4 r1 = ld4(bp + N);
            const float4 r2 = ld4(bp + 2 * N);
            const float4 r3 = ld4(bp + 3 * N);
            half4 c0, c1, c2, c3;
            c0[0] = (f16)r0.x; c0[1] = (f16)r1.x; c0[2] = (f16)r2.x; c0[3] = (f16)r3.x;
            c1[0] = (f16)r0.y; c1[1] = (f16)r1.y; c1[2] = (f16)r2.y; c1[3] = (f16)r3.y;
            c2[0] = (f16)r0.z; c2[1] = (f16)r1.z; c2[2] = (f16)r2.z; c2[3] = (f16)r3.z;
            c3[0] = (f16)r0.w; c3[1] = (f16)r1.w; c3[2] = (f16)r2.w; c3[3] = (f16)r3.w;
            *(half4*)&Bs[bcg * 4 + 0][bkg * 4] = c0;
            *(half4*)&Bs[bcg * 4 + 1][bkg * 4] = c1;
            *(half4*)&Bs[bcg * 4 + 2][bkg * 4] = c2;
            *(half4*)&Bs[bcg * 4 + 3][bkg * 4] = c3;
        }
        __syncthreads();
        half8 af[4], bf[4];
#pragma unroll
        for (int m = 0; m < 4; ++m)
            af[m] = *(const half8*)&As[wr * 64 + m * 16 + al][kg * 8];
#pragma unroll
        for (int n = 0; n < 4; ++n)
            bf[n] = *(const half8*)&Bs[wc * 64 + n * 16 + al][kg * 8];
#pragma unroll
        for (int m = 0; m < 4; ++m)
#pragma unroll
            for (int n = 0; n < 4; ++n)
                acc[m][n] = __builtin_amdgcn_mfma_f32_16x16x32_f16(
                    af[m], bf[n], acc[m][n], 0, 0, 0);
        __syncthreads();
    }
    const int r0 = bm + wr * 64 + kg * 4;
    const int c0 = bn + wc * 64 + al;
#pragma unroll
    for (int m = 0; m < 4; ++m)
#pragma unroll
        for (int n = 0; n < 4; ++n)
#pragma unroll
            for (int r = 0; r < 4; ++r)
                stf(&C[(size_t)(r0 + m * 16 + r) * N + c0 + n * 16],
                    acc[m][n][r] * scale);
}

// ---------------------------------------------------------------------------
// gk = log_sigmoid((x @ Wgk1) @ Wgk2 + bgk2) / 16 ; one block per row
// ---------------------------------------------------------------------------
template <typename GKT>
__global__ __launch_bounds__(256) void gate_k(
    const float* __restrict__ x, const float* __restrict__ Wgk1,
    const float* __restrict__ Wgk2, const float* __restrict__ bgk2,
    GKT* __restrict__ GK)
{
    __shared__ float xs[512];
    __shared__ float part[16][17];
    __shared__ float tl[16];
    const int row = blockIdx.x;
    const int tid = threadIdx.x;
    const float* xp = x + (size_t)row * 512;
    xs[tid] = xp[tid];
    xs[tid + 256] = xp[tid + 256];
    __syncthreads();
    const int j = tid & 15, seg = tid >> 4;
    float p = 0.f;
#pragma unroll
    for (int i = 0; i < 32; ++i) {
        const int c = seg * 32 + i;
        p = fmaf(xs[c], Wgk1[c * 16 + j], p);
    }
    part[seg][j] = p;
    __syncthreads();
    if (tid < 16) {
        float s = 0.f;
#pragma unroll
        for (int sg = 0; sg < 16; ++sg) s += part[sg][tid];
        tl[tid] = s;
    }
    __syncthreads();
    float z = bgk2[tid];
#pragma unroll
    for (int r = 0; r < 16; ++r)
        z = fmaf(tl[r], Wgk2[r * 256 + tid], z);
    const float ls = fminf(z, 0.f) - log1pf(expf(-fabsf(z)));
    stf(&GK[(size_t)row * 256 + tid], ls * (1.f / 16.f));
}

// ---------------------------------------------------------------------------
// Per-chunk local state: S[k][v] = sum_t e^{B63[k]-Bt[k]} k_t[k] v_t[v],
// D[k] = e^{B63[k]}. Stored transposed: CS[blk][v*64+k]. blk = bh*256+chunk.
// ---------------------------------------------------------------------------
template <typename QKT, typename GKT, typename CST>
__global__ __launch_bounds__(256) void chunk_state_k(
    const QKT* __restrict__ Km, const bf16* __restrict__ Vm,
    const GKT* __restrict__ GKm, CST* __restrict__ CS,
    float* __restrict__ DD)
{
    __shared__ float gs[64][64];   // gk cumsum, then overwritten with k2
    __shared__ float d63[64];
    __shared__ __align__(16) float vs[64][128];
    const int blk = blockIdx.x;
    const int chunk = blk & 255;
    const int bh = blk >> 8;
    const int bi = bh >> 2, h = bh & 3;
    const int rowbase = bi * 16384 + chunk * 64;
    const int tid = threadIdx.x;

    for (int e = tid; e < 4096; e += 256) {
        const int t = e >> 6, k = e & 63;
        gs[t][k] = ldf(&GKm[(size_t)(rowbase + t) * 256 + h * 64 + k]);
    }
    __syncthreads();
    if (tid < 64) {
        float run = 0.f;
        for (int t = 0; t < 64; ++t) { run += gs[t][tid]; gs[t][tid] = run; }
        d63[tid] = run;
    }
    __syncthreads();
    for (int e = tid; e < 4096; e += 256) {
        const int t = e >> 6, k = e & 63;
        const float kv = ldf(&Km[(size_t)(rowbase + t) * 256 + h * 64 + k]);
        gs[t][k] = kv * expf(d63[k] - gs[t][k]);   // in-place: k2
    }
    for (int e = tid; e < 8192; e += 256) {
        const int t = e >> 7, v = e & 127;
        vs[t][v] = ldf(&Vm[(size_t)(rowbase + t) * 512 + h * 128 + v]);
    }
    if (tid < 64) DD[(size_t)blk * 64 + tid] = expf(d63[tid]);
    __syncthreads();

    const int kq = tid & 63, vq = tid >> 6;
    float acc[32];
#pragma unroll
    for (int j = 0; j < 32; ++j) acc[j] = 0.f;
    for (int t = 0; t < 64; ++t) {
        const float kc = gs[t][kq];
        const float4* vrow = (const float4*)(&vs[t][vq * 32]);
#pragma unroll
        for (int jj = 0; jj < 8; ++jj) {
            const float4 vv = vrow[jj];
            acc[jj * 4 + 0] = fmaf(kc, vv.x, acc[jj * 4 + 0]);
            acc[jj * 4 + 1] = fmaf(kc, vv.y, acc[jj * 4 + 1]);
            acc[jj * 4 + 2] = fmaf(kc, vv.z, acc[jj * 4 + 2]);
            acc[jj * 4 + 3] = fmaf(kc, vv.w, acc[jj * 4 + 3]);
        }
    }
    CST* out = CS + (size_t)blk * 8192;
#pragma unroll
    for (int j = 0; j < 32; ++j)
        stf(&out[(vq * 32 + j) * 64 + kq], acc[j]);
}

// ---------------------------------------------------------------------------
// Affine scan over chunks: slot n <- H_n (pre-chunk state), H_{n+1}=D_n H_n+S_n
// grid = 8 bh * 32 elem-slices; fully parallel across state elements.
// ---------------------------------------------------------------------------
template <typename CST>
__global__ __launch_bounds__(256) void scan_k(
    CST* __restrict__ CS, const float* __restrict__ DD)
{
    const int bh = blockIdx.x >> 5;
    const int slice = blockIdx.x & 31;
    const int tid = threadIdx.x;
    const int e = slice * 256 + tid;
    const int k = e & 63;
    float H = 0.f;
    CST* base = CS + (size_t)bh * 256 * 8192 + e;
    const float* dbase = DD + (size_t)bh * 256 * 64 + k;
#pragma unroll 4
    for (int n = 0; n < 256; ++n) {
        const float s = ldf(&base[(size_t)n * 8192]);
        const float d = dbase[(size_t)n * 64];
        const float nH = fmaf(d, H, s);
        stf(&base[(size_t)n * 8192], H);
        H = nH;
    }
}

// ---------------------------------------------------------------------------
// Per-chunk output + fused LayerNorm + silu gate.
//   A[t][i] = sum_k (q_t e^{Bt})[k] (k_i e^{-Bi})[k], i<=t
//   o_t = A @ V + (q_t e^{Bt}) @ H_n ; GO = LN(o)*silu(GO)  (bf16, in place)
// ---------------------------------------------------------------------------
template <typename QKT, typename GKT, typename CST>
__global__ __launch_bounds__(256) void chunk_out_k(
    const QKT* __restrict__ Qm, const QKT* __restrict__ Km,
    const bf16* __restrict__ Vm, const GKT* __restrict__ GKm,
    const CST* __restrict__ CS, bf16* GO)   // GO: read gate, write OL (same buf)
{
    __shared__ __align__(16) float smem[3 * 64 * 65 + 512];
    float (*gs)[65] = (float (*)[65])(smem);             // cumsum -> A
    float (*qs)[65] = (float (*)[65])(smem + 64 * 65);
    float (*ks)[65] = (float (*)[65])(smem + 2 * 64 * 65);
    float (*vs)[128] = (float (*)[128])(smem + 64 * 65); // overlays qs+ks
    float* redS = smem + 3 * 64 * 65;
    float* redQ = redS + 256;

    const int blk = blockIdx.x;
    const int chunk = blk & 255;
    const int bh = blk >> 8;
    const int bi = bh >> 2, h = bh & 3;
    const int rowbase = bi * 16384 + chunk * 64;
    const int tid = threadIdx.x;

    for (int e = tid; e < 4096; e += 256) {
        const int t = e >> 6, k = e & 63;
        gs[t][k] = ldf(&GKm[(size_t)(rowbase + t) * 256 + h * 64 + k]);
    }
    __syncthreads();
    if (tid < 64) {
        float run = 0.f;
        for (int t = 0; t < 64; ++t) { run += gs[t][tid]; gs[t][tid] = run; }
    }
    __syncthreads();
    for (int e = tid; e < 4096; e += 256) {
        const int t = e >> 6, k = e & 63;
        const float g = gs[t][k];
        const size_t idx = (size_t)(rowbase + t) * 256 + h * 64 + k;
        qs[t][k] = ldf(&Qm[idx]) * expf(g);
        ks[t][k] = ldf(&Km[idx]) * expf(-g);
    }
    __syncthreads();
    // A = (causal) qs @ ks^T, written into gs region
    {
        const int tq = tid >> 2, iq = tid & 3;
        float a[16];
#pragma unroll
        for (int j = 0; j < 16; ++j) a[j] = 0.f;
        for (int k = 0; k < 64; ++k) {
            const float qv = qs[tq][k];
#pragma unroll
            for (int j = 0; j < 16; ++j)
                a[j] = fmaf(qv, ks[iq * 16 + j][k], a[j]);
        }
#pragma unroll
        for (int j = 0; j < 16; ++j) {
            const int i = iq * 16 + j;
            gs[tq][i] = (i <= tq) ? a[j] : 0.f;
        }
    }
    // inter-chunk: acc += qs[t][:] . H[v][:]  (H rows contiguous)
    const int t = tid & 63, vq = tid >> 6;
    float acc[32];
#pragma unroll
    for (int j = 0; j < 32; ++j) acc[j] = 0.f;
    const CST* Hb = CS + (size_t)blk * 8192;
    for (int kb = 0; kb < 64; kb += 16) {
        float qreg[16];
#pragma unroll
        for (int kk = 0; kk < 16; ++kk) qreg[kk] = qs[t][kb + kk];
#pragma unroll
        for (int j = 0; j < 32; ++j) {
            const CST* hrow = Hb + (size_t)(vq * 32 + j) * 64 + kb;
            const float4 h0 = ld4(hrow + 0), h1 = ld4(hrow + 4);
            const float4 h2 = ld4(hrow + 8), h3 = ld4(hrow + 12);
            float s = acc[j];
            s = fmaf(qreg[0], h0.x, s);  s = fmaf(qreg[1], h0.y, s);
            s = fmaf(qreg[2], h0.z, s);  s = fmaf(qreg[3], h0.w, s);
            s = fmaf(qreg[4], h1.x, s);  s = fmaf(qreg[5], h1.y, s);
            s = fmaf(qreg[6], h1.z, s);  s = fmaf(qreg[7], h1.w, s);
            s = fmaf(qreg[8], h2.x, s);  s = fmaf(qreg[9], h2.y, s);
            s = fmaf(qreg[10], h2.z, s); s = fmaf(qreg[11], h2.w, s);
            s = fmaf(qreg[12], h3.x, s); s = fmaf(qreg[13], h3.y, s);
            s = fmaf(qreg[14], h3.z, s); s = fmaf(qreg[15], h3.w, s);
            acc[j] = s;
        }
    }
    __syncthreads();   // all done with qs/ks before overlaying with V
    for (int e = tid; e < 8192; e += 256) {
        const int tt = e >> 7, v = e & 127;
        vs[tt][v] = ldf(&Vm[(size_t)(rowbase + tt) * 512 + h * 128 + v]);
    }
    __syncthreads();
    // intra-chunk: acc += A[t][i] * V[i][v]
    for (int i = 0; i < 64; ++i) {
        const float av = gs[t][i];
        const float4* vrow = (const float4*)(&vs[i][vq * 32]);
#pragma unroll
        for (int jj = 0; jj < 8; ++jj) {
            const float4 vv = vrow[jj];
            acc[jj * 4 + 0] = fmaf(av, vv.x, acc[jj * 4 + 0]);
            acc[jj * 4 + 1] = fmaf(av, vv.y, acc[jj * 4 + 1]);
            acc[jj * 4 + 2] = fmaf(av, vv.z, acc[jj * 4 + 2]);
            acc[jj * 4 + 3] = fmaf(av, vv.w, acc[jj * 4 + 3]);
        }
    }
    // fused LayerNorm (over 128, split across 4 waves) + silu(g) gate
    float psum = 0.f, psq = 0.f;
#pragma unroll
    for (int j = 0; j < 32; ++j) { psum += acc[j]; psq = fmaf(acc[j], acc[j], psq); }
    redS[t * 4 + vq] = psum;
    redQ[t * 4 + vq] = psq;
    __syncthreads();
    const float s4 = redS[t * 4 + 0] + redS[t * 4 + 1] + redS[t * 4 + 2] + redS[t * 4 + 3];
    const float q4 = redQ[t * 4 + 0] + redQ[t * 4 + 1] + redQ[t * 4 + 2] + redQ[t * 4 + 3];
    const float mu = s4 * (1.f / 128.f);
    const float var = q4 * (1.f / 128.f) - mu * mu;
    const float rstd = rsqrtf(fmaxf(var, 0.f) + 1e-5f);
    const int row = rowbase + t;
    bf16* gop = GO + (size_t)row * 512 + h * 128 + vq * 32;
#pragma unroll
    for (int j = 0; j < 32; ++j) {
        const float gv = b2f(gop[j]);             // read gate
        const float sil = gv / (1.f + expf(-gv));
        gop[j] = f2b((acc[j] - mu) * rstd * sil); // overwrite with OL
    }
}

__global__ __launch_bounds__(256) void zero_k(float* out, int n) {
    const int i = blockIdx.x * 256 + threadIdx.x;
    if (i < n) out[i] = 0.f;
}

// ---------------------------------------------------------------------------
template <typename QKT, typename GKT, typename CST>
static void run_all(const float* x, const float* Wq, const float* Wk,
                    const float* Wv, const float* Wg, const float* Wgk1,
                    const float* Wgk2, const float* bgk2, const float* Wo,
                    float* out, char* ws, hipStream_t stream)
{
    const int M = 32768;  // B*S
    auto aln = [](size_t v) { return (v + 255) & ~(size_t)255; };
    char* cur = ws;
    QKT* Qb = (QKT*)cur;  cur += aln((size_t)M * 256 * sizeof(QKT));
    QKT* Kb = (QKT*)cur;  cur += aln((size_t)M * 256 * sizeof(QKT));
    bf16* Vb = (bf16*)cur;  cur += aln((size_t)M * 512 * 2);
    bf16* GOb = (bf16*)cur; cur += aln((size_t)M * 512 * 2);   // gate, then OL
    float* DDb = (float*)cur; cur += aln((size_t)2048 * 64 * 4);
    GKT* GKb = (GKT*)cur;   cur += aln((size_t)M * 256 * sizeof(GKT));
    CST* CSb = (CST*)cur;

    const dim3 blk(256);
    gemm_mfma_k<<<dim3(M / 128, 2), blk, 0, stream>>>(x, Wq, Qb, M, 256, 512, 0.125f);
    gemm_mfma_k<<<dim3(M / 128, 2), blk, 0, stream>>>(x, Wk, Kb, M, 256, 512, 1.f);
    gemm_mfma_k<<<dim3(M / 128, 4), blk, 0, stream>>>(x, Wv, Vb, M, 512, 512, 1.f);
    gemm_mfma_k<<<dim3(M / 128, 4), blk, 0, stream>>>(x, Wg, GOb, M, 512, 512, 1.f);
    gate_k<<<dim3(M), blk, 0, stream>>>(x, Wgk1, Wgk2, bgk2, GKb);
    chunk_state_k<<<dim3(2048), blk, 0, stream>>>(Kb, Vb, GKb, CSb, DDb);
    scan_k<<<dim3(256), blk, 0, stream>>>(CSb, DDb);
    chunk_out_k<<<dim3(2048), blk, 0, stream>>>(Qb, Kb, Vb, GKb, CSb, GOb);
    gemm_mfma_k<<<dim3(M / 128, 4), blk, 0, stream>>>(GOb, Wo, out, M, 512, 512, 1.f);
}

extern "C" void kernel_launch(void* const* d_in, const int* in_sizes, int n_in,
                              void* d_out, int out_size, void* d_ws, size_t ws_size,
                              hipStream_t stream)
{
    const float* x    = (const float*)d_in[0];
    const float* Wq   = (const float*)d_in[1];
    const float* Wk   = (const float*)d_in[2];
    const float* Wv   = (const float*)d_in[3];
    const float* Wg   = (const float*)d_in[4];
    const float* Wgk1 = (const float*)d_in[5];
    const float* Wgk2 = (const float*)d_in[6];
    const float* bgk2 = (const float*)d_in[7];
    const float* Wo   = (const float*)d_in[8];
    float* out = (float*)d_out;

    const size_t M = 32768;
    const size_t slack = 4096;
    // shared pieces: V (bf16) + GO (bf16) + DD
    const size_t base = M * 512 * 2 * 2 + 2048 * 64 * 4 + slack;
    const size_t qk_f = 2 * M * 256 * 4, qk_b = 2 * M * 256 * 2;
    const size_t gk_f = M * 256 * 4,     gk_b = M * 256 * 2;
    const size_t cs_f = (size_t)2048 * 8192 * 4, cs_b = (size_t)2048 * 8192 * 2;
    const size_t needA = base + qk_f + gk_f + cs_f;  // ~236 MB
    const size_t needB = base + qk_b + gk_f + cs_f;  // ~202 MB
    const size_t needC = base + qk_b + gk_b + cs_b;  // ~152 MB

    if (ws_size >= needA) {
        run_all<float, float, float>(x, Wq, Wk, Wv, Wg, Wgk1, Wgk2, bgk2, Wo,
                                     out, (char*)d_ws, stream);
    } else if (ws_size >= needB) {
        run_all<bf16, float, float>(x, Wq, Wk, Wv, Wg, Wgk1, Wgk2, bgk2, Wo,
                                    out, (char*)d_ws, stream);
    } else if (ws_size >= needC) {
        run_all<bf16, bf16, bf16>(x, Wq, Wk, Wv, Wg, Wgk1, Wgk2, bgk2, Wo,
                                  out, (char*)d_ws, stream);
    } else {
        // diagnostic: ws too small even for tier C -> deterministic zero output
        zero_k<<<dim3((out_size + 255) / 256), dim3(256), 0, stream>>>(out, out_size);
    }
}

// Round 2
// 579.451 us; speedup vs baseline: 2.3351x; 1.2451x over previous
//
#include <hip/hip_runtime.h>
#include <hip/hip_bf16.h>

// GLA forward for MI355X. Inputs fp32, OUTPUT fp32. Pipeline:
//  1) gemm_mfma_k: q,k (QKT ws), g (bf16 ws) projections (f16 MFMA)
//     gemm_vt_k:   v projection, stored CHUNK-TRANSPOSED Vt[bi][h][chunk][v][t]
//  2) gate_k: gk = log_sigmoid((x@Wgk1)@Wgk2 + b)/16  (GKT ws)
//  3) chunk_state_k: per-(b,h,chunk=64) local state S^T[v][k] + decay D (bf16 MFMA)
//  4) scan_k: affine scan over chunks -> chunk-start states H_n (in place)
//  5) chunk_out_k: o = q*e^B @ H + causal-decayed intra attention @ V (bf16 MFMA),
//     fused per-head LayerNorm + silu(g) gate -> OL (bf16, aliases G buffer)
//  6) gemm_mfma_k: out = OL @ Wo (fp32 to d_out)
// bf16 (not f16) for chunk matmuls: k*e^{-g} can reach ~e^20, beyond fp16 range.

typedef __hip_bfloat16 bf16;
typedef _Float16 f16;
typedef _Float16 half8 __attribute__((ext_vector_type(8)));
typedef _Float16 half4 __attribute__((ext_vector_type(4)));
typedef float f32x4 __attribute__((ext_vector_type(4)));
typedef short short8 __attribute__((ext_vector_type(8)));

#define DEV static __device__ __forceinline__

DEV float b2f(bf16 v) { return __bfloat162float(v); }
DEV bf16 f2b(float v) { return __float2bfloat16(v); }
DEV float bits2f(unsigned int u16) {
    union { unsigned int u; float f; } c; c.u = u16 << 16; return c.f;
}
// RNE fp32->bf16 bit conversion (finite inputs), avoids type-punning on bf16
DEV unsigned short f2bu(float v) {
    union { float f; unsigned u; } c; c.f = v;
    const unsigned r = c.u + 0x7fffu + ((c.u >> 16) & 1u);
    return (unsigned short)(r >> 16);
}
DEV short f2bs(float v) { return (short)f2bu(v); }

DEV float ldf(const float* p) { return *p; }
DEV float ldf(const bf16* p) { return b2f(*p); }
DEV void stf(float* p, float v) { *p = v; }
DEV void stf(bf16* p, float v) { *p = f2b(v); }

DEV float4 ld4(const float* p) { return *(const float4*)p; }
DEV float4 ld4(const bf16* p) {
    const uint2 r = *(const uint2*)p;
    return make_float4(bits2f(r.x & 0xffffu), bits2f(r.x >> 16),
                       bits2f(r.y & 0xffffu), bits2f(r.y >> 16));
}

// load 8 elems as bf16 fragment (fp32 src: convert; bf16 src: direct 16B)
DEV short8 ld8bf(const float* p) {
    const float4 a = *(const float4*)p, b = *(const float4*)(p + 4);
    short8 r;
    r[0] = f2bs(a.x); r[1] = f2bs(a.y); r[2] = f2bs(a.z); r[3] = f2bs(a.w);
    r[4] = f2bs(b.x); r[5] = f2bs(b.y); r[6] = f2bs(b.z); r[7] = f2bs(b.w);
    return r;
}
DEV short8 ld8bf(const bf16* p) { return *(const short8*)p; }

DEV f32x4 mfma_bf(short8 a, short8 b, f32x4 c) {
    return __builtin_amdgcn_mfma_f32_16x16x32_bf16(a, b, c, 0, 0, 0);
}

// ---------------------------------------------------------------------------
// MFMA GEMM (f16 operands): C[M,N] = scale * A[M,K] @ B[K,N]. A: float|bf16.
// 256 thr = 4 waves (2x2), tile 128x128, BK=32, 4x4 16x16 frags per wave.
// Fragment convention (HW-verified round 1): A[row][k] and B[col][k] with
// per-lane k = kg*8..+7 (same permutation both sides -> contraction exact);
// D: col=lane&15, row=4*(lane>>4)+reg.
// ---------------------------------------------------------------------------
template <typename AT, typename OutT>
__global__ __launch_bounds__(256) void gemm_mfma_k(
    const AT* __restrict__ A, const float* __restrict__ B,
    OutT* __restrict__ C, int M, int N, int K, float scale)
{
    __shared__ __align__(16) f16 As[128][40];
    __shared__ __align__(16) f16 Bs[128][40];
    const int bm = blockIdx.x * 128;
    const int bn = blockIdx.y * 128;
    const int tid = threadIdx.x;
    const int lane = tid & 63;
    const int wid = tid >> 6;
    const int wr = wid >> 1, wc = wid & 1;
    const int al = lane & 15;
    const int kg = lane >> 4;

    f32x4 acc[4][4];
#pragma unroll
    for (int m = 0; m < 4; ++m)
#pragma unroll
        for (int n = 0; n < 4; ++n)
#pragma unroll
            for (int r = 0; r < 4; ++r) acc[m][n][r] = 0.f;

    const int ar = tid >> 1;
    const int ac = (tid & 1) * 16;
    const int bkg = tid >> 5;
    const int bcg = tid & 31;

    for (int k0 = 0; k0 < K; k0 += 32) {
        {
            const AT* ap = A + (size_t)(bm + ar) * K + k0 + ac;
            const float4 a0 = ld4(ap), a1 = ld4(ap + 4);
            const float4 a2 = ld4(ap + 8), a3 = ld4(ap + 12);
            half8 h0, h1;
            h0[0] = (f16)a0.x; h0[1] = (f16)a0.y; h0[2] = (f16)a0.z; h0[3] = (f16)a0.w;
            h0[4] = (f16)a1.x; h0[5] = (f16)a1.y; h0[6] = (f16)a1.z; h0[7] = (f16)a1.w;
            h1[0] = (f16)a2.x; h1[1] = (f16)a2.y; h1[2] = (f16)a2.z; h1[3] = (f16)a2.w;
            h1[4] = (f16)a3.x; h1[5] = (f16)a3.y; h1[6] = (f16)a3.z; h1[7] = (f16)a3.w;
            *(half8*)&As[ar][ac] = h0;
            *(half8*)&As[ar][ac + 8] = h1;
        }
        {
            const float* bp = B + (size_t)(k0 + bkg * 4) * N + bn + bcg * 4;
            const float4 r0 = ld4(bp);
            const float4 r1 = ld4(bp + N);
            const float4 r2 = ld4(bp + 2 * N);
            const float4 r3 = ld4(bp + 3 * N);
            half4 c0, c1, c2, c3;
            c0[0] = (f16)r0.x; c0[1] = (f16)r1.x; c0[2] = (f16)r2.x; c0[3] = (f16)r3.x;
            c1[0] = (f16)r0.y; c1[1] = (f16)r1.y; c1[2] = (f16)r2.y; c1[3] = (f16)r3.y;
            c2[0] = (f16)r0.z; c2[1] = (f16)r1.z; c2[2] = (f16)r2.z; c2[3] = (f16)r3.z;
            c3[0] = (f16)r0.w; c3[1] = (f16)r1.w; c3[2] = (f16)r2.w; c3[3] = (f16)r3.w;
            *(half4*)&Bs[bcg * 4 + 0][bkg * 4] = c0;
            *(half4*)&Bs[bcg * 4 + 1][bkg * 4] = c1;
            *(half4*)&Bs[bcg * 4 + 2][bkg * 4] = c2;
            *(half4*)&Bs[bcg * 4 + 3][bkg * 4] = c3;
        }
        __syncthreads();
        half8 af[4], bfr[4];
#pragma unroll
        for (int m = 0; m < 4; ++m)
            af[m] = *(const half8*)&As[wr * 64 + m * 16 + al][kg * 8];
#pragma unroll
        for (int n = 0; n < 4; ++n)
            bfr[n] = *(const half8*)&Bs[wc * 64 + n * 16 + al][kg * 8];
#pragma unroll
        for (int m = 0; m < 4; ++m)
#pragma unroll
            for (int n = 0; n < 4; ++n)
                acc[m][n] = __builtin_amdgcn_mfma_f32_16x16x32_f16(
                    af[m], bfr[n], acc[m][n], 0, 0, 0);
        __syncthreads();
    }
    const int r0 = bm + wr * 64 + kg * 4;
    const int c0 = bn + wc * 64 + al;
#pragma unroll
    for (int m = 0; m < 4; ++m)
#pragma unroll
        for (int n = 0; n < 4; ++n)
#pragma unroll
            for (int r = 0; r < 4; ++r)
                stf(&C[(size_t)(r0 + m * 16 + r) * N + c0 + n * 16],
                    acc[m][n][r] * scale);
}

// ---------------------------------------------------------------------------
// V projection with chunk-transposed store: Vt[((bi*4+h)*256+chunk)*128+v][t]
// bf16. D-fragment rows (4 consecutive t at fixed v) -> one contiguous 8B
// store per fragment per lane. N==512, M==32768 layout assumed.
// ---------------------------------------------------------------------------
__global__ __launch_bounds__(256) void gemm_vt_k(
    const float* __restrict__ A, const float* __restrict__ B,
    bf16* __restrict__ VT, int M, int N, int K)
{
    __shared__ __align__(16) f16 As[128][40];
    __shared__ __align__(16) f16 Bs[128][40];
    const int bm = blockIdx.x * 128;
    const int bn = blockIdx.y * 128;
    const int tid = threadIdx.x;
    const int lane = tid & 63;
    const int wid = tid >> 6;
    const int wr = wid >> 1, wc = wid & 1;
    const int al = lane & 15;
    const int kg = lane >> 4;

    f32x4 acc[4][4];
#pragma unroll
    for (int m = 0; m < 4; ++m)
#pragma unroll
        for (int n = 0; n < 4; ++n)
#pragma unroll
            for (int r = 0; r < 4; ++r) acc[m][n][r] = 0.f;

    const int ar = tid >> 1;
    const int ac = (tid & 1) * 16;
    const int bkg = tid >> 5;
    const int bcg = tid & 31;

    for (int k0 = 0; k0 < K; k0 += 32) {
        {
            const float* ap = A + (size_t)(bm + ar) * K + k0 + ac;
            const float4 a0 = ld4(ap), a1 = ld4(ap + 4);
            const float4 a2 = ld4(ap + 8), a3 = ld4(ap + 12);
            half8 h0, h1;
            h0[0] = (f16)a0.x; h0[1] = (f16)a0.y; h0[2] = (f16)a0.z; h0[3] = (f16)a0.w;
            h0[4] = (f16)a1.x; h0[5] = (f16)a1.y; h0[6] = (f16)a1.z; h0[7] = (f16)a1.w;
            h1[0] = (f16)a2.x; h1[1] = (f16)a2.y; h1[2] = (f16)a2.z; h1[3] = (f16)a2.w;
            h1[4] = (f16)a3.x; h1[5] = (f16)a3.y; h1[6] = (f16)a3.z; h1[7] = (f16)a3.w;
            *(half8*)&As[ar][ac] = h0;
            *(half8*)&As[ar][ac + 8] = h1;
        }
        {
            const float* bp = B + (size_t)(k0 + bkg * 4) * N + bn + bcg * 4;
            const float4 r0 = ld4(bp);
            const float4 r1 = ld4(bp + N);
            const float4 r2 = ld4(bp + 2 * N);
            const float4 r3 = ld4(bp + 3 * N);
            half4 c0, c1, c2, c3;
            c0[0] = (f16)r0.x; c0[1] = (f16)r1.x; c0[2] = (f16)r2.x; c0[3] = (f16)r3.x;
            c1[0] = (f16)r0.y; c1[1] = (f16)r1.y; c1[2] = (f16)r2.y; c1[3] = (f16)r3.y;
            c2[0] = (f16)r0.z; c2[1] = (f16)r1.z; c2[2] = (f16)r2.z; c2[3] = (f16)r3.z;
            c3[0] = (f16)r0.w; c3[1] = (f16)r1.w; c3[2] = (f16)r2.w; c3[3] = (f16)r3.w;
            *(half4*)&Bs[bcg * 4 + 0][bkg * 4] = c0;
            *(half4*)&Bs[bcg * 4 + 1][bkg * 4] = c1;
            *(half4*)&Bs[bcg * 4 + 2][bkg * 4] = c2;
            *(half4*)&Bs[bcg * 4 + 3][bkg * 4] = c3;
        }
        __syncthreads();
        half8 af[4], bfr[4];
#pragma unroll
        for (int m = 0; m < 4; ++m)
            af[m] = *(const half8*)&As[wr * 64 + m * 16 + al][kg * 8];
#pragma unroll
        for (int n = 0; n < 4; ++n)
            bfr[n] = *(const half8*)&Bs[wc * 64 + n * 16 + al][kg * 8];
#pragma unroll
        for (int m = 0; m < 4; ++m)
#pragma unroll
            for (int n = 0; n < 4; ++n)
                acc[m][n] = __builtin_amdgcn_mfma_f32_16x16x32_f16(
                    af[m], bfr[n], acc[m][n], 0, 0, 0);
        __syncthreads();
    }
    const int r00 = bm + wr * 64 + kg * 4;
    const int c00 = bn + wc * 64 + al;
#pragma unroll
    for (int m = 0; m < 4; ++m) {
        const int row0 = r00 + m * 16;                 // 4 consecutive t rows
        const int bi = row0 >> 14;
        const int chunk = (row0 >> 6) & 255;
        const int tc = row0 & 63;
#pragma unroll
        for (int n = 0; n < 4; ++n) {
            const int col = c00 + n * 16;
            const int h = col >> 7, v = col & 127;
            bf16* dst = VT + ((size_t)((bi * 4 + h) * 256 + chunk) * 128 + v) * 64 + tc;
            ushort4 pk;
            pk.x = f2bu(acc[m][n][0]); pk.y = f2bu(acc[m][n][1]);
            pk.z = f2bu(acc[m][n][2]); pk.w = f2bu(acc[m][n][3]);
            *(ushort4*)dst = pk;
        }
    }
}

// ---------------------------------------------------------------------------
// gk = log_sigmoid((x @ Wgk1) @ Wgk2 + bgk2) / 16 ; one block per row
// ---------------------------------------------------------------------------
template <typename GKT>
__global__ __launch_bounds__(256) void gate_k(
    const float* __restrict__ x, const float* __restrict__ Wgk1,
    const float* __restrict__ Wgk2, const float* __restrict__ bgk2,
    GKT* __restrict__ GK)
{
    __shared__ float xs[512];
    __shared__ float part[16][17];
    __shared__ float tl[16];
    const int row = blockIdx.x;
    const int tid = threadIdx.x;
    const float* xp = x + (size_t)row * 512;
    xs[tid] = xp[tid];
    xs[tid + 256] = xp[tid + 256];
    __syncthreads();
    const int j = tid & 15, seg = tid >> 4;
    float p = 0.f;
#pragma unroll
    for (int i = 0; i < 32; ++i) {
        const int c = seg * 32 + i;
        p = fmaf(xs[c], Wgk1[c * 16 + j], p);
    }
    part[seg][j] = p;
    __syncthreads();
    if (tid < 16) {
        float s = 0.f;
#pragma unroll
        for (int sg = 0; sg < 16; ++sg) s += part[sg][tid];
        tl[tid] = s;
    }
    __syncthreads();
    float z = bgk2[tid];
#pragma unroll
    for (int r = 0; r < 16; ++r)
        z = fmaf(tl[r], Wgk2[r * 256 + tid], z);
    const float ls = fminf(z, 0.f) - log1pf(expf(-fabsf(z)));
    stf(&GK[(size_t)row * 256 + tid], ls * (1.f / 16.f));
}

// ---------------------------------------------------------------------------
// Per-chunk local state via MFMA: CS[blk][v*64+k] = S^T[v][k]
//   = sum_t V[t][v] * (k_t[k] e^{d63[k]-g_t[k]}) ; DD[blk][k] = e^{d63[k]}.
// X = Vt rows [v][t] (global, bf16), Y = k2^T [k][t] (LDS transpose, bf16).
// ---------------------------------------------------------------------------
template <typename QKT, typename GKT, typename CST>
__global__ __launch_bounds__(256) void chunk_state_k(
    const QKT* __restrict__ Km, const bf16* __restrict__ VT,
    const GKT* __restrict__ GKm, CST* __restrict__ CS,
    float* __restrict__ DD)
{
    __shared__ __align__(16) float gs[64][68];
    __shared__ float d63[64];
    __shared__ __align__(16) short k2t[64][72];   // [k][t] bf16
    const int blk = blockIdx.x;
    const int chunk = blk & 255;
    const int bh = blk >> 8;
    const int bi = bh >> 2, h = bh & 3;
    const int rowbase = bi * 16384 + chunk * 64;
    const int tid = threadIdx.x;

    for (int e = tid; e < 4096; e += 256) {
        const int t = e >> 6, k = e & 63;
        gs[t][k] = ldf(&GKm[(size_t)(rowbase + t) * 256 + h * 64 + k]);
    }
    __syncthreads();
    if (tid < 64) {
        float run = 0.f;
        for (int t = 0; t < 64; ++t) { run += gs[t][tid]; gs[t][tid] = run; }
        d63[tid] = run;
        DD[(size_t)blk * 64 + tid] = expf(run);
    }
    __syncthreads();
    {   // k2^T staging: thread owns column k, 16 t values (coalesced K reads)
        const int k = tid & 63, tg = tid >> 6;
        const float dk = d63[k];
        short8 p0, p1;
#pragma unroll
        for (int j = 0; j < 16; ++j) {
            const int t = tg * 16 + j;
            const float kv = ldf(&Km[(size_t)(rowbase + t) * 256 + h * 64 + k]);
            const float w = kv * expf(dk - gs[t][k]);   // decay <= 1
            if (j < 8) p0[j] = f2bs(w); else p1[j - 8] = f2bs(w);
        }
        *(short8*)&k2t[k][tg * 16] = p0;
        *(short8*)&k2t[k][tg * 16 + 8] = p1;
    }
    __syncthreads();

    const int lane = tid & 63, wid = tid >> 6;
    const int al = lane & 15, kg = lane >> 4, kg8 = kg * 8;
    const bf16* Vtb = VT + (size_t)blk * 8192;

    short8 xf[2][2];   // [m: v-rowblock][kstep]
#pragma unroll
    for (int m = 0; m < 2; ++m)
#pragma unroll
        for (int ks = 0; ks < 2; ++ks)
            xf[m][ks] = ld8bf(&Vtb[(size_t)(wid * 32 + m * 16 + al) * 64 + ks * 32 + kg8]);
    short8 yf[2][4];   // [kstep][n: k-colblock]
#pragma unroll
    for (int ks = 0; ks < 2; ++ks)
#pragma unroll
        for (int n = 0; n < 4; ++n)
            yf[ks][n] = *(const short8*)&k2t[n * 16 + al][ks * 32 + kg8];

    f32x4 acc[2][4];
#pragma unroll
    for (int m = 0; m < 2; ++m)
#pragma unroll
        for (int n = 0; n < 4; ++n)
#pragma unroll
            for (int r = 0; r < 4; ++r) acc[m][n][r] = 0.f;
#pragma unroll
    for (int ks = 0; ks < 2; ++ks)
#pragma unroll
        for (int m = 0; m < 2; ++m)
#pragma unroll
            for (int n = 0; n < 4; ++n)
                acc[m][n] = mfma_bf(xf[m][ks], yf[ks][n], acc[m][n]);

    CST* out = CS + (size_t)blk * 8192;
#pragma unroll
    for (int m = 0; m < 2; ++m)
#pragma unroll
        for (int n = 0; n < 4; ++n)
#pragma unroll
            for (int r = 0; r < 4; ++r)
                stf(&out[(size_t)(wid * 32 + m * 16 + kg * 4 + r) * 64 + n * 16 + al],
                    acc[m][n][r]);
}

// ---------------------------------------------------------------------------
// Affine scan over chunks (unchanged): slot n <- H_n; H_{n+1}=D_n H_n+S_n
// ---------------------------------------------------------------------------
template <typename CST>
__global__ __launch_bounds__(256) void scan_k(
    CST* __restrict__ CS, const float* __restrict__ DD)
{
    const int bh = blockIdx.x >> 5;
    const int slice = blockIdx.x & 31;
    const int tid = threadIdx.x;
    const int e = slice * 256 + tid;
    const int k = e & 63;
    float H = 0.f;
    CST* base = CS + (size_t)bh * 256 * 8192 + e;
    const float* dbase = DD + (size_t)bh * 256 * 64 + k;
#pragma unroll 4
    for (int n = 0; n < 256; ++n) {
        const float s = ldf(&base[(size_t)n * 8192]);
        const float d = dbase[(size_t)n * 64];
        const float nH = fmaf(d, H, s);
        stf(&base[(size_t)n * 8192], H);
        H = nH;
    }
}

// ---------------------------------------------------------------------------
// Per-chunk output via MFMA + fused LayerNorm + silu gate.
//   A = causal(qs @ ks^T); O = A @ V + qs @ H^T; GO = LN(O)*silu(GO).
// Wave w owns t-rows w*16..w*16+15 for A and O (A LDS round trip is
// wave-local -> no extra barrier). V^T, H read as fragments from global.
// LDS: gk-cumsum tile (fp32) overlaid by A (bf16) after staging.
// ---------------------------------------------------------------------------
template <typename QKT, typename GKT, typename CST>
__global__ __launch_bounds__(256) void chunk_out_k(
    const QKT* __restrict__ Qm, const QKT* __restrict__ Km,
    const bf16* __restrict__ VT, const GKT* __restrict__ GKm,
    const CST* __restrict__ CS, bf16* GO)
{
    __shared__ __align__(16) char smem[17408 + 2 * 9216];   // 35.8 KB
    float (*gs)[68] = (float (*)[68])smem;                  // gk cumsum (fp32)
    short (*qs)[72] = (short (*)[72])(smem + 17408);        // q*e^g   (bf16)
    short (*ks)[72] = (short (*)[72])(smem + 17408 + 9216); // k*e^-g  (bf16)
    short (*ab)[72] = (short (*)[72])smem;                  // A, overlays gs

    const int blk = blockIdx.x;
    const int chunk = blk & 255;
    const int bh = blk >> 8;
    const int bi = bh >> 2, h = bh & 3;
    const int rowbase = bi * 16384 + chunk * 64;
    const int tid = threadIdx.x;

    for (int e = tid; e < 4096; e += 256) {
        const int t = e >> 6, k = e & 63;
        gs[t][k] = ldf(&GKm[(size_t)(rowbase + t) * 256 + h * 64 + k]);
    }
    __syncthreads();
    if (tid < 64) {
        float run = 0.f;
        for (int t = 0; t < 64; ++t) { run += gs[t][tid]; gs[t][tid] = run; }
    }
    __syncthreads();
    {   // qs/ks staging: thread owns (row st, 16-col segment sk)
        const int st = tid >> 2, sk = (tid & 3) * 16;
        const size_t idx0 = (size_t)(rowbase + st) * 256 + h * 64 + sk;
        float qv[16], kv[16];
#pragma unroll
        for (int jj = 0; jj < 4; ++jj) {
            const float4 a = ld4(Qm + idx0 + jj * 4);
            const float4 b = ld4(Km + idx0 + jj * 4);
            qv[jj * 4 + 0] = a.x; qv[jj * 4 + 1] = a.y;
            qv[jj * 4 + 2] = a.z; qv[jj * 4 + 3] = a.w;
            kv[jj * 4 + 0] = b.x; kv[jj * 4 + 1] = b.y;
            kv[jj * 4 + 2] = b.z; kv[jj * 4 + 3] = b.w;
        }
        short8 q0, q1, k0, k1;
#pragma unroll
        for (int j = 0; j < 16; ++j) {
            const float g = gs[st][sk + j];
            const float qq = qv[j] * expf(g);
            const float kk = kv[j] * expf(-g);
            if (j < 8) { q0[j] = f2bs(qq); k0[j] = f2bs(kk); }
            else       { q1[j - 8] = f2bs(qq); k1[j - 8] = f2bs(kk); }
        }
        *(short8*)&qs[st][sk] = q0; *(short8*)&qs[st][sk + 8] = q1;
        *(short8*)&ks[st][sk] = k0; *(short8*)&ks[st][sk + 8] = k1;
    }
    __syncthreads();   // after this, gs region is dead -> ab may overlay

    const int lane = tid & 63, wid = tid >> 6;
    const int al = lane & 15, kg = lane >> 4;
    const int w16 = wid * 16, kg8 = kg * 8;

    short8 xq[2];
    xq[0] = *(const short8*)&qs[w16 + al][kg8];
    xq[1] = *(const short8*)&qs[w16 + al][32 + kg8];

    // A = qs @ ks^T for this wave's 16 t-rows
    f32x4 aacc[4];
#pragma unroll
    for (int n = 0; n < 4; ++n)
#pragma unroll
        for (int r = 0; r < 4; ++r) aacc[n][r] = 0.f;
#pragma unroll
    for (int ksb = 0; ksb < 2; ++ksb)
#pragma unroll
        for (int n = 0; n < 4; ++n) {
            const short8 y = *(const short8*)&ks[n * 16 + al][ksb * 32 + kg8];
            aacc[n] = mfma_bf(xq[ksb], y, aacc[n]);
        }
    // causal mask + bf16, wave-local rows of ab
#pragma unroll
    for (int n = 0; n < 4; ++n)
#pragma unroll
        for (int r = 0; r < 4; ++r) {
            const int tt = w16 + kg * 4 + r;
            const int ii = n * 16 + al;
            ab[tt][ii] = (ii <= tt) ? f2bs(aacc[n][r]) : (short)0;
        }
    short8 xa[2];
    xa[0] = *(const short8*)&ab[w16 + al][kg8];
    xa[1] = *(const short8*)&ab[w16 + al][32 + kg8];

    // O = A @ V + qs @ H^T  (V^T, H fragments straight from global)
    const bf16* Vtb = VT + (size_t)blk * 8192;
    const CST* Hb = CS + (size_t)blk * 8192;
    f32x4 oacc[8];
#pragma unroll
    for (int n = 0; n < 8; ++n)
#pragma unroll
        for (int r = 0; r < 4; ++r) oacc[n][r] = 0.f;
#pragma unroll
    for (int n = 0; n < 8; ++n) {
        const int vr = n * 16 + al;
        const short8 yv0 = ld8bf(&Vtb[(size_t)vr * 64 + kg8]);
        const short8 yv1 = ld8bf(&Vtb[(size_t)vr * 64 + 32 + kg8]);
        const short8 yh0 = ld8bf(&Hb[(size_t)vr * 64 + kg8]);
        const short8 yh1 = ld8bf(&Hb[(size_t)vr * 64 + 32 + kg8]);
        oacc[n] = mfma_bf(xa[0], yv0, oacc[n]);
        oacc[n] = mfma_bf(xa[1], yv1, oacc[n]);
        oacc[n] = mfma_bf(xq[0], yh0, oacc[n]);
        oacc[n] = mfma_bf(xq[1], yh1, oacc[n]);
    }

    // fused LayerNorm over v=128 (reduce across the 16 'al' lanes) + silu gate
    float psum[4] = {0.f, 0.f, 0.f, 0.f}, psq[4] = {0.f, 0.f, 0.f, 0.f};
#pragma unroll
    for (int n = 0; n < 8; ++n)
#pragma unroll
        for (int r = 0; r < 4; ++r) {
            const float v = oacc[n][r];
            psum[r] += v; psq[r] = fmaf(v, v, psq[r]);
        }
#pragma unroll
    for (int off = 1; off < 16; off <<= 1)
#pragma unroll
        for (int r = 0; r < 4; ++r) {
            psum[r] += __shfl_xor(psum[r], off);
            psq[r] += __shfl_xor(psq[r], off);
        }
#pragma unroll
    for (int r = 0; r < 4; ++r) {
        const float mu = psum[r] * (1.f / 128.f);
        const float var = psq[r] * (1.f / 128.f) - mu * mu;
        const float rstd = rsqrtf(fmaxf(var, 0.f) + 1e-5f);
        const int row = rowbase + w16 + kg * 4 + r;
        bf16* gop = GO + (size_t)row * 512 + h * 128 + al;
#pragma unroll
        for (int n = 0; n < 8; ++n) {
            const float gv = b2f(gop[n * 16]);
            const float sil = gv / (1.f + expf(-gv));
            gop[n * 16] = f2b((oacc[n][r] - mu) * rstd * sil);
        }
    }
}

__global__ __launch_bounds__(256) void zero_k(float* out, int n) {
    const int i = blockIdx.x * 256 + threadIdx.x;
    if (i < n) out[i] = 0.f;
}

// ---------------------------------------------------------------------------
template <typename QKT, typename GKT, typename CST>
static void run_all(const float* x, const float* Wq, const float* Wk,
                    const float* Wv, const float* Wg, const float* Wgk1,
                    const float* Wgk2, const float* bgk2, const float* Wo,
                    float* out, char* ws, hipStream_t stream)
{
    const int M = 32768;  // B*S
    auto aln = [](size_t v) { return (v + 255) & ~(size_t)255; };
    char* cur = ws;
    QKT* Qb = (QKT*)cur;  cur += aln((size_t)M * 256 * sizeof(QKT));
    QKT* Kb = (QKT*)cur;  cur += aln((size_t)M * 256 * sizeof(QKT));
    bf16* Vtb = (bf16*)cur; cur += aln((size_t)M * 512 * 2);   // chunk-transposed V
    bf16* GOb = (bf16*)cur; cur += aln((size_t)M * 512 * 2);   // gate, then OL
    float* DDb = (float*)cur; cur += aln((size_t)2048 * 64 * 4);
    GKT* GKb = (GKT*)cur;   cur += aln((size_t)M * 256 * sizeof(GKT));
    CST* CSb = (CST*)cur;

    const dim3 blk(256);
    gemm_mfma_k<<<dim3(M / 128, 2), blk, 0, stream>>>(x, Wq, Qb, M, 256, 512, 0.125f);
    gemm_mfma_k<<<dim3(M / 128, 2), blk, 0, stream>>>(x, Wk, Kb, M, 256, 512, 1.f);
    gemm_vt_k<<<dim3(M / 128, 4), blk, 0, stream>>>(x, Wv, Vtb, M, 512, 512);
    gemm_mfma_k<<<dim3(M / 128, 4), blk, 0, stream>>>(x, Wg, GOb, M, 512, 512, 1.f);
    gate_k<<<dim3(M), blk, 0, stream>>>(x, Wgk1, Wgk2, bgk2, GKb);
    chunk_state_k<<<dim3(2048), blk, 0, stream>>>(Kb, Vtb, GKb, CSb, DDb);
    scan_k<<<dim3(256), blk, 0, stream>>>(CSb, DDb);
    chunk_out_k<<<dim3(2048), blk, 0, stream>>>(Qb, Kb, Vtb, GKb, CSb, GOb);
    gemm_mfma_k<<<dim3(M / 128, 4), blk, 0, stream>>>(GOb, Wo, out, M, 512, 512, 1.f);
}

extern "C" void kernel_launch(void* const* d_in, const int* in_sizes, int n_in,
                              void* d_out, int out_size, void* d_ws, size_t ws_size,
                              hipStream_t stream)
{
    const float* x    = (const float*)d_in[0];
    const float* Wq   = (const float*)d_in[1];
    const float* Wk   = (const float*)d_in[2];
    const float* Wv   = (const float*)d_in[3];
    const float* Wg   = (const float*)d_in[4];
    const float* Wgk1 = (const float*)d_in[5];
    const float* Wgk2 = (const float*)d_in[6];
    const float* bgk2 = (const float*)d_in[7];
    const float* Wo   = (const float*)d_in[8];
    float* out = (float*)d_out;

    const size_t M = 32768;
    const size_t slack = 4096;
    const size_t base = M * 512 * 2 * 2 + 2048 * 64 * 4 + slack;
    const size_t qk_f = 2 * M * 256 * 4, qk_b = 2 * M * 256 * 2;
    const size_t gk_f = M * 256 * 4,     gk_b = M * 256 * 2;
    const size_t cs_f = (size_t)2048 * 8192 * 4, cs_b = (size_t)2048 * 8192 * 2;
    const size_t needA = base + qk_f + gk_f + cs_f;  // ~236 MB
    const size_t needB = base + qk_b + gk_f + cs_f;  // ~202 MB
    const size_t needC = base + qk_b + gk_b + cs_b;  // ~152 MB

    if (ws_size >= needA) {
        run_all<float, float, float>(x, Wq, Wk, Wv, Wg, Wgk1, Wgk2, bgk2, Wo,
                                     out, (char*)d_ws, stream);
    } else if (ws_size >= needB) {
        run_all<bf16, float, float>(x, Wq, Wk, Wv, Wg, Wgk1, Wgk2, bgk2, Wo,
                                    out, (char*)d_ws, stream);
    } else if (ws_size >= needC) {
        run_all<bf16, bf16, bf16>(x, Wq, Wk, Wv, Wg, Wgk1, Wgk2, bgk2, Wo,
                                  out, (char*)d_ws, stream);
    } else {
        zero_k<<<dim3((out_size + 255) / 256), dim3(256), 0, stream>>>(out, out_size);
    }
}

// Round 3
// 552.115 us; speedup vs baseline: 2.4507x; 1.0495x over previous
//
#include <hip/hip_runtime.h>
#include <hip/hip_bf16.h>

// GLA forward for MI355X. Inputs fp32, OUTPUT fp32. Pipeline:
//  0) cvt_xh_k: x (fp32) -> xh (f16) once; xh aliases CS workspace (dead until
//     chunk_state). All projection GEMMs read xh with pure 16B copies.
//  1) gemm_mfma_k: q,k (QKT ws), g (bf16 ws, silu applied in epilogue)
//     gemm_vt_k:   v projection, stored CHUNK-TRANSPOSED Vt[bh][chunk][v][t]
//  2) gate_k: gk = log_sigmoid((x@Wgk1)@Wgk2 + b)/16  (GKT ws)
//  3) chunk_state_k: per-(b,h,chunk=64) local state S^T[v][k] + decay D (bf16
//     MFMA). Column-owned staging: 4-way-parallel cumsum, no fp32 gs tile.
//  4) scan_k: affine scan over chunks -> chunk-start states H_n (in place)
//  5) chunk_out_k: o = q*e^B @ H + causal-decayed intra attention @ V (bf16
//     MFMA), fused per-head LayerNorm * pre-computed silu(g) -> OL (bf16)
//  6) gemm_mfma_k: out = OL @ Wo (fp32 to d_out)
// bf16 (not f16) for chunk matmuls: k*e^{-g} can reach ~e^20, beyond fp16 range.

typedef __hip_bfloat16 bf16;
typedef _Float16 f16;
typedef _Float16 half8 __attribute__((ext_vector_type(8)));
typedef _Float16 half4 __attribute__((ext_vector_type(4)));
typedef float f32x4 __attribute__((ext_vector_type(4)));
typedef short short8 __attribute__((ext_vector_type(8)));

#define DEV static __device__ __forceinline__

DEV float b2f(bf16 v) { return __bfloat162float(v); }
DEV bf16 f2b(float v) { return __float2bfloat16(v); }
DEV float bits2f(unsigned int u16) {
    union { unsigned int u; float f; } c; c.u = u16 << 16; return c.f;
}
// fp32 -> bf16 bits via native convert (RNE)
DEV short f2bs(float v) {
    union { bf16 h; short s; } u; u.h = __float2bfloat16(v); return u.s;
}
DEV unsigned short f2bu(float v) {
    union { bf16 h; unsigned short s; } u; u.h = __float2bfloat16(v); return u.s;
}
DEV float fast_rcp(float v) { return __builtin_amdgcn_rcpf(v); }

DEV float ldf(const float* p) { return *p; }
DEV float ldf(const bf16* p) { return b2f(*p); }
DEV void stf(float* p, float v) { *p = v; }
DEV void stf(bf16* p, float v) { *p = f2b(v); }

DEV float4 ld4(const float* p) { return *(const float4*)p; }
DEV float4 ld4(const bf16* p) {
    const uint2 r = *(const uint2*)p;
    return make_float4(bits2f(r.x & 0xffffu), bits2f(r.x >> 16),
                       bits2f(r.y & 0xffffu), bits2f(r.y >> 16));
}

// 8 elems as f16 fragment half
DEV half8 ld8h(const float* p) {
    const float4 a = *(const float4*)p, b = *(const float4*)(p + 4);
    half8 h;
    h[0] = (f16)a.x; h[1] = (f16)a.y; h[2] = (f16)a.z; h[3] = (f16)a.w;
    h[4] = (f16)b.x; h[5] = (f16)b.y; h[6] = (f16)b.z; h[7] = (f16)b.w;
    return h;
}
DEV half8 ld8h(const f16* p) { return *(const half8*)p; }
DEV half8 ld8h(const bf16* p) {
    const float4 a = ld4(p), b = ld4(p + 4);
    half8 h;
    h[0] = (f16)a.x; h[1] = (f16)a.y; h[2] = (f16)a.z; h[3] = (f16)a.w;
    h[4] = (f16)b.x; h[5] = (f16)b.y; h[6] = (f16)b.z; h[7] = (f16)b.w;
    return h;
}

// 8 elems as bf16 fragment (fp32 src: native cvt; bf16 src: direct 16B)
DEV short8 ld8bf(const float* p) {
    const float4 a = *(const float4*)p, b = *(const float4*)(p + 4);
    short8 r;
    r[0] = f2bs(a.x); r[1] = f2bs(a.y); r[2] = f2bs(a.z); r[3] = f2bs(a.w);
    r[4] = f2bs(b.x); r[5] = f2bs(b.y); r[6] = f2bs(b.z); r[7] = f2bs(b.w);
    return r;
}
DEV short8 ld8bf(const bf16* p) { return *(const short8*)p; }

DEV f32x4 mfma_bf(short8 a, short8 b, f32x4 c) {
    return __builtin_amdgcn_mfma_f32_16x16x32_bf16(a, b, c, 0, 0, 0);
}

// ---------------------------------------------------------------------------
// x (fp32) -> xh (f16), 8 elems/thread, exact-size grid
// ---------------------------------------------------------------------------
__global__ __launch_bounds__(256) void cvt_xh_k(
    const float* __restrict__ x, f16* __restrict__ xh)
{
    const size_t i = ((size_t)blockIdx.x * 256 + threadIdx.x) * 8;
    *(half8*)&xh[i] = ld8h(&x[i]);
}

// ---------------------------------------------------------------------------
// MFMA GEMM (f16 operands): C[M,N] = scale * A[M,K] @ B[K,N].
// A: float|f16|bf16. 256 thr = 4 waves (2x2), tile 128x128, BK=32,
// 4x4 16x16 frags/wave. Fragment convention (HW-verified): A[row][k],
// B[col][k], per-lane k = kg*8..+7 both sides; D: col=lane&15,
// row=4*(lane>>4)+reg. Optional silu epilogue (for the Wg projection).
// ---------------------------------------------------------------------------
template <typename AT, typename OutT, bool SILU>
__global__ __launch_bounds__(256) void gemm_mfma_k(
    const AT* __restrict__ A, const float* __restrict__ B,
    OutT* __restrict__ C, int M, int N, int K, float scale)
{
    __shared__ __align__(16) f16 As[128][40];
    __shared__ __align__(16) f16 Bs[128][40];
    const int bm = blockIdx.x * 128;
    const int bn = blockIdx.y * 128;
    const int tid = threadIdx.x;
    const int lane = tid & 63;
    const int wid = tid >> 6;
    const int wr = wid >> 1, wc = wid & 1;
    const int al = lane & 15;
    const int kg = lane >> 4;

    f32x4 acc[4][4];
#pragma unroll
    for (int m = 0; m < 4; ++m)
#pragma unroll
        for (int n = 0; n < 4; ++n)
#pragma unroll
            for (int r = 0; r < 4; ++r) acc[m][n][r] = 0.f;

    const int ar = tid >> 1;
    const int ac = (tid & 1) * 16;
    const int bkg = tid >> 5;
    const int bcg = tid & 31;

    for (int k0 = 0; k0 < K; k0 += 32) {
        {
            const AT* ap = A + (size_t)(bm + ar) * K + k0 + ac;
            *(half8*)&As[ar][ac] = ld8h(ap);
            *(half8*)&As[ar][ac + 8] = ld8h(ap + 8);
        }
        {
            const float* bp = B + (size_t)(k0 + bkg * 4) * N + bn + bcg * 4;
            const float4 r0 = ld4(bp);
            const float4 r1 = ld4(bp + N);
            const float4 r2 = ld4(bp + 2 * N);
            const float4 r3 = ld4(bp + 3 * N);
            half4 c0, c1, c2, c3;
            c0[0] = (f16)r0.x; c0[1] = (f16)r1.x; c0[2] = (f16)r2.x; c0[3] = (f16)r3.x;
            c1[0] = (f16)r0.y; c1[1] = (f16)r1.y; c1[2] = (f16)r2.y; c1[3] = (f16)r3.y;
            c2[0] = (f16)r0.z; c2[1] = (f16)r1.z; c2[2] = (f16)r2.z; c2[3] = (f16)r3.z;
            c3[0] = (f16)r0.w; c3[1] = (f16)r1.w; c3[2] = (f16)r2.w; c3[3] = (f16)r3.w;
            *(half4*)&Bs[bcg * 4 + 0][bkg * 4] = c0;
            *(half4*)&Bs[bcg * 4 + 1][bkg * 4] = c1;
            *(half4*)&Bs[bcg * 4 + 2][bkg * 4] = c2;
            *(half4*)&Bs[bcg * 4 + 3][bkg * 4] = c3;
        }
        __syncthreads();
        half8 af[4], bfr[4];
#pragma unroll
        for (int m = 0; m < 4; ++m)
            af[m] = *(const half8*)&As[wr * 64 + m * 16 + al][kg * 8];
#pragma unroll
        for (int n = 0; n < 4; ++n)
            bfr[n] = *(const half8*)&Bs[wc * 64 + n * 16 + al][kg * 8];
#pragma unroll
        for (int m = 0; m < 4; ++m)
#pragma unroll
            for (int n = 0; n < 4; ++n)
                acc[m][n] = __builtin_amdgcn_mfma_f32_16x16x32_f16(
                    af[m], bfr[n], acc[m][n], 0, 0, 0);
        __syncthreads();
    }
    const int r0 = bm + wr * 64 + kg * 4;
    const int c0 = bn + wc * 64 + al;
#pragma unroll
    for (int m = 0; m < 4; ++m)
#pragma unroll
        for (int n = 0; n < 4; ++n)
#pragma unroll
            for (int r = 0; r < 4; ++r) {
                float v = acc[m][n][r] * scale;
                if (SILU) v = v * fast_rcp(1.f + __expf(-v));
                stf(&C[(size_t)(r0 + m * 16 + r) * N + c0 + n * 16], v);
            }
}

// ---------------------------------------------------------------------------
// V projection with chunk-transposed store: Vt[((bi*4+h)*256+chunk)*128+v][t]
// ---------------------------------------------------------------------------
template <typename AT>
__global__ __launch_bounds__(256) void gemm_vt_k(
    const AT* __restrict__ A, const float* __restrict__ B,
    bf16* __restrict__ VT, int M, int N, int K)
{
    __shared__ __align__(16) f16 As[128][40];
    __shared__ __align__(16) f16 Bs[128][40];
    const int bm = blockIdx.x * 128;
    const int bn = blockIdx.y * 128;
    const int tid = threadIdx.x;
    const int lane = tid & 63;
    const int wid = tid >> 6;
    const int wr = wid >> 1, wc = wid & 1;
    const int al = lane & 15;
    const int kg = lane >> 4;

    f32x4 acc[4][4];
#pragma unroll
    for (int m = 0; m < 4; ++m)
#pragma unroll
        for (int n = 0; n < 4; ++n)
#pragma unroll
            for (int r = 0; r < 4; ++r) acc[m][n][r] = 0.f;

    const int ar = tid >> 1;
    const int ac = (tid & 1) * 16;
    const int bkg = tid >> 5;
    const int bcg = tid & 31;

    for (int k0 = 0; k0 < K; k0 += 32) {
        {
            const AT* ap = A + (size_t)(bm + ar) * K + k0 + ac;
            *(half8*)&As[ar][ac] = ld8h(ap);
            *(half8*)&As[ar][ac + 8] = ld8h(ap + 8);
        }
        {
            const float* bp = B + (size_t)(k0 + bkg * 4) * N + bn + bcg * 4;
            const float4 r0 = ld4(bp);
            const float4 r1 = ld4(bp + N);
            const float4 r2 = ld4(bp + 2 * N);
            const float4 r3 = ld4(bp + 3 * N);
            half4 c0, c1, c2, c3;
            c0[0] = (f16)r0.x; c0[1] = (f16)r1.x; c0[2] = (f16)r2.x; c0[3] = (f16)r3.x;
            c1[0] = (f16)r0.y; c1[1] = (f16)r1.y; c1[2] = (f16)r2.y; c1[3] = (f16)r3.y;
            c2[0] = (f16)r0.z; c2[1] = (f16)r1.z; c2[2] = (f16)r2.z; c2[3] = (f16)r3.z;
            c3[0] = (f16)r0.w; c3[1] = (f16)r1.w; c3[2] = (f16)r2.w; c3[3] = (f16)r3.w;
            *(half4*)&Bs[bcg * 4 + 0][bkg * 4] = c0;
            *(half4*)&Bs[bcg * 4 + 1][bkg * 4] = c1;
            *(half4*)&Bs[bcg * 4 + 2][bkg * 4] = c2;
            *(half4*)&Bs[bcg * 4 + 3][bkg * 4] = c3;
        }
        __syncthreads();
        half8 af[4], bfr[4];
#pragma unroll
        for (int m = 0; m < 4; ++m)
            af[m] = *(const half8*)&As[wr * 64 + m * 16 + al][kg * 8];
#pragma unroll
        for (int n = 0; n < 4; ++n)
            bfr[n] = *(const half8*)&Bs[wc * 64 + n * 16 + al][kg * 8];
#pragma unroll
        for (int m = 0; m < 4; ++m)
#pragma unroll
            for (int n = 0; n < 4; ++n)
                acc[m][n] = __builtin_amdgcn_mfma_f32_16x16x32_f16(
                    af[m], bfr[n], acc[m][n], 0, 0, 0);
        __syncthreads();
    }
    const int r00 = bm + wr * 64 + kg * 4;
    const int c00 = bn + wc * 64 + al;
#pragma unroll
    for (int m = 0; m < 4; ++m) {
        const int row0 = r00 + m * 16;                 // 4 consecutive t rows
        const int bi = row0 >> 14;
        const int chunk = (row0 >> 6) & 255;
        const int tc = row0 & 63;
#pragma unroll
        for (int n = 0; n < 4; ++n) {
            const int col = c00 + n * 16;
            const int h = col >> 7, v = col & 127;
            bf16* dst = VT + ((size_t)((bi * 4 + h) * 256 + chunk) * 128 + v) * 64 + tc;
            ushort4 pk;
            pk.x = f2bu(acc[m][n][0]); pk.y = f2bu(acc[m][n][1]);
            pk.z = f2bu(acc[m][n][2]); pk.w = f2bu(acc[m][n][3]);
            *(ushort4*)dst = pk;
        }
    }
}

// ---------------------------------------------------------------------------
// gk = log_sigmoid((x @ Wgk1) @ Wgk2 + bgk2) / 16 ; one block per row
// ---------------------------------------------------------------------------
template <typename GKT>
__global__ __launch_bounds__(256) void gate_k(
    const float* __restrict__ x, const float* __restrict__ Wgk1,
    const float* __restrict__ Wgk2, const float* __restrict__ bgk2,
    GKT* __restrict__ GK)
{
    __shared__ float xs[512];
    __shared__ float part[16][17];
    __shared__ float tl[16];
    const int row = blockIdx.x;
    const int tid = threadIdx.x;
    const float* xp = x + (size_t)row * 512;
    xs[tid] = xp[tid];
    xs[tid + 256] = xp[tid + 256];
    __syncthreads();
    const int j = tid & 15, seg = tid >> 4;
    float p = 0.f;
#pragma unroll
    for (int i = 0; i < 32; ++i) {
        const int c = seg * 32 + i;
        p = fmaf(xs[c], Wgk1[c * 16 + j], p);
    }
    part[seg][j] = p;
    __syncthreads();
    if (tid < 16) {
        float s = 0.f;
#pragma unroll
        for (int sg = 0; sg < 16; ++sg) s += part[sg][tid];
        tl[tid] = s;
    }
    __syncthreads();
    float z = bgk2[tid];
#pragma unroll
    for (int r = 0; r < 16; ++r)
        z = fmaf(tl[r], Wgk2[r * 256 + tid], z);
    const float ls = fminf(z, 0.f) - log1pf(expf(-fabsf(z)));
    stf(&GK[(size_t)row * 256 + tid], ls * (1.f / 16.f));
}

// ---------------------------------------------------------------------------
// Per-chunk local state via MFMA: CS[blk][v*64+k] = S^T[v][k]
//   = sum_t V[t][v] * (k_t[k] e^{d63[k]-g_t[k]}) ; DD[blk][k] = e^{d63[k]}.
// Column-owned staging: thread (k=tid&63, tg=tid>>6) handles 16 t-rows of
// column k -> 4-way parallel cumsum via group partials, no fp32 gs tile.
// ---------------------------------------------------------------------------
template <typename QKT, typename GKT, typename CST>
__global__ __launch_bounds__(256) void chunk_state_k(
    const QKT* __restrict__ Km, const bf16* __restrict__ VT,
    const GKT* __restrict__ GKm, CST* __restrict__ CS,
    float* __restrict__ DD)
{
    __shared__ __align__(16) short k2t[64][72];   // [k][t] bf16
    __shared__ float cpart[4][64];
    const int blk = blockIdx.x;
    const int chunk = blk & 255;
    const int bh = blk >> 8;
    const int bi = bh >> 2, h = bh & 3;
    const int rowbase = bi * 16384 + chunk * 64;
    const int tid = threadIdx.x;
    const int k = tid & 63, tg = tid >> 6;

    // pass 1: local inclusive cumsum of gk over this thread's 16 t-rows
    float g[16];
    {
        float run = 0.f;
#pragma unroll
        for (int j = 0; j < 16; ++j) {
            run += ldf(&GKm[(size_t)(rowbase + tg * 16 + j) * 256 + h * 64 + k]);
            g[j] = run;
        }
        cpart[tg][k] = run;
    }
    __syncthreads();
    float off = 0.f;
#pragma unroll
    for (int s = 0; s < 3; ++s) if (s < tg) off += cpart[s][k];
    const float tot = cpart[0][k] + cpart[1][k] + cpart[2][k] + cpart[3][k];
    if (tg == 0) DD[(size_t)blk * 64 + k] = __expf(tot);

    // pass 2: k2^T staging
    {
        short8 p0, p1;
#pragma unroll
        for (int j = 0; j < 16; ++j) {
            const float kv = ldf(&Km[(size_t)(rowbase + tg * 16 + j) * 256 + h * 64 + k]);
            const float w = kv * __expf(tot - (g[j] + off));   // decay <= 1
            if (j < 8) p0[j] = f2bs(w); else p1[j - 8] = f2bs(w);
        }
        *(short8*)&k2t[k][tg * 16] = p0;
        *(short8*)&k2t[k][tg * 16 + 8] = p1;
    }
    __syncthreads();

    const int lane = tid & 63, wid = tid >> 6;
    const int al = lane & 15, kg = lane >> 4, kg8 = kg * 8;
    const bf16* Vtb = VT + (size_t)blk * 8192;

    short8 xf[2][2];   // [m: v-rowblock][kstep]
#pragma unroll
    for (int m = 0; m < 2; ++m)
#pragma unroll
        for (int ks = 0; ks < 2; ++ks)
            xf[m][ks] = ld8bf(&Vtb[(size_t)(wid * 32 + m * 16 + al) * 64 + ks * 32 + kg8]);
    short8 yf[2][4];   // [kstep][n: k-colblock]
#pragma unroll
    for (int ks = 0; ks < 2; ++ks)
#pragma unroll
        for (int n = 0; n < 4; ++n)
            yf[ks][n] = *(const short8*)&k2t[n * 16 + al][ks * 32 + kg8];

    f32x4 acc[2][4];
#pragma unroll
    for (int m = 0; m < 2; ++m)
#pragma unroll
        for (int n = 0; n < 4; ++n)
#pragma unroll
            for (int r = 0; r < 4; ++r) acc[m][n][r] = 0.f;
#pragma unroll
    for (int ks = 0; ks < 2; ++ks)
#pragma unroll
        for (int m = 0; m < 2; ++m)
#pragma unroll
            for (int n = 0; n < 4; ++n)
                acc[m][n] = mfma_bf(xf[m][ks], yf[ks][n], acc[m][n]);

    CST* out = CS + (size_t)blk * 8192;
#pragma unroll
    for (int m = 0; m < 2; ++m)
#pragma unroll
        for (int n = 0; n < 4; ++n)
#pragma unroll
            for (int r = 0; r < 4; ++r)
                stf(&out[(size_t)(wid * 32 + m * 16 + kg * 4 + r) * 64 + n * 16 + al],
                    acc[m][n][r]);
}

// ---------------------------------------------------------------------------
// Affine scan over chunks (unchanged): slot n <- H_n; H_{n+1}=D_n H_n+S_n
// ---------------------------------------------------------------------------
template <typename CST>
__global__ __launch_bounds__(256) void scan_k(
    CST* __restrict__ CS, const float* __restrict__ DD)
{
    const int bh = blockIdx.x >> 5;
    const int slice = blockIdx.x & 31;
    const int tid = threadIdx.x;
    const int e = slice * 256 + tid;
    const int k = e & 63;
    float H = 0.f;
    CST* base = CS + (size_t)bh * 256 * 8192 + e;
    const float* dbase = DD + (size_t)bh * 256 * 64 + k;
#pragma unroll 4
    for (int n = 0; n < 256; ++n) {
        const float s = ldf(&base[(size_t)n * 8192]);
        const float d = dbase[(size_t)n * 64];
        const float nH = fmaf(d, H, s);
        stf(&base[(size_t)n * 8192], H);
        H = nH;
    }
}

// ---------------------------------------------------------------------------
// Per-chunk output via MFMA + fused LayerNorm * precomputed silu(g).
//   A = causal(qs @ ks^T); O = A @ V + qs @ H^T; GO = LN(O)*GO.
// Column-owned staging (no fp32 gs tile), parallel cumsum; A LDS round trip
// is wave-local (no extra barrier). LDS 28.7 KB -> 5 blocks/CU.
// ---------------------------------------------------------------------------
template <typename QKT, typename GKT, typename CST>
__global__ __launch_bounds__(256) void chunk_out_k(
    const QKT* __restrict__ Qm, const QKT* __restrict__ Km,
    const bf16* __restrict__ VT, const GKT* __restrict__ GKm,
    const CST* __restrict__ CS, bf16* GO)
{
    __shared__ __align__(16) short qs[64][72];   // q*e^g   (bf16)
    __shared__ __align__(16) short ks[64][72];   // k*e^-g  (bf16)
    __shared__ __align__(16) short ab[64][72];   // causal A (bf16)
    __shared__ float cpart[4][64];

    const int blk = blockIdx.x;
    const int chunk = blk & 255;
    const int bh = blk >> 8;
    const int bi = bh >> 2, h = bh & 3;
    const int rowbase = bi * 16384 + chunk * 64;
    const int tid = threadIdx.x;
    const int k = tid & 63, tg = tid >> 6;

    // cumsum of gk (4-way parallel over t-groups)
    float g[16];
    {
        float run = 0.f;
#pragma unroll
        for (int j = 0; j < 16; ++j) {
            run += ldf(&GKm[(size_t)(rowbase + tg * 16 + j) * 256 + h * 64 + k]);
            g[j] = run;
        }
        cpart[tg][k] = run;
    }
    __syncthreads();
    float off = 0.f;
#pragma unroll
    for (int s = 0; s < 3; ++s) if (s < tg) off += cpart[s][k];

    // qs/ks staging, column-owned
#pragma unroll
    for (int j = 0; j < 16; ++j) {
        const int t = tg * 16 + j;
        const size_t idx = (size_t)(rowbase + t) * 256 + h * 64 + k;
        const float gc = g[j] + off;
        const float eg = __expf(gc);
        qs[t][k] = f2bs(ldf(&Qm[idx]) * eg);
        ks[t][k] = f2bs(ldf(&Km[idx]) * fast_rcp(eg));
    }
    __syncthreads();

    const int lane = tid & 63, wid = tid >> 6;
    const int al = lane & 15, kg = lane >> 4;
    const int w16 = wid * 16, kg8 = kg * 8;

    short8 xq[2];
    xq[0] = *(const short8*)&qs[w16 + al][kg8];
    xq[1] = *(const short8*)&qs[w16 + al][32 + kg8];

    // A = qs @ ks^T for this wave's 16 t-rows
    f32x4 aacc[4];
#pragma unroll
    for (int n = 0; n < 4; ++n)
#pragma unroll
        for (int r = 0; r < 4; ++r) aacc[n][r] = 0.f;
#pragma unroll
    for (int ksb = 0; ksb < 2; ++ksb)
#pragma unroll
        for (int n = 0; n < 4; ++n) {
            const short8 y = *(const short8*)&ks[n * 16 + al][ksb * 32 + kg8];
            aacc[n] = mfma_bf(xq[ksb], y, aacc[n]);
        }
    // causal mask + bf16, wave-local rows of ab
#pragma unroll
    for (int n = 0; n < 4; ++n)
#pragma unroll
        for (int r = 0; r < 4; ++r) {
            const int tt = w16 + kg * 4 + r;
            const int ii = n * 16 + al;
            ab[tt][ii] = (ii <= tt) ? f2bs(aacc[n][r]) : (short)0;
        }
    short8 xa[2];
    xa[0] = *(const short8*)&ab[w16 + al][kg8];
    xa[1] = *(const short8*)&ab[w16 + al][32 + kg8];

    // O = A @ V + qs @ H^T  (V^T, H fragments straight from global)
    const bf16* Vtb = VT + (size_t)blk * 8192;
    const CST* Hb = CS + (size_t)blk * 8192;
    f32x4 oacc[8];
#pragma unroll
    for (int n = 0; n < 8; ++n)
#pragma unroll
        for (int r = 0; r < 4; ++r) oacc[n][r] = 0.f;
#pragma unroll
    for (int n = 0; n < 8; ++n) {
        const int vr = n * 16 + al;
        const short8 yv0 = ld8bf(&Vtb[(size_t)vr * 64 + kg8]);
        const short8 yv1 = ld8bf(&Vtb[(size_t)vr * 64 + 32 + kg8]);
        const short8 yh0 = ld8bf(&Hb[(size_t)vr * 64 + kg8]);
        const short8 yh1 = ld8bf(&Hb[(size_t)vr * 64 + 32 + kg8]);
        oacc[n] = mfma_bf(xa[0], yv0, oacc[n]);
        oacc[n] = mfma_bf(xa[1], yv1, oacc[n]);
        oacc[n] = mfma_bf(xq[0], yh0, oacc[n]);
        oacc[n] = mfma_bf(xq[1], yh1, oacc[n]);
    }

    // fused LayerNorm over v=128 (reduce across the 16 'al' lanes) * silu(g)
    float psum[4] = {0.f, 0.f, 0.f, 0.f}, psq[4] = {0.f, 0.f, 0.f, 0.f};
#pragma unroll
    for (int n = 0; n < 8; ++n)
#pragma unroll
        for (int r = 0; r < 4; ++r) {
            const float v = oacc[n][r];
            psum[r] += v; psq[r] = fmaf(v, v, psq[r]);
        }
#pragma unroll
    for (int offx = 1; offx < 16; offx <<= 1)
#pragma unroll
        for (int r = 0; r < 4; ++r) {
            psum[r] += __shfl_xor(psum[r], offx);
            psq[r] += __shfl_xor(psq[r], offx);
        }
#pragma unroll
    for (int r = 0; r < 4; ++r) {
        const float mu = psum[r] * (1.f / 128.f);
        const float var = psq[r] * (1.f / 128.f) - mu * mu;
        const float rstd = rsqrtf(fmaxf(var, 0.f) + 1e-5f);
        const int row = rowbase + w16 + kg * 4 + r;
        bf16* gop = GO + (size_t)row * 512 + h * 128 + al;
#pragma unroll
        for (int n = 0; n < 8; ++n) {
            const float sil = b2f(gop[n * 16]);          // silu(g), precomputed
            gop[n * 16] = f2b((oacc[n][r] - mu) * rstd * sil);
        }
    }
}

__global__ __launch_bounds__(256) void zero_k(float* out, int n) {
    const int i = blockIdx.x * 256 + threadIdx.x;
    if (i < n) out[i] = 0.f;
}

// ---------------------------------------------------------------------------
template <typename QKT, typename GKT, typename CST>
static void run_all(const float* x, const float* Wq, const float* Wk,
                    const float* Wv, const float* Wg, const float* Wgk1,
                    const float* Wgk2, const float* bgk2, const float* Wo,
                    float* out, char* ws, hipStream_t stream)
{
    const int M = 32768;  // B*S
    auto aln = [](size_t v) { return (v + 255) & ~(size_t)255; };
    char* cur = ws;
    QKT* Qb = (QKT*)cur;  cur += aln((size_t)M * 256 * sizeof(QKT));
    QKT* Kb = (QKT*)cur;  cur += aln((size_t)M * 256 * sizeof(QKT));
    bf16* Vtb = (bf16*)cur; cur += aln((size_t)M * 512 * 2);   // chunk-transposed V
    bf16* GOb = (bf16*)cur; cur += aln((size_t)M * 512 * 2);   // silu(g), then OL
    float* DDb = (float*)cur; cur += aln((size_t)2048 * 64 * 4);
    GKT* GKb = (GKT*)cur;   cur += aln((size_t)M * 256 * sizeof(GKT));
    CST* CSb = (CST*)cur;
    f16* xh = (f16*)CSb;    // aliases CS: dead until chunk_state_k writes it

    const dim3 blk(256);
    cvt_xh_k<<<dim3(8192), blk, 0, stream>>>(x, xh);
    gemm_mfma_k<f16, QKT, false><<<dim3(M / 128, 2), blk, 0, stream>>>(xh, Wq, Qb, M, 256, 512, 0.125f);
    gemm_mfma_k<f16, QKT, false><<<dim3(M / 128, 2), blk, 0, stream>>>(xh, Wk, Kb, M, 256, 512, 1.f);
    gemm_vt_k<f16><<<dim3(M / 128, 4), blk, 0, stream>>>(xh, Wv, Vtb, M, 512, 512);
    gemm_mfma_k<f16, bf16, true><<<dim3(M / 128, 4), blk, 0, stream>>>(xh, Wg, GOb, M, 512, 512, 1.f);
    gate_k<<<dim3(M), blk, 0, stream>>>(x, Wgk1, Wgk2, bgk2, GKb);
    chunk_state_k<<<dim3(2048), blk, 0, stream>>>(Kb, Vtb, GKb, CSb, DDb);
    scan_k<<<dim3(256), blk, 0, stream>>>(CSb, DDb);
    chunk_out_k<<<dim3(2048), blk, 0, stream>>>(Qb, Kb, Vtb, GKb, CSb, GOb);
    gemm_mfma_k<bf16, float, false><<<dim3(M / 128, 4), blk, 0, stream>>>(GOb, Wo, out, M, 512, 512, 1.f);
}

extern "C" void kernel_launch(void* const* d_in, const int* in_sizes, int n_in,
                              void* d_out, int out_size, void* d_ws, size_t ws_size,
                              hipStream_t stream)
{
    const float* x    = (const float*)d_in[0];
    const float* Wq   = (const float*)d_in[1];
    const float* Wk   = (const float*)d_in[2];
    const float* Wv   = (const float*)d_in[3];
    const float* Wg   = (const float*)d_in[4];
    const float* Wgk1 = (const float*)d_in[5];
    const float* Wgk2 = (const float*)d_in[6];
    const float* bgk2 = (const float*)d_in[7];
    const float* Wo   = (const float*)d_in[8];
    float* out = (float*)d_out;

    const size_t M = 32768;
    const size_t slack = 4096;
    const size_t base = M * 512 * 2 * 2 + 2048 * 64 * 4 + slack;
    const size_t qk_f = 2 * M * 256 * 4, qk_b = 2 * M * 256 * 2;
    const size_t gk_f = M * 256 * 4,     gk_b = M * 256 * 2;
    const size_t cs_f = (size_t)2048 * 8192 * 4, cs_b = (size_t)2048 * 8192 * 2;
    const size_t needA = base + qk_f + gk_f + cs_f;  // ~236 MB
    const size_t needB = base + qk_b + gk_f + cs_f;  // ~202 MB
    const size_t needC = base + qk_b + gk_b + cs_b;  // ~152 MB

    if (ws_size >= needA) {
        run_all<float, float, float>(x, Wq, Wk, Wv, Wg, Wgk1, Wgk2, bgk2, Wo,
                                     out, (char*)d_ws, stream);
    } else if (ws_size >= needB) {
        run_all<bf16, float, float>(x, Wq, Wk, Wv, Wg, Wgk1, Wgk2, bgk2, Wo,
                                    out, (char*)d_ws, stream);
    } else if (ws_size >= needC) {
        run_all<bf16, bf16, bf16>(x, Wq, Wk, Wv, Wg, Wgk1, Wgk2, bgk2, Wo,
                                  out, (char*)d_ws, stream);
    } else {
        zero_k<<<dim3((out_size + 255) / 256), dim3(256), 0, stream>>>(out, out_size);
    }
}

// Round 5
// 535.764 us; speedup vs baseline: 2.5255x; 1.0305x over previous
//
#include <hip/hip_runtime.h>
#include <hip/hip_bf16.h>

// GLA forward for MI355X. Inputs fp32, OUTPUT fp32. Pipeline:
//  0) cvt_xh_k: x (fp32) -> xh (f16) once; xh aliases CS workspace.
//  1) gemm_mfma_k: q,k -> bf16; g -> bf16 with fused silu epilogue
//     gemm_vt_k:   v projection -> FRAGMENT-MAJOR Vf[blk][frag][lane][8] bf16
//  2) gate_k: gk = log_sigmoid((x@Wgk1)@Wgk2 + b)/16  (GKT ws)
//  3) chunk_state_k: per-(b,h,chunk=64) local state S^T[v][k] (fp32/CST) + D
//  4) scan_k: affine scan over chunks; writes chunk-start states H_n to Hf
//     (bf16, FRAGMENT-MAJOR) -- CS keeps S, no in-place rewrite
//  5) chunk_out_k: o = q*e^B @ H + causal intra attention @ V (bf16 MFMA),
//     fused per-head LayerNorm * precomputed silu(g) -> OL (bf16)
//  6) gemm_mfma_k: out = OL @ Wo (fp32 to d_out)
// Fragment-major layout for a [v][t] (128x64) bf16 matrix consumed as MFMA
// B/A operands: off(v,t) = (((v>>4)*2+(t>>5))*4+((t>>3)&3))*128+(v&15)*8+(t&7)
//             = frag*512 + lane*8 + elem  -> per-wave fragment load is one
// contiguous 1KB transaction (16B/lane). Same convention on both MFMA
// operands => contraction exact regardless of HW k-ordering.

typedef __hip_bfloat16 bf16;
typedef _Float16 f16;
typedef _Float16 half8 __attribute__((ext_vector_type(8)));
typedef _Float16 half4 __attribute__((ext_vector_type(4)));
typedef float f32x4 __attribute__((ext_vector_type(4)));
typedef short short8 __attribute__((ext_vector_type(8)));

#define DEV static __device__ __forceinline__

DEV float b2f(bf16 v) { return __bfloat162float(v); }
DEV bf16 f2b(float v) { return __float2bfloat16(v); }
DEV float bits2f(unsigned int u16) {
    union { unsigned int u; float f; } c; c.u = u16 << 16; return c.f;
}
DEV short f2bs(float v) {
    union { bf16 h; short s; } u; u.h = __float2bfloat16(v); return u.s;
}
DEV unsigned short f2bu(float v) {
    union { bf16 h; unsigned short s; } u; u.h = __float2bfloat16(v); return u.s;
}
DEV float fast_rcp(float v) { return __builtin_amdgcn_rcpf(v); }

DEV float ldf(const float* p) { return *p; }
DEV float ldf(const bf16* p) { return b2f(*p); }
DEV void stf(float* p, float v) { *p = v; }
DEV void stf(bf16* p, float v) { *p = f2b(v); }

DEV float4 ld4(const float* p) { return *(const float4*)p; }
DEV float4 ld4(const bf16* p) {
    const uint2 r = *(const uint2*)p;
    return make_float4(bits2f(r.x & 0xffffu), bits2f(r.x >> 16),
                       bits2f(r.y & 0xffffu), bits2f(r.y >> 16));
}

DEV half8 ld8h(const float* p) {
    const float4 a = *(const float4*)p, b = *(const float4*)(p + 4);
    half8 h;
    h[0] = (f16)a.x; h[1] = (f16)a.y; h[2] = (f16)a.z; h[3] = (f16)a.w;
    h[4] = (f16)b.x; h[5] = (f16)b.y; h[6] = (f16)b.z; h[7] = (f16)b.w;
    return h;
}
DEV half8 ld8h(const f16* p) { return *(const half8*)p; }
DEV half8 ld8h(const bf16* p) {           // bf16 -> f16 (exact for |v|<2^15)
    const float4 a = ld4(p), b = ld4(p + 4);
    half8 h;
    h[0] = (f16)a.x; h[1] = (f16)a.y; h[2] = (f16)a.z; h[3] = (f16)a.w;
    h[4] = (f16)b.x; h[5] = (f16)b.y; h[6] = (f16)b.z; h[7] = (f16)b.w;
    return h;
}

DEV f32x4 mfma_bf(short8 a, short8 b, f32x4 c) {
    return __builtin_amdgcn_mfma_f32_16x16x32_bf16(a, b, c, 0, 0, 0);
}

// fragment-major offset for a 128x64 [v][t] operand matrix
DEV size_t voff(int v, int t) {
    return (size_t)(((((v >> 4) * 2 + (t >> 5)) * 4 + ((t >> 3) & 3)) * 16
                     + (v & 15)) * 8 + (t & 7));
}

// ---------------------------------------------------------------------------
// x (fp32) -> xh (f16), 8 elems/thread
// ---------------------------------------------------------------------------
__global__ __launch_bounds__(256) void cvt_xh_k(
    const float* __restrict__ x, f16* __restrict__ xh)
{
    const size_t i = ((size_t)blockIdx.x * 256 + threadIdx.x) * 8;
    *(half8*)&xh[i] = ld8h(&x[i]);
}

// ---------------------------------------------------------------------------
// MFMA GEMM (f16 operands): C[M,N] = scale * A[M,K] @ B[K,N].
// 256 thr = 4 waves (2x2), tile 128x128, BK=32, 4x4 16x16 frags/wave.
// D: col=lane&15, row=4*(lane>>4)+reg (HW-verified). Optional silu epilogue.
// ---------------------------------------------------------------------------
template <typename AT, typename OutT, bool SILU>
__global__ __launch_bounds__(256) void gemm_mfma_k(
    const AT* __restrict__ A, const float* __restrict__ B,
    OutT* __restrict__ C, int M, int N, int K, float scale)
{
    __shared__ __align__(16) f16 As[128][40];
    __shared__ __align__(16) f16 Bs[128][40];
    const int bm = blockIdx.x * 128;
    const int bn = blockIdx.y * 128;
    const int tid = threadIdx.x;
    const int lane = tid & 63;
    const int wid = tid >> 6;
    const int wr = wid >> 1, wc = wid & 1;
    const int al = lane & 15;
    const int kg = lane >> 4;

    f32x4 acc[4][4];
#pragma unroll
    for (int m = 0; m < 4; ++m)
#pragma unroll
        for (int n = 0; n < 4; ++n)
#pragma unroll
            for (int r = 0; r < 4; ++r) acc[m][n][r] = 0.f;

    const int ar = tid >> 1;
    const int ac = (tid & 1) * 16;
    const int bkg = tid >> 5;
    const int bcg = tid & 31;

    for (int k0 = 0; k0 < K; k0 += 32) {
        {
            const AT* ap = A + (size_t)(bm + ar) * K + k0 + ac;
            *(half8*)&As[ar][ac] = ld8h(ap);
            *(half8*)&As[ar][ac + 8] = ld8h(ap + 8);
        }
        {
            const float* bp = B + (size_t)(k0 + bkg * 4) * N + bn + bcg * 4;
            const float4 r0 = ld4(bp);
            const float4 r1 = ld4(bp + N);
            const float4 r2 = ld4(bp + 2 * N);
            const float4 r3 = ld4(bp + 3 * N);
            half4 c0, c1, c2, c3;
            c0[0] = (f16)r0.x; c0[1] = (f16)r1.x; c0[2] = (f16)r2.x; c0[3] = (f16)r3.x;
            c1[0] = (f16)r0.y; c1[1] = (f16)r1.y; c1[2] = (f16)r2.y; c1[3] = (f16)r3.y;
            c2[0] = (f16)r0.z; c2[1] = (f16)r1.z; c2[2] = (f16)r2.z; c2[3] = (f16)r3.z;
            c3[0] = (f16)r0.w; c3[1] = (f16)r1.w; c3[2] = (f16)r2.w; c3[3] = (f16)r3.w;
            *(half4*)&Bs[bcg * 4 + 0][bkg * 4] = c0;
            *(half4*)&Bs[bcg * 4 + 1][bkg * 4] = c1;
            *(half4*)&Bs[bcg * 4 + 2][bkg * 4] = c2;
            *(half4*)&Bs[bcg * 4 + 3][bkg * 4] = c3;
        }
        __syncthreads();
        half8 af[4], bfr[4];
#pragma unroll
        for (int m = 0; m < 4; ++m)
            af[m] = *(const half8*)&As[wr * 64 + m * 16 + al][kg * 8];
#pragma unroll
        for (int n = 0; n < 4; ++n)
            bfr[n] = *(const half8*)&Bs[wc * 64 + n * 16 + al][kg * 8];
#pragma unroll
        for (int m = 0; m < 4; ++m)
#pragma unroll
            for (int n = 0; n < 4; ++n)
                acc[m][n] = __builtin_amdgcn_mfma_f32_16x16x32_f16(
                    af[m], bfr[n], acc[m][n], 0, 0, 0);
        __syncthreads();
    }
    const int r0 = bm + wr * 64 + kg * 4;
    const int c0 = bn + wc * 64 + al;
#pragma unroll
    for (int m = 0; m < 4; ++m)
#pragma unroll
        for (int n = 0; n < 4; ++n)
#pragma unroll
            for (int r = 0; r < 4; ++r) {
                float v = acc[m][n][r] * scale;
                if (SILU) v = v * fast_rcp(1.f + __expf(-v));
                stf(&C[(size_t)(r0 + m * 16 + r) * N + c0 + n * 16], v);
            }
}

// ---------------------------------------------------------------------------
// V projection, stored fragment-major per (bh,chunk) block: Vf[blk*8192 +
// voff(v,t)]. 4 consecutive t at fixed v = 4 contiguous elems -> 8B store.
// ---------------------------------------------------------------------------
__global__ __launch_bounds__(256) void gemm_vt_k(
    const f16* __restrict__ A, const float* __restrict__ B,
    bf16* __restrict__ VF, int M, int N, int K)
{
    __shared__ __align__(16) f16 As[128][40];
    __shared__ __align__(16) f16 Bs[128][40];
    const int bm = blockIdx.x * 128;
    const int bn = blockIdx.y * 128;
    const int tid = threadIdx.x;
    const int lane = tid & 63;
    const int wid = tid >> 6;
    const int wr = wid >> 1, wc = wid & 1;
    const int al = lane & 15;
    const int kg = lane >> 4;

    f32x4 acc[4][4];
#pragma unroll
    for (int m = 0; m < 4; ++m)
#pragma unroll
        for (int n = 0; n < 4; ++n)
#pragma unroll
            for (int r = 0; r < 4; ++r) acc[m][n][r] = 0.f;

    const int ar = tid >> 1;
    const int ac = (tid & 1) * 16;
    const int bkg = tid >> 5;
    const int bcg = tid & 31;

    for (int k0 = 0; k0 < K; k0 += 32) {
        {
            const f16* ap = A + (size_t)(bm + ar) * K + k0 + ac;
            *(half8*)&As[ar][ac] = ld8h(ap);
            *(half8*)&As[ar][ac + 8] = ld8h(ap + 8);
        }
        {
            const float* bp = B + (size_t)(k0 + bkg * 4) * N + bn + bcg * 4;
            const float4 r0 = ld4(bp);
            const float4 r1 = ld4(bp + N);
            const float4 r2 = ld4(bp + 2 * N);
            const float4 r3 = ld4(bp + 3 * N);
            half4 c0, c1, c2, c3;
            c0[0] = (f16)r0.x; c0[1] = (f16)r1.x; c0[2] = (f16)r2.x; c0[3] = (f16)r3.x;
            c1[0] = (f16)r0.y; c1[1] = (f16)r1.y; c1[2] = (f16)r2.y; c1[3] = (f16)r3.y;
            c2[0] = (f16)r0.z; c2[1] = (f16)r1.z; c2[2] = (f16)r2.z; c2[3] = (f16)r3.z;
            c3[0] = (f16)r0.w; c3[1] = (f16)r1.w; c3[2] = (f16)r2.w; c3[3] = (f16)r3.w;
            *(half4*)&Bs[bcg * 4 + 0][bkg * 4] = c0;
            *(half4*)&Bs[bcg * 4 + 1][bkg * 4] = c1;
            *(half4*)&Bs[bcg * 4 + 2][bkg * 4] = c2;
            *(half4*)&Bs[bcg * 4 + 3][bkg * 4] = c3;
        }
        __syncthreads();
        half8 af[4], bfr[4];
#pragma unroll
        for (int m = 0; m < 4; ++m)
            af[m] = *(const half8*)&As[wr * 64 + m * 16 + al][kg * 8];
#pragma unroll
        for (int n = 0; n < 4; ++n)
            bfr[n] = *(const half8*)&Bs[wc * 64 + n * 16 + al][kg * 8];
#pragma unroll
        for (int m = 0; m < 4; ++m)
#pragma unroll
            for (int n = 0; n < 4; ++n)
                acc[m][n] = __builtin_amdgcn_mfma_f32_16x16x32_f16(
                    af[m], bfr[n], acc[m][n], 0, 0, 0);
        __syncthreads();
    }
    const int r00 = bm + wr * 64 + kg * 4;
    const int c00 = bn + wc * 64 + al;
#pragma unroll
    for (int m = 0; m < 4; ++m) {
        const int row0 = r00 + m * 16;                 // 4 consecutive t rows
        const int bi = row0 >> 14;
        const int chunk = (row0 >> 6) & 255;
        const int tc = row0 & 63;
#pragma unroll
        for (int n = 0; n < 4; ++n) {
            const int col = c00 + n * 16;
            const int h = col >> 7, v = col & 127;
            bf16* dst = VF + (size_t)((bi * 4 + h) * 256 + chunk) * 8192
                           + voff(v, tc);
            ushort4 pk;
            pk.x = f2bu(acc[m][n][0]); pk.y = f2bu(acc[m][n][1]);
            pk.z = f2bu(acc[m][n][2]); pk.w = f2bu(acc[m][n][3]);
            *(ushort4*)dst = pk;
        }
    }
}

// ---------------------------------------------------------------------------
// gk = log_sigmoid((x @ Wgk1) @ Wgk2 + bgk2) / 16 ; one block per row
// ---------------------------------------------------------------------------
template <typename GKT>
__global__ __launch_bounds__(256) void gate_k(
    const float* __restrict__ x, const float* __restrict__ Wgk1,
    const float* __restrict__ Wgk2, const float* __restrict__ bgk2,
    GKT* __restrict__ GK)
{
    __shared__ float xs[512];
    __shared__ float part[16][17];
    __shared__ float tl[16];
    const int row = blockIdx.x;
    const int tid = threadIdx.x;
    const float* xp = x + (size_t)row * 512;
    xs[tid] = xp[tid];
    xs[tid + 256] = xp[tid + 256];
    __syncthreads();
    const int j = tid & 15, seg = tid >> 4;
    float p = 0.f;
#pragma unroll
    for (int i = 0; i < 32; ++i) {
        const int c = seg * 32 + i;
        p = fmaf(xs[c], Wgk1[c * 16 + j], p);
    }
    part[seg][j] = p;
    __syncthreads();
    if (tid < 16) {
        float s = 0.f;
#pragma unroll
        for (int sg = 0; sg < 16; ++sg) s += part[sg][tid];
        tl[tid] = s;
    }
    __syncthreads();
    float z = bgk2[tid];
#pragma unroll
    for (int r = 0; r < 16; ++r)
        z = fmaf(tl[r], Wgk2[r * 256 + tid], z);
    const float ls = fminf(z, 0.f) - log1pf(expf(-fabsf(z)));
    stf(&GK[(size_t)row * 256 + tid], ls * (1.f / 16.f));
}

// ---------------------------------------------------------------------------
// Per-chunk local state via MFMA: CS[blk][v*64+k] = S^T[v][k]
//   = sum_t V[t][v] * (k_t[k] e^{d63[k]-g_t[k]}) ; DD[blk][k] = e^{d63[k]}.
// V fragments read coalesced from fragment-major Vf; k2^T built in LDS.
// ---------------------------------------------------------------------------
template <typename GKT, typename CST>
__global__ __launch_bounds__(256) void chunk_state_k(
    const bf16* __restrict__ Km, const bf16* __restrict__ VF,
    const GKT* __restrict__ GKm, CST* __restrict__ CS,
    float* __restrict__ DD)
{
    __shared__ __align__(16) short k2t[64][72];   // [k][t] bf16
    __shared__ float cpart[4][64];
    const int blk = blockIdx.x;
    const int chunk = blk & 255;
    const int bh = blk >> 8;
    const int bi = bh >> 2, h = bh & 3;
    const int rowbase = bi * 16384 + chunk * 64;
    const int tid = threadIdx.x;
    const int k = tid & 63, tg = tid >> 6;

    float g[16];
    {
        float run = 0.f;
#pragma unroll
        for (int j = 0; j < 16; ++j) {
            run += ldf(&GKm[(size_t)(rowbase + tg * 16 + j) * 256 + h * 64 + k]);
            g[j] = run;
        }
        cpart[tg][k] = run;
    }
    __syncthreads();
    float off = 0.f;
#pragma unroll
    for (int s = 0; s < 3; ++s) if (s < tg) off += cpart[s][k];
    const float tot = cpart[0][k] + cpart[1][k] + cpart[2][k] + cpart[3][k];
    if (tg == 0) DD[(size_t)blk * 64 + k] = __expf(tot);

    {
        short8 p0, p1;
#pragma unroll
        for (int j = 0; j < 16; ++j) {
            const float kv = ldf(&Km[(size_t)(rowbase + tg * 16 + j) * 256 + h * 64 + k]);
            const float w = kv * __expf(tot - (g[j] + off));   // decay <= 1
            if (j < 8) p0[j] = f2bs(w); else p1[j - 8] = f2bs(w);
        }
        *(short8*)&k2t[k][tg * 16] = p0;
        *(short8*)&k2t[k][tg * 16 + 8] = p1;
    }
    __syncthreads();

    const int lane = tid & 63, wid = tid >> 6;
    const int al = lane & 15, kg = lane >> 4, kg8 = kg * 8;
    const bf16* Vtb = VF + (size_t)blk * 8192;

    short8 xf[2][2];   // [m: v-rowblock][kstep]; coalesced 1KB/wave loads
#pragma unroll
    for (int m = 0; m < 2; ++m)
#pragma unroll
        for (int ks = 0; ks < 2; ++ks)
            xf[m][ks] = *(const short8*)&Vtb[(size_t)(((wid * 2 + m) * 2 + ks) * 64 + lane) * 8];
    short8 yf[2][4];   // [kstep][n: k-colblock]
#pragma unroll
    for (int ks = 0; ks < 2; ++ks)
#pragma unroll
        for (int n = 0; n < 4; ++n)
            yf[ks][n] = *(const short8*)&k2t[n * 16 + al][ks * 32 + kg8];

    f32x4 acc[2][4];
#pragma unroll
    for (int m = 0; m < 2; ++m)
#pragma unroll
        for (int n = 0; n < 4; ++n)
#pragma unroll
            for (int r = 0; r < 4; ++r) acc[m][n][r] = 0.f;
#pragma unroll
    for (int ks = 0; ks < 2; ++ks)
#pragma unroll
        for (int m = 0; m < 2; ++m)
#pragma unroll
            for (int n = 0; n < 4; ++n)
                acc[m][n] = mfma_bf(xf[m][ks], yf[ks][n], acc[m][n]);

    CST* out = CS + (size_t)blk * 8192;
#pragma unroll
    for (int m = 0; m < 2; ++m)
#pragma unroll
        for (int n = 0; n < 4; ++n)
#pragma unroll
            for (int r = 0; r < 4; ++r)
                stf(&out[(size_t)(wid * 32 + m * 16 + kg * 4 + r) * 64 + n * 16 + al],
                    acc[m][n][r]);
}

// ---------------------------------------------------------------------------
// Affine scan over chunks: H_{n+1}=D_n H_n+S_n. Reads S from CS (kept),
// writes pre-chunk state H_n to Hf in bf16 FRAGMENT-MAJOR layout.
// ---------------------------------------------------------------------------
template <typename CST>
__global__ __launch_bounds__(256) void scan_k(
    const CST* __restrict__ CS, const float* __restrict__ DD,
    bf16* __restrict__ HF)
{
    const int bh = blockIdx.x >> 5;
    const int slice = blockIdx.x & 31;
    const int tid = threadIdx.x;
    const int e = slice * 256 + tid;
    const int v = e >> 6, k = e & 63;
    float H = 0.f;
    const CST* base = CS + (size_t)bh * 256 * 8192 + e;
    bf16* hbase = HF + (size_t)bh * 256 * 8192 + voff(v, k);
    const float* dbase = DD + (size_t)bh * 256 * 64 + k;
#pragma unroll 4
    for (int n = 0; n < 256; ++n) {
        const float s = ldf(&base[(size_t)n * 8192]);
        const float d = dbase[(size_t)n * 64];
        stf(&hbase[(size_t)n * 8192], H);
        H = fmaf(d, H, s);
    }
}

// ---------------------------------------------------------------------------
// Per-chunk output via MFMA + fused LayerNorm * precomputed silu(g).
//   A = causal(qs @ ks^T); O = A @ V + qs @ H^T; GO = LN(O)*GO.
// V/H fragments: coalesced 1KB/wave loads from fragment-major global.
// ---------------------------------------------------------------------------
template <typename GKT>
__global__ __launch_bounds__(256) void chunk_out_k(
    const bf16* __restrict__ Qm, const bf16* __restrict__ Km,
    const bf16* __restrict__ VF, const GKT* __restrict__ GKm,
    const bf16* __restrict__ HF, bf16* GO)
{
    __shared__ __align__(16) short qs[64][72];   // q*e^g   (bf16)
    __shared__ __align__(16) short ks[64][72];   // k*e^-g  (bf16)
    __shared__ __align__(16) short ab[64][72];   // causal A (bf16)
    __shared__ float cpart[4][64];

    const int blk = blockIdx.x;
    const int chunk = blk & 255;
    const int bh = blk >> 8;
    const int bi = bh >> 2, h = bh & 3;
    const int rowbase = bi * 16384 + chunk * 64;
    const int tid = threadIdx.x;
    const int k = tid & 63, tg = tid >> 6;

    float g[16];
    {
        float run = 0.f;
#pragma unroll
        for (int j = 0; j < 16; ++j) {
            run += ldf(&GKm[(size_t)(rowbase + tg * 16 + j) * 256 + h * 64 + k]);
            g[j] = run;
        }
        cpart[tg][k] = run;
    }
    __syncthreads();
    float off = 0.f;
#pragma unroll
    for (int s = 0; s < 3; ++s) if (s < tg) off += cpart[s][k];

#pragma unroll
    for (int j = 0; j < 16; ++j) {
        const int t = tg * 16 + j;
        const size_t idx = (size_t)(rowbase + t) * 256 + h * 64 + k;
        const float gc = g[j] + off;
        const float eg = __expf(gc);
        qs[t][k] = f2bs(ldf(&Qm[idx]) * eg);
        ks[t][k] = f2bs(ldf(&Km[idx]) * fast_rcp(eg));
    }
    __syncthreads();

    const int lane = tid & 63, wid = tid >> 6;
    const int al = lane & 15, kg = lane >> 4;
    const int w16 = wid * 16, kg8 = kg * 8;

    short8 xq[2];
    xq[0] = *(const short8*)&qs[w16 + al][kg8];
    xq[1] = *(const short8*)&qs[w16 + al][32 + kg8];

    // A = qs @ ks^T for this wave's 16 t-rows
    f32x4 aacc[4];
#pragma unroll
    for (int n = 0; n < 4; ++n)
#pragma unroll
        for (int r = 0; r < 4; ++r) aacc[n][r] = 0.f;
#pragma unroll
    for (int ksb = 0; ksb < 2; ++ksb)
#pragma unroll
        for (int n = 0; n < 4; ++n) {
            const short8 y = *(const short8*)&ks[n * 16 + al][ksb * 32 + kg8];
            aacc[n] = mfma_bf(xq[ksb], y, aacc[n]);
        }
#pragma unroll
    for (int n = 0; n < 4; ++n)
#pragma unroll
        for (int r = 0; r < 4; ++r) {
            const int tt = w16 + kg * 4 + r;
            const int ii = n * 16 + al;
            ab[tt][ii] = (ii <= tt) ? f2bs(aacc[n][r]) : (short)0;
        }
    short8 xa[2];
    xa[0] = *(const short8*)&ab[w16 + al][kg8];
    xa[1] = *(const short8*)&ab[w16 + al][32 + kg8];

    // O = A @ V + qs @ H^T  (coalesced fragment-major global loads)
    const bf16* Vtb = VF + (size_t)blk * 8192;
    const bf16* Hb = HF + (size_t)blk * 8192;
    f32x4 oacc[8];
#pragma unroll
    for (int n = 0; n < 8; ++n)
#pragma unroll
        for (int r = 0; r < 4; ++r) oacc[n][r] = 0.f;
#pragma unroll
    for (int n = 0; n < 8; ++n) {
        const size_t f0 = (size_t)((n * 2 + 0) * 64 + lane) * 8;
        const size_t f1 = (size_t)((n * 2 + 1) * 64 + lane) * 8;
        const short8 yv0 = *(const short8*)&Vtb[f0];
        const short8 yv1 = *(const short8*)&Vtb[f1];
        const short8 yh0 = *(const short8*)&Hb[f0];
        const short8 yh1 = *(const short8*)&Hb[f1];
        oacc[n] = mfma_bf(xa[0], yv0, oacc[n]);
        oacc[n] = mfma_bf(xa[1], yv1, oacc[n]);
        oacc[n] = mfma_bf(xq[0], yh0, oacc[n]);
        oacc[n] = mfma_bf(xq[1], yh1, oacc[n]);
    }

    // fused LayerNorm over v=128 (reduce across the 16 'al' lanes) * silu(g)
    float psum[4] = {0.f, 0.f, 0.f, 0.f}, psq[4] = {0.f, 0.f, 0.f, 0.f};
#pragma unroll
    for (int n = 0; n < 8; ++n)
#pragma unroll
        for (int r = 0; r < 4; ++r) {
            const float v = oacc[n][r];
            psum[r] += v; psq[r] = fmaf(v, v, psq[r]);
        }
#pragma unroll
    for (int offx = 1; offx < 16; offx <<= 1)
#pragma unroll
        for (int r = 0; r < 4; ++r) {
            psum[r] += __shfl_xor(psum[r], offx);
            psq[r] += __shfl_xor(psq[r], offx);
        }
#pragma unroll
    for (int r = 0; r < 4; ++r) {
        const float mu = psum[r] * (1.f / 128.f);
        const float var = psq[r] * (1.f / 128.f) - mu * mu;
        const float rstd = rsqrtf(fmaxf(var, 0.f) + 1e-5f);
        const int row = rowbase + w16 + kg * 4 + r;
        bf16* gop = GO + (size_t)row * 512 + h * 128 + al;
#pragma unroll
        for (int n = 0; n < 8; ++n) {
            const float sil = b2f(gop[n * 16]);          // silu(g), precomputed
            gop[n * 16] = f2b((oacc[n][r] - mu) * rstd * sil);
        }
    }
}

__global__ __launch_bounds__(256) void zero_k(float* out, int n) {
    const int i = blockIdx.x * 256 + threadIdx.x;
    if (i < n) out[i] = 0.f;
}

// ---------------------------------------------------------------------------
template <typename GKT, typename CST>
static void run_all(const float* x, const float* Wq, const float* Wk,
                    const float* Wv, const float* Wg, const float* Wgk1,
                    const float* Wgk2, const float* bgk2, const float* Wo,
                    float* out, char* ws, hipStream_t stream)
{
    const int M = 32768;  // B*S
    auto aln = [](size_t v) { return (v + 255) & ~(size_t)255; };
    char* cur = ws;
    bf16* Qb = (bf16*)cur;  cur += aln((size_t)M * 256 * 2);
    bf16* Kb = (bf16*)cur;  cur += aln((size_t)M * 256 * 2);
    bf16* Vfb = (bf16*)cur; cur += aln((size_t)M * 512 * 2);   // fragment-major V
    bf16* GOb = (bf16*)cur; cur += aln((size_t)M * 512 * 2);   // silu(g), then OL
    bf16* Hfb = (bf16*)cur; cur += aln((size_t)2048 * 8192 * 2); // fragment-major H
    float* DDb = (float*)cur; cur += aln((size_t)2048 * 64 * 4);
    GKT* GKb = (GKT*)cur;   cur += aln((size_t)M * 256 * sizeof(GKT));
    CST* CSb = (CST*)cur;
    f16* xh = (f16*)CSb;    // aliases CS: dead until chunk_state_k writes it

    const dim3 blk(256);
    cvt_xh_k<<<dim3(8192), blk, 0, stream>>>(x, xh);
    gemm_mfma_k<f16, bf16, false><<<dim3(M / 128, 2), blk, 0, stream>>>(xh, Wq, Qb, M, 256, 512, 0.125f);
    gemm_mfma_k<f16, bf16, false><<<dim3(M / 128, 2), blk, 0, stream>>>(xh, Wk, Kb, M, 256, 512, 1.f);
    gemm_vt_k<<<dim3(M / 128, 4), blk, 0, stream>>>(xh, Wv, Vfb, M, 512, 512);
    gemm_mfma_k<f16, bf16, true><<<dim3(M / 128, 4), blk, 0, stream>>>(xh, Wg, GOb, M, 512, 512, 1.f);
    gate_k<<<dim3(M), blk, 0, stream>>>(x, Wgk1, Wgk2, bgk2, GKb);
    chunk_state_k<<<dim3(2048), blk, 0, stream>>>(Kb, Vfb, GKb, CSb, DDb);
    scan_k<<<dim3(256), blk, 0, stream>>>(CSb, DDb, Hfb);
    chunk_out_k<<<dim3(2048), blk, 0, stream>>>(Qb, Kb, Vfb, GKb, Hfb, GOb);
    gemm_mfma_k<bf16, float, false><<<dim3(M / 128, 4), blk, 0, stream>>>(GOb, Wo, out, M, 512, 512, 1.f);
}

extern "C" void kernel_launch(void* const* d_in, const int* in_sizes, int n_in,
                              void* d_out, int out_size, void* d_ws, size_t ws_size,
                              hipStream_t stream)
{
    const float* x    = (const float*)d_in[0];
    const float* Wq   = (const float*)d_in[1];
    const float* Wk   = (const float*)d_in[2];
    const float* Wv   = (const float*)d_in[3];
    const float* Wg   = (const float*)d_in[4];
    const float* Wgk1 = (const float*)d_in[5];
    const float* Wgk2 = (const float*)d_in[6];
    const float* bgk2 = (const float*)d_in[7];
    const float* Wo   = (const float*)d_in[8];
    float* out = (float*)d_out;

    const size_t M = 32768;
    const size_t slack = 8192;
    // fixed: Q,K (bf16) + Vf + GO + Hf + DD
    const size_t base = 2 * M * 256 * 2 + 2 * M * 512 * 2
                      + (size_t)2048 * 8192 * 2 + 2048 * 64 * 4 + slack;
    const size_t gk_f = M * 256 * 4, gk_b = M * 256 * 2;
    const size_t cs_f = (size_t)2048 * 8192 * 4, cs_b = (size_t)2048 * 8192 * 2;
    const size_t needA = base + gk_f + cs_f;   // ~235 MB
    const size_t needB = base + gk_b + cs_b;   // ~185 MB

    if (ws_size >= needA) {
        run_all<float, float>(x, Wq, Wk, Wv, Wg, Wgk1, Wgk2, bgk2, Wo,
                              out, (char*)d_ws, stream);
    } else if (ws_size >= needB) {
        run_all<bf16, bf16>(x, Wq, Wk, Wv, Wg, Wgk1, Wgk2, bgk2, Wo,
                            out, (char*)d_ws, stream);
    } else {
        zero_k<<<dim3((out_size + 255) / 256), dim3(256), 0, stream>>>(out, out_size);
    }
}

// Round 6
// 469.449 us; speedup vs baseline: 2.8822x; 1.1413x over previous
//
#include <hip/hip_runtime.h>
#include <hip/hip_bf16.h>

// GLA forward for MI355X. Inputs fp32, OUTPUT fp32. Pipeline:
//  0) cvt_xh_k: x (fp32) -> xh (f16) once; xh aliases CS workspace.
//  1) gemm_mfma_k: q,k -> bf16; g -> bf16 with fused silu epilogue
//     gemm_vt_k:   v projection -> FRAGMENT-MAJOR Vf[blk][frag][lane][8] bf16
//  2) gate_mfma_k: gk = log_sigmoid((xh@Wgk1)@Wgk2 + b)/16 ; stage-1 on MFMA
//     (f16, N=16), stage-2 column-owned VALU with coalesced Wgk2 reads.
//  3) chunk_state_k: per-(b,h,chunk=64) local state S^T[v][k] (fp32/CST) + D
//  4) scan_k: affine scan over chunks; writes chunk-start states H_n to Hf
//     (bf16, FRAGMENT-MAJOR) -- CS keeps S, no in-place rewrite
//  5) chunk_out_k: o = q*e^B @ H + causal intra attention @ V (bf16 MFMA),
//     fused per-head LayerNorm * precomputed silu(g) -> OL (bf16)
//  6) gemm_mfma_k: out = OL @ Wo (fp32 to d_out)
// Fragment-major layout for a [v][t] (128x64) bf16 matrix consumed as MFMA
// B/A operands: off(v,t) = frag*512 + lane*8 + elem -> per-wave fragment load
// is one contiguous 1KB transaction. Same convention on both MFMA operands
// => contraction exact regardless of HW k-ordering.

typedef __hip_bfloat16 bf16;
typedef _Float16 f16;
typedef _Float16 half8 __attribute__((ext_vector_type(8)));
typedef _Float16 half4 __attribute__((ext_vector_type(4)));
typedef float f32x4 __attribute__((ext_vector_type(4)));
typedef short short8 __attribute__((ext_vector_type(8)));

#define DEV static __device__ __forceinline__

DEV float b2f(bf16 v) { return __bfloat162float(v); }
DEV bf16 f2b(float v) { return __float2bfloat16(v); }
DEV float bits2f(unsigned int u16) {
    union { unsigned int u; float f; } c; c.u = u16 << 16; return c.f;
}
DEV short f2bs(float v) {
    union { bf16 h; short s; } u; u.h = __float2bfloat16(v); return u.s;
}
DEV unsigned short f2bu(float v) {
    union { bf16 h; unsigned short s; } u; u.h = __float2bfloat16(v); return u.s;
}
DEV float fast_rcp(float v) { return __builtin_amdgcn_rcpf(v); }

DEV float ldf(const float* p) { return *p; }
DEV float ldf(const bf16* p) { return b2f(*p); }
DEV void stf(float* p, float v) { *p = v; }
DEV void stf(bf16* p, float v) { *p = f2b(v); }

DEV float4 ld4(const float* p) { return *(const float4*)p; }
DEV float4 ld4(const bf16* p) {
    const uint2 r = *(const uint2*)p;
    return make_float4(bits2f(r.x & 0xffffu), bits2f(r.x >> 16),
                       bits2f(r.y & 0xffffu), bits2f(r.y >> 16));
}

DEV half8 ld8h(const float* p) {
    const float4 a = *(const float4*)p, b = *(const float4*)(p + 4);
    half8 h;
    h[0] = (f16)a.x; h[1] = (f16)a.y; h[2] = (f16)a.z; h[3] = (f16)a.w;
    h[4] = (f16)b.x; h[5] = (f16)b.y; h[6] = (f16)b.z; h[7] = (f16)b.w;
    return h;
}
DEV half8 ld8h(const f16* p) { return *(const half8*)p; }
DEV half8 ld8h(const bf16* p) {           // bf16 -> f16 (exact for |v|<2^15)
    const float4 a = ld4(p), b = ld4(p + 4);
    half8 h;
    h[0] = (f16)a.x; h[1] = (f16)a.y; h[2] = (f16)a.z; h[3] = (f16)a.w;
    h[4] = (f16)b.x; h[5] = (f16)b.y; h[6] = (f16)b.z; h[7] = (f16)b.w;
    return h;
}

DEV f32x4 mfma_bf(short8 a, short8 b, f32x4 c) {
    return __builtin_amdgcn_mfma_f32_16x16x32_bf16(a, b, c, 0, 0, 0);
}

// fragment-major offset for a 128x64 [v][t] operand matrix
DEV size_t voff(int v, int t) {
    return (size_t)(((((v >> 4) * 2 + (t >> 5)) * 4 + ((t >> 3) & 3)) * 16
                     + (v & 15)) * 8 + (t & 7));
}

// ---------------------------------------------------------------------------
// x (fp32) -> xh (f16), 8 elems/thread
// ---------------------------------------------------------------------------
__global__ __launch_bounds__(256) void cvt_xh_k(
    const float* __restrict__ x, f16* __restrict__ xh)
{
    const size_t i = ((size_t)blockIdx.x * 256 + threadIdx.x) * 8;
    *(half8*)&xh[i] = ld8h(&x[i]);
}

// ---------------------------------------------------------------------------
// MFMA GEMM (f16 operands): C[M,N] = scale * A[M,K] @ B[K,N].
// 256 thr = 4 waves (2x2), tile 128x128, BK=32, 4x4 16x16 frags/wave.
// D: col=lane&15, row=4*(lane>>4)+reg (HW-verified). Optional silu epilogue.
// ---------------------------------------------------------------------------
template <typename AT, typename OutT, bool SILU>
__global__ __launch_bounds__(256) void gemm_mfma_k(
    const AT* __restrict__ A, const float* __restrict__ B,
    OutT* __restrict__ C, int M, int N, int K, float scale)
{
    __shared__ __align__(16) f16 As[128][40];
    __shared__ __align__(16) f16 Bs[128][40];
    const int bm = blockIdx.x * 128;
    const int bn = blockIdx.y * 128;
    const int tid = threadIdx.x;
    const int lane = tid & 63;
    const int wid = tid >> 6;
    const int wr = wid >> 1, wc = wid & 1;
    const int al = lane & 15;
    const int kg = lane >> 4;

    f32x4 acc[4][4];
#pragma unroll
    for (int m = 0; m < 4; ++m)
#pragma unroll
        for (int n = 0; n < 4; ++n)
#pragma unroll
            for (int r = 0; r < 4; ++r) acc[m][n][r] = 0.f;

    const int ar = tid >> 1;
    const int ac = (tid & 1) * 16;
    const int bkg = tid >> 5;
    const int bcg = tid & 31;

    for (int k0 = 0; k0 < K; k0 += 32) {
        {
            const AT* ap = A + (size_t)(bm + ar) * K + k0 + ac;
            *(half8*)&As[ar][ac] = ld8h(ap);
            *(half8*)&As[ar][ac + 8] = ld8h(ap + 8);
        }
        {
            const float* bp = B + (size_t)(k0 + bkg * 4) * N + bn + bcg * 4;
            const float4 r0 = ld4(bp);
            const float4 r1 = ld4(bp + N);
            const float4 r2 = ld4(bp + 2 * N);
            const float4 r3 = ld4(bp + 3 * N);
            half4 c0, c1, c2, c3;
            c0[0] = (f16)r0.x; c0[1] = (f16)r1.x; c0[2] = (f16)r2.x; c0[3] = (f16)r3.x;
            c1[0] = (f16)r0.y; c1[1] = (f16)r1.y; c1[2] = (f16)r2.y; c1[3] = (f16)r3.y;
            c2[0] = (f16)r0.z; c2[1] = (f16)r1.z; c2[2] = (f16)r2.z; c2[3] = (f16)r3.z;
            c3[0] = (f16)r0.w; c3[1] = (f16)r1.w; c3[2] = (f16)r2.w; c3[3] = (f16)r3.w;
            *(half4*)&Bs[bcg * 4 + 0][bkg * 4] = c0;
            *(half4*)&Bs[bcg * 4 + 1][bkg * 4] = c1;
            *(half4*)&Bs[bcg * 4 + 2][bkg * 4] = c2;
            *(half4*)&Bs[bcg * 4 + 3][bkg * 4] = c3;
        }
        __syncthreads();
        half8 af[4], bfr[4];
#pragma unroll
        for (int m = 0; m < 4; ++m)
            af[m] = *(const half8*)&As[wr * 64 + m * 16 + al][kg * 8];
#pragma unroll
        for (int n = 0; n < 4; ++n)
            bfr[n] = *(const half8*)&Bs[wc * 64 + n * 16 + al][kg * 8];
#pragma unroll
        for (int m = 0; m < 4; ++m)
#pragma unroll
            for (int n = 0; n < 4; ++n)
                acc[m][n] = __builtin_amdgcn_mfma_f32_16x16x32_f16(
                    af[m], bfr[n], acc[m][n], 0, 0, 0);
        __syncthreads();
    }
    const int r0 = bm + wr * 64 + kg * 4;
    const int c0 = bn + wc * 64 + al;
#pragma unroll
    for (int m = 0; m < 4; ++m)
#pragma unroll
        for (int n = 0; n < 4; ++n)
#pragma unroll
            for (int r = 0; r < 4; ++r) {
                float v = acc[m][n][r] * scale;
                if (SILU) v = v * fast_rcp(1.f + __expf(-v));
                stf(&C[(size_t)(r0 + m * 16 + r) * N + c0 + n * 16], v);
            }
}

// ---------------------------------------------------------------------------
// V projection, stored fragment-major per (bh,chunk) block: Vf[blk*8192 +
// voff(v,t)]. 4 consecutive t at fixed v = 4 contiguous elems -> 8B store.
// ---------------------------------------------------------------------------
__global__ __launch_bounds__(256) void gemm_vt_k(
    const f16* __restrict__ A, const float* __restrict__ B,
    bf16* __restrict__ VF, int M, int N, int K)
{
    __shared__ __align__(16) f16 As[128][40];
    __shared__ __align__(16) f16 Bs[128][40];
    const int bm = blockIdx.x * 128;
    const int bn = blockIdx.y * 128;
    const int tid = threadIdx.x;
    const int lane = tid & 63;
    const int wid = tid >> 6;
    const int wr = wid >> 1, wc = wid & 1;
    const int al = lane & 15;
    const int kg = lane >> 4;

    f32x4 acc[4][4];
#pragma unroll
    for (int m = 0; m < 4; ++m)
#pragma unroll
        for (int n = 0; n < 4; ++n)
#pragma unroll
            for (int r = 0; r < 4; ++r) acc[m][n][r] = 0.f;

    const int ar = tid >> 1;
    const int ac = (tid & 1) * 16;
    const int bkg = tid >> 5;
    const int bcg = tid & 31;

    for (int k0 = 0; k0 < K; k0 += 32) {
        {
            const f16* ap = A + (size_t)(bm + ar) * K + k0 + ac;
            *(half8*)&As[ar][ac] = ld8h(ap);
            *(half8*)&As[ar][ac + 8] = ld8h(ap + 8);
        }
        {
            const float* bp = B + (size_t)(k0 + bkg * 4) * N + bn + bcg * 4;
            const float4 r0 = ld4(bp);
            const float4 r1 = ld4(bp + N);
            const float4 r2 = ld4(bp + 2 * N);
            const float4 r3 = ld4(bp + 3 * N);
            half4 c0, c1, c2, c3;
            c0[0] = (f16)r0.x; c0[1] = (f16)r1.x; c0[2] = (f16)r2.x; c0[3] = (f16)r3.x;
            c1[0] = (f16)r0.y; c1[1] = (f16)r1.y; c1[2] = (f16)r2.y; c1[3] = (f16)r3.y;
            c2[0] = (f16)r0.z; c2[1] = (f16)r1.z; c2[2] = (f16)r2.z; c2[3] = (f16)r3.z;
            c3[0] = (f16)r0.w; c3[1] = (f16)r1.w; c3[2] = (f16)r2.w; c3[3] = (f16)r3.w;
            *(half4*)&Bs[bcg * 4 + 0][bkg * 4] = c0;
            *(half4*)&Bs[bcg * 4 + 1][bkg * 4] = c1;
            *(half4*)&Bs[bcg * 4 + 2][bkg * 4] = c2;
            *(half4*)&Bs[bcg * 4 + 3][bkg * 4] = c3;
        }
        __syncthreads();
        half8 af[4], bfr[4];
#pragma unroll
        for (int m = 0; m < 4; ++m)
            af[m] = *(const half8*)&As[wr * 64 + m * 16 + al][kg * 8];
#pragma unroll
        for (int n = 0; n < 4; ++n)
            bfr[n] = *(const half8*)&Bs[wc * 64 + n * 16 + al][kg * 8];
#pragma unroll
        for (int m = 0; m < 4; ++m)
#pragma unroll
            for (int n = 0; n < 4; ++n)
                acc[m][n] = __builtin_amdgcn_mfma_f32_16x16x32_f16(
                    af[m], bfr[n], acc[m][n], 0, 0, 0);
        __syncthreads();
    }
    const int r00 = bm + wr * 64 + kg * 4;
    const int c00 = bn + wc * 64 + al;
#pragma unroll
    for (int m = 0; m < 4; ++m) {
        const int row0 = r00 + m * 16;                 // 4 consecutive t rows
        const int bi = row0 >> 14;
        const int chunk = (row0 >> 6) & 255;
        const int tc = row0 & 63;
#pragma unroll
        for (int n = 0; n < 4; ++n) {
            const int col = c00 + n * 16;
            const int h = col >> 7, v = col & 127;
            bf16* dst = VF + (size_t)((bi * 4 + h) * 256 + chunk) * 8192
                           + voff(v, tc);
            ushort4 pk;
            pk.x = f2bu(acc[m][n][0]); pk.y = f2bu(acc[m][n][1]);
            pk.z = f2bu(acc[m][n][2]); pk.w = f2bu(acc[m][n][3]);
            *(ushort4*)dst = pk;
        }
    }
}

// ---------------------------------------------------------------------------
// gate: gk = log_sigmoid((xh @ Wgk1) @ Wgk2 + bgk2) / 16
// Block = 128 rows. Stage 1 (K=512, N=16) on f16 MFMA, Wgk1 in LDS [n][k].
// Stage 2 (K=16, N=256): thread owns column c=tid; Wgk2 reads coalesced,
// tl broadcast from LDS; log-sigmoid via __expf/__logf.
// ---------------------------------------------------------------------------
template <typename GKT>
__global__ __launch_bounds__(256) void gate_mfma_k(
    const f16* __restrict__ xh, const float* __restrict__ Wgk1,
    const float* __restrict__ Wgk2, const float* __restrict__ bgk2,
    GKT* __restrict__ GK)
{
    __shared__ __align__(16) f16 As[128][40];
    __shared__ __align__(16) f16 w1s[16][520];   // Wgk1^T [n][k], padded
    __shared__ float tls[128][17];               // tl fp32
    const int bm = blockIdx.x * 128;
    const int tid = threadIdx.x;
    const int lane = tid & 63;
    const int wid = tid >> 6;
    const int al = lane & 15;
    const int kg = lane >> 4;
    const int kg8 = kg * 8;

    // Wgk1 [512][16] fp32 -> w1s[n][k] f16 (coalesced global reads)
    for (int e = tid; e < 8192; e += 256) {
        const int kk = e >> 4, n = e & 15;
        w1s[n][kk] = (f16)Wgk1[e];
    }

    f32x4 acc[2];
#pragma unroll
    for (int m = 0; m < 2; ++m)
#pragma unroll
        for (int r = 0; r < 4; ++r) acc[m][r] = 0.f;

    const int ar = tid >> 1;
    const int ac = (tid & 1) * 16;
    for (int k0 = 0; k0 < 512; k0 += 32) {
        {
            const f16* ap = xh + (size_t)(bm + ar) * 512 + k0 + ac;
            *(half8*)&As[ar][ac] = ld8h(ap);
            *(half8*)&As[ar][ac + 8] = ld8h(ap + 8);
        }
        __syncthreads();
        const half8 bfr = *(const half8*)&w1s[al][k0 + kg8];
#pragma unroll
        for (int m = 0; m < 2; ++m) {
            const half8 af = *(const half8*)&As[wid * 32 + m * 16 + al][kg8];
            acc[m] = __builtin_amdgcn_mfma_f32_16x16x32_f16(af, bfr, acc[m], 0, 0, 0);
        }
        __syncthreads();
    }
    // D-layout: col(al)=gate dim, row=kg*4+r -> tls[row][gatedim]
#pragma unroll
    for (int m = 0; m < 2; ++m)
#pragma unroll
        for (int r = 0; r < 4; ++r)
            tls[wid * 32 + m * 16 + kg * 4 + r][al] = acc[m][r];
    __syncthreads();

    // stage 2: thread owns output column c = tid
    float w2[16];
#pragma unroll
    for (int r = 0; r < 16; ++r) w2[r] = Wgk2[r * 256 + tid];
    const float bb = bgk2[tid];
    GKT* gout = GK + (size_t)bm * 256 + tid;
    for (int m = 0; m < 128; ++m) {
        float z = bb;
#pragma unroll
        for (int r = 0; r < 16; ++r) z = fmaf(tls[m][r], w2[r], z);
        const float ls = fminf(z, 0.f) - __logf(1.f + __expf(-fabsf(z)));
        stf(&gout[(size_t)m * 256], ls * (1.f / 16.f));
    }
}

// ---------------------------------------------------------------------------
// Per-chunk local state via MFMA: CS[blk][v*64+k] = S^T[v][k]
//   = sum_t V[t][v] * (k_t[k] e^{d63[k]-g_t[k]}) ; DD[blk][k] = e^{d63[k]}.
// V fragments read coalesced from fragment-major Vf; k2^T built in LDS.
// ---------------------------------------------------------------------------
template <typename GKT, typename CST>
__global__ __launch_bounds__(256) void chunk_state_k(
    const bf16* __restrict__ Km, const bf16* __restrict__ VF,
    const GKT* __restrict__ GKm, CST* __restrict__ CS,
    float* __restrict__ DD)
{
    __shared__ __align__(16) short k2t[64][72];   // [k][t] bf16
    __shared__ float cpart[4][64];
    const int blk = blockIdx.x;
    const int chunk = blk & 255;
    const int bh = blk >> 8;
    const int bi = bh >> 2, h = bh & 3;
    const int rowbase = bi * 16384 + chunk * 64;
    const int tid = threadIdx.x;
    const int k = tid & 63, tg = tid >> 6;

    float g[16];
    {
        float run = 0.f;
#pragma unroll
        for (int j = 0; j < 16; ++j) {
            run += ldf(&GKm[(size_t)(rowbase + tg * 16 + j) * 256 + h * 64 + k]);
            g[j] = run;
        }
        cpart[tg][k] = run;
    }
    __syncthreads();
    float off = 0.f;
#pragma unroll
    for (int s = 0; s < 3; ++s) if (s < tg) off += cpart[s][k];
    const float tot = cpart[0][k] + cpart[1][k] + cpart[2][k] + cpart[3][k];
    if (tg == 0) DD[(size_t)blk * 64 + k] = __expf(tot);

    {
        short8 p0, p1;
#pragma unroll
        for (int j = 0; j < 16; ++j) {
            const float kv = ldf(&Km[(size_t)(rowbase + tg * 16 + j) * 256 + h * 64 + k]);
            const float w = kv * __expf(tot - (g[j] + off));   // decay <= 1
            if (j < 8) p0[j] = f2bs(w); else p1[j - 8] = f2bs(w);
        }
        *(short8*)&k2t[k][tg * 16] = p0;
        *(short8*)&k2t[k][tg * 16 + 8] = p1;
    }
    __syncthreads();

    const int lane = tid & 63, wid = tid >> 6;
    const int al = lane & 15, kg = lane >> 4, kg8 = kg * 8;
    const bf16* Vtb = VF + (size_t)blk * 8192;

    short8 xf[2][2];   // [m: v-rowblock][kstep]; coalesced 1KB/wave loads
#pragma unroll
    for (int m = 0; m < 2; ++m)
#pragma unroll
        for (int ks = 0; ks < 2; ++ks)
            xf[m][ks] = *(const short8*)&Vtb[(size_t)(((wid * 2 + m) * 2 + ks) * 64 + lane) * 8];
    short8 yf[2][4];   // [kstep][n: k-colblock]
#pragma unroll
    for (int ks = 0; ks < 2; ++ks)
#pragma unroll
        for (int n = 0; n < 4; ++n)
            yf[ks][n] = *(const short8*)&k2t[n * 16 + al][ks * 32 + kg8];

    f32x4 acc[2][4];
#pragma unroll
    for (int m = 0; m < 2; ++m)
#pragma unroll
        for (int n = 0; n < 4; ++n)
#pragma unroll
            for (int r = 0; r < 4; ++r) acc[m][n][r] = 0.f;
#pragma unroll
    for (int ks = 0; ks < 2; ++ks)
#pragma unroll
        for (int m = 0; m < 2; ++m)
#pragma unroll
            for (int n = 0; n < 4; ++n)
                acc[m][n] = mfma_bf(xf[m][ks], yf[ks][n], acc[m][n]);

    CST* out = CS + (size_t)blk * 8192;
#pragma unroll
    for (int m = 0; m < 2; ++m)
#pragma unroll
        for (int n = 0; n < 4; ++n)
#pragma unroll
            for (int r = 0; r < 4; ++r)
                stf(&out[(size_t)(wid * 32 + m * 16 + kg * 4 + r) * 64 + n * 16 + al],
                    acc[m][n][r]);
}

// ---------------------------------------------------------------------------
// Affine scan over chunks: H_{n+1}=D_n H_n+S_n. Reads S from CS (kept),
// writes pre-chunk state H_n to Hf in bf16 FRAGMENT-MAJOR layout.
// ---------------------------------------------------------------------------
template <typename CST>
__global__ __launch_bounds__(256) void scan_k(
    const CST* __restrict__ CS, const float* __restrict__ DD,
    bf16* __restrict__ HF)
{
    const int bh = blockIdx.x >> 5;
    const int slice = blockIdx.x & 31;
    const int tid = threadIdx.x;
    const int e = slice * 256 + tid;
    const int v = e >> 6, k = e & 63;
    float H = 0.f;
    const CST* base = CS + (size_t)bh * 256 * 8192 + e;
    bf16* hbase = HF + (size_t)bh * 256 * 8192 + voff(v, k);
    const float* dbase = DD + (size_t)bh * 256 * 64 + k;
#pragma unroll 4
    for (int n = 0; n < 256; ++n) {
        const float s = ldf(&base[(size_t)n * 8192]);
        const float d = dbase[(size_t)n * 64];
        stf(&hbase[(size_t)n * 8192], H);
        H = fmaf(d, H, s);
    }
}

// ---------------------------------------------------------------------------
// Per-chunk output via MFMA + fused LayerNorm * precomputed silu(g).
//   A = causal(qs @ ks^T); O = A @ V + qs @ H^T; GO = LN(O)*GO.
// V/H fragments: coalesced 1KB/wave loads from fragment-major global.
// ---------------------------------------------------------------------------
template <typename GKT>
__global__ __launch_bounds__(256) void chunk_out_k(
    const bf16* __restrict__ Qm, const bf16* __restrict__ Km,
    const bf16* __restrict__ VF, const GKT* __restrict__ GKm,
    const bf16* __restrict__ HF, bf16* GO)
{
    __shared__ __align__(16) short qs[64][72];   // q*e^g   (bf16)
    __shared__ __align__(16) short ks[64][72];   // k*e^-g  (bf16)
    __shared__ __align__(16) short ab[64][72];   // causal A (bf16)
    __shared__ float cpart[4][64];

    const int blk = blockIdx.x;
    const int chunk = blk & 255;
    const int bh = blk >> 8;
    const int bi = bh >> 2, h = bh & 3;
    const int rowbase = bi * 16384 + chunk * 64;
    const int tid = threadIdx.x;
    const int k = tid & 63, tg = tid >> 6;

    float g[16];
    {
        float run = 0.f;
#pragma unroll
        for (int j = 0; j < 16; ++j) {
            run += ldf(&GKm[(size_t)(rowbase + tg * 16 + j) * 256 + h * 64 + k]);
            g[j] = run;
        }
        cpart[tg][k] = run;
    }
    __syncthreads();
    float off = 0.f;
#pragma unroll
    for (int s = 0; s < 3; ++s) if (s < tg) off += cpart[s][k];

#pragma unroll
    for (int j = 0; j < 16; ++j) {
        const int t = tg * 16 + j;
        const size_t idx = (size_t)(rowbase + t) * 256 + h * 64 + k;
        const float gc = g[j] + off;
        const float eg = __expf(gc);
        qs[t][k] = f2bs(ldf(&Qm[idx]) * eg);
        ks[t][k] = f2bs(ldf(&Km[idx]) * fast_rcp(eg));
    }
    __syncthreads();

    const int lane = tid & 63, wid = tid >> 6;
    const int al = lane & 15, kg = lane >> 4;
    const int w16 = wid * 16, kg8 = kg * 8;

    short8 xq[2];
    xq[0] = *(const short8*)&qs[w16 + al][kg8];
    xq[1] = *(const short8*)&qs[w16 + al][32 + kg8];

    // A = qs @ ks^T for this wave's 16 t-rows
    f32x4 aacc[4];
#pragma unroll
    for (int n = 0; n < 4; ++n)
#pragma unroll
        for (int r = 0; r < 4; ++r) aacc[n][r] = 0.f;
#pragma unroll
    for (int ksb = 0; ksb < 2; ++ksb)
#pragma unroll
        for (int n = 0; n < 4; ++n) {
            const short8 y = *(const short8*)&ks[n * 16 + al][ksb * 32 + kg8];
            aacc[n] = mfma_bf(xq[ksb], y, aacc[n]);
        }
#pragma unroll
    for (int n = 0; n < 4; ++n)
#pragma unroll
        for (int r = 0; r < 4; ++r) {
            const int tt = w16 + kg * 4 + r;
            const int ii = n * 16 + al;
            ab[tt][ii] = (ii <= tt) ? f2bs(aacc[n][r]) : (short)0;
        }
    short8 xa[2];
    xa[0] = *(const short8*)&ab[w16 + al][kg8];
    xa[1] = *(const short8*)&ab[w16 + al][32 + kg8];

    // O = A @ V + qs @ H^T  (coalesced fragment-major global loads)
    const bf16* Vtb = VF + (size_t)blk * 8192;
    const bf16* Hb = HF + (size_t)blk * 8192;
    f32x4 oacc[8];
#pragma unroll
    for (int n = 0; n < 8; ++n)
#pragma unroll
        for (int r = 0; r < 4; ++r) oacc[n][r] = 0.f;
#pragma unroll
    for (int n = 0; n < 8; ++n) {
        const size_t f0 = (size_t)((n * 2 + 0) * 64 + lane) * 8;
        const size_t f1 = (size_t)((n * 2 + 1) * 64 + lane) * 8;
        const short8 yv0 = *(const short8*)&Vtb[f0];
        const short8 yv1 = *(const short8*)&Vtb[f1];
        const short8 yh0 = *(const short8*)&Hb[f0];
        const short8 yh1 = *(const short8*)&Hb[f1];
        oacc[n] = mfma_bf(xa[0], yv0, oacc[n]);
        oacc[n] = mfma_bf(xa[1], yv1, oacc[n]);
        oacc[n] = mfma_bf(xq[0], yh0, oacc[n]);
        oacc[n] = mfma_bf(xq[1], yh1, oacc[n]);
    }

    // fused LayerNorm over v=128 (reduce across the 16 'al' lanes) * silu(g)
    float psum[4] = {0.f, 0.f, 0.f, 0.f}, psq[4] = {0.f, 0.f, 0.f, 0.f};
#pragma unroll
    for (int n = 0; n < 8; ++n)
#pragma unroll
        for (int r = 0; r < 4; ++r) {
            const float v = oacc[n][r];
            psum[r] += v; psq[r] = fmaf(v, v, psq[r]);
        }
#pragma unroll
    for (int offx = 1; offx < 16; offx <<= 1)
#pragma unroll
        for (int r = 0; r < 4; ++r) {
            psum[r] += __shfl_xor(psum[r], offx);
            psq[r] += __shfl_xor(psq[r], offx);
        }
#pragma unroll
    for (int r = 0; r < 4; ++r) {
        const float mu = psum[r] * (1.f / 128.f);
        const float var = psq[r] * (1.f / 128.f) - mu * mu;
        const float rstd = rsqrtf(fmaxf(var, 0.f) + 1e-5f);
        const int row = rowbase + w16 + kg * 4 + r;
        bf16* gop = GO + (size_t)row * 512 + h * 128 + al;
#pragma unroll
        for (int n = 0; n < 8; ++n) {
            const float sil = b2f(gop[n * 16]);          // silu(g), precomputed
            gop[n * 16] = f2b((oacc[n][r] - mu) * rstd * sil);
        }
    }
}

__global__ __launch_bounds__(256) void zero_k(float* out, int n) {
    const int i = blockIdx.x * 256 + threadIdx.x;
    if (i < n) out[i] = 0.f;
}

// ---------------------------------------------------------------------------
template <typename GKT, typename CST>
static void run_all(const float* x, const float* Wq, const float* Wk,
                    const float* Wv, const float* Wg, const float* Wgk1,
                    const float* Wgk2, const float* bgk2, const float* Wo,
                    float* out, char* ws, hipStream_t stream)
{
    const int M = 32768;  // B*S
    auto aln = [](size_t v) { return (v + 255) & ~(size_t)255; };
    char* cur = ws;
    bf16* Qb = (bf16*)cur;  cur += aln((size_t)M * 256 * 2);
    bf16* Kb = (bf16*)cur;  cur += aln((size_t)M * 256 * 2);
    bf16* Vfb = (bf16*)cur; cur += aln((size_t)M * 512 * 2);   // fragment-major V
    bf16* GOb = (bf16*)cur; cur += aln((size_t)M * 512 * 2);   // silu(g), then OL
    bf16* Hfb = (bf16*)cur; cur += aln((size_t)2048 * 8192 * 2); // fragment-major H
    float* DDb = (float*)cur; cur += aln((size_t)2048 * 64 * 4);
    GKT* GKb = (GKT*)cur;   cur += aln((size_t)M * 256 * sizeof(GKT));
    CST* CSb = (CST*)cur;
    f16* xh = (f16*)CSb;    // aliases CS: dead until chunk_state_k writes it

    const dim3 blk(256);
    cvt_xh_k<<<dim3(8192), blk, 0, stream>>>(x, xh);
    gemm_mfma_k<f16, bf16, false><<<dim3(M / 128, 2), blk, 0, stream>>>(xh, Wq, Qb, M, 256, 512, 0.125f);
    gemm_mfma_k<f16, bf16, false><<<dim3(M / 128, 2), blk, 0, stream>>>(xh, Wk, Kb, M, 256, 512, 1.f);
    gemm_vt_k<<<dim3(M / 128, 4), blk, 0, stream>>>(xh, Wv, Vfb, M, 512, 512);
    gemm_mfma_k<f16, bf16, true><<<dim3(M / 128, 4), blk, 0, stream>>>(xh, Wg, GOb, M, 512, 512, 1.f);
    gate_mfma_k<<<dim3(M / 128), blk, 0, stream>>>(xh, Wgk1, Wgk2, bgk2, GKb);
    chunk_state_k<<<dim3(2048), blk, 0, stream>>>(Kb, Vfb, GKb, CSb, DDb);
    scan_k<<<dim3(256), blk, 0, stream>>>(CSb, DDb, Hfb);
    chunk_out_k<<<dim3(2048), blk, 0, stream>>>(Qb, Kb, Vfb, GKb, Hfb, GOb);
    gemm_mfma_k<bf16, float, false><<<dim3(M / 128, 4), blk, 0, stream>>>(GOb, Wo, out, M, 512, 512, 1.f);
}

extern "C" void kernel_launch(void* const* d_in, const int* in_sizes, int n_in,
                              void* d_out, int out_size, void* d_ws, size_t ws_size,
                              hipStream_t stream)
{
    const float* x    = (const float*)d_in[0];
    const float* Wq   = (const float*)d_in[1];
    const float* Wk   = (const float*)d_in[2];
    const float* Wv   = (const float*)d_in[3];
    const float* Wg   = (const float*)d_in[4];
    const float* Wgk1 = (const float*)d_in[5];
    const float* Wgk2 = (const float*)d_in[6];
    const float* bgk2 = (const float*)d_in[7];
    const float* Wo   = (const float*)d_in[8];
    float* out = (float*)d_out;

    const size_t M = 32768;
    const size_t slack = 8192;
    // fixed: Q,K (bf16) + Vf + GO + Hf + DD
    const size_t base = 2 * M * 256 * 2 + 2 * M * 512 * 2
                      + (size_t)2048 * 8192 * 2 + 2048 * 64 * 4 + slack;
    const size_t gk_f = M * 256 * 4, gk_b = M * 256 * 2;
    const size_t cs_f = (size_t)2048 * 8192 * 4, cs_b = (size_t)2048 * 8192 * 2;
    const size_t needA = base + gk_f + cs_f;   // ~235 MB
    const size_t needB = base + gk_b + cs_b;   // ~185 MB

    if (ws_size >= needA) {
        run_all<float, float>(x, Wq, Wk, Wv, Wg, Wgk1, Wgk2, bgk2, Wo,
                              out, (char*)d_ws, stream);
    } else if (ws_size >= needB) {
        run_all<bf16, bf16>(x, Wq, Wk, Wv, Wg, Wgk1, Wgk2, bgk2, Wo,
                            out, (char*)d_ws, stream);
    } else {
        zero_k<<<dim3((out_size + 255) / 256), dim3(256), 0, stream>>>(out, out_size);
    }
}

// Round 7
// 389.420 us; speedup vs baseline: 3.4746x; 1.2055x over previous
//
#include <hip/hip_runtime.h>
#include <hip/hip_bf16.h>

// GLA forward for MI355X. Inputs fp32, OUTPUT fp32. Pipeline:
//  0) cvt_xh_k: x (fp32) -> xh (f16) once; xh aliases CS workspace.
//     cvt_wt_k: [Wq|Wk|Wv|Wg|Wo] fp32 [k][n] -> Wt f16 [n][k] (2048x512, 2MB)
//  1) proj_gemm_k: ONE GEMM M=32768 x N=1536 over Wt rows 0..1535 with
//     per-segment epilogue: Q(scale 1/8)->bf16, K->bf16,
//     V->FRAGMENT-MAJOR Vf, G->silu->bf16. B-staging = pure 16B copies
//     (no transpose -> no 16-way LDS write conflicts).
//  2) gate_mfma_k: gk = log_sigmoid((xh@Wgk1)@Wgk2 + b)/16 (stage-1 MFMA)
//  3) chunk_state_k: per-(b,h,chunk=64) local state S^T[v][k] (CST) + D
//  4) scan_k: affine scan over chunks -> chunk-start states H_n -> Hf
//     (bf16 FRAGMENT-MAJOR); CS keeps S
//  5) chunk_out_k: o = q*e^B @ H + causal intra attention @ V (bf16 MFMA),
//     fused per-head LayerNorm * precomputed silu(g) -> OL (bf16)
//  6) gemm_bt_k: out = OL @ Wo (Wt rows 1536..2047, fp32 out)
// Fragment-major layout for a [v][t] (128x64) bf16 matrix consumed as MFMA
// B/A operands: off(v,t) = frag*512 + lane*8 + elem -> per-wave fragment load
// is one contiguous 1KB transaction. Same convention on both MFMA operands
// => contraction exact regardless of HW k-ordering.

typedef __hip_bfloat16 bf16;
typedef _Float16 f16;
typedef _Float16 half8 __attribute__((ext_vector_type(8)));
typedef float f32x4 __attribute__((ext_vector_type(4)));
typedef short short8 __attribute__((ext_vector_type(8)));

#define DEV static __device__ __forceinline__

DEV float b2f(bf16 v) { return __bfloat162float(v); }
DEV bf16 f2b(float v) { return __float2bfloat16(v); }
DEV float bits2f(unsigned int u16) {
    union { unsigned int u; float f; } c; c.u = u16 << 16; return c.f;
}
DEV short f2bs(float v) {
    union { bf16 h; short s; } u; u.h = __float2bfloat16(v); return u.s;
}
DEV unsigned short f2bu(float v) {
    union { bf16 h; unsigned short s; } u; u.h = __float2bfloat16(v); return u.s;
}
DEV float fast_rcp(float v) { return __builtin_amdgcn_rcpf(v); }

DEV float ldf(const float* p) { return *p; }
DEV float ldf(const bf16* p) { return b2f(*p); }
DEV void stf(float* p, float v) { *p = v; }
DEV void stf(bf16* p, float v) { *p = f2b(v); }

DEV float4 ld4(const float* p) { return *(const float4*)p; }
DEV float4 ld4(const bf16* p) {
    const uint2 r = *(const uint2*)p;
    return make_float4(bits2f(r.x & 0xffffu), bits2f(r.x >> 16),
                       bits2f(r.y & 0xffffu), bits2f(r.y >> 16));
}

DEV half8 ld8h(const float* p) {
    const float4 a = *(const float4*)p, b = *(const float4*)(p + 4);
    half8 h;
    h[0] = (f16)a.x; h[1] = (f16)a.y; h[2] = (f16)a.z; h[3] = (f16)a.w;
    h[4] = (f16)b.x; h[5] = (f16)b.y; h[6] = (f16)b.z; h[7] = (f16)b.w;
    return h;
}
DEV half8 ld8h(const f16* p) { return *(const half8*)p; }
DEV half8 ld8h(const bf16* p) {           // bf16 -> f16 (exact, range safe)
    const float4 a = ld4(p), b = ld4(p + 4);
    half8 h;
    h[0] = (f16)a.x; h[1] = (f16)a.y; h[2] = (f16)a.z; h[3] = (f16)a.w;
    h[4] = (f16)b.x; h[5] = (f16)b.y; h[6] = (f16)b.z; h[7] = (f16)b.w;
    return h;
}

DEV f32x4 mfma_bf(short8 a, short8 b, f32x4 c) {
    return __builtin_amdgcn_mfma_f32_16x16x32_bf16(a, b, c, 0, 0, 0);
}
DEV f32x4 mfma_h(half8 a, half8 b, f32x4 c) {
    return __builtin_amdgcn_mfma_f32_16x16x32_f16(a, b, c, 0, 0, 0);
}

// fragment-major offset for a 128x64 [v][t] operand matrix
DEV size_t voff(int v, int t) {
    return (size_t)(((((v >> 4) * 2 + (t >> 5)) * 4 + ((t >> 3) & 3)) * 16
                     + (v & 15)) * 8 + (t & 7));
}

// ---------------------------------------------------------------------------
// x (fp32) -> xh (f16), 8 elems/thread
// ---------------------------------------------------------------------------
__global__ __launch_bounds__(256) void cvt_xh_k(
    const float* __restrict__ x, f16* __restrict__ xh)
{
    const size_t i = ((size_t)blockIdx.x * 256 + threadIdx.x) * 8;
    *(half8*)&xh[i] = ld8h(&x[i]);
}

// ---------------------------------------------------------------------------
// Weights -> Wt f16 [n][k] (2048 rows): [0,256)=Wq [256,512)=Wk
// [512,1024)=Wv [1024,1536)=Wg [1536,2048)=Wo. LDS transpose, 64-row blocks.
// ---------------------------------------------------------------------------
__global__ __launch_bounds__(256) void cvt_wt_k(
    const float* __restrict__ Wq, const float* __restrict__ Wk,
    const float* __restrict__ Wv, const float* __restrict__ Wg,
    const float* __restrict__ Wo, f16* __restrict__ Wt)
{
    __shared__ float tile[64][65];
    const int nb = blockIdx.x * 64;
    const int tid = threadIdx.x;
    const float* src; int nloc, N;
    if (nb < 256)       { src = Wq; N = 256; nloc = nb; }
    else if (nb < 512)  { src = Wk; N = 256; nloc = nb - 256; }
    else if (nb < 1024) { src = Wv; N = 512; nloc = nb - 512; }
    else if (nb < 1536) { src = Wg; N = 512; nloc = nb - 1024; }
    else                { src = Wo; N = 512; nloc = nb - 1536; }
    for (int k0 = 0; k0 < 512; k0 += 64) {
        for (int e = tid; e < 4096; e += 256) {
            const int i = e >> 6, j = e & 63;           // i: k, j: n
            tile[i][j] = src[(size_t)(k0 + i) * N + nloc + j];
        }
        __syncthreads();
        for (int e = tid; e < 4096; e += 256) {
            const int j = e >> 6, i = e & 63;           // coalesced over k
            Wt[(size_t)(nb + j) * 512 + k0 + i] = (f16)tile[i][j];
        }
        __syncthreads();
    }
}

// ---------------------------------------------------------------------------
// Combined projection GEMM: C_seg = xh @ Wt_seg. Tile 128x128, BK=32,
// 4 waves (2x2), 4x4 16x16 frags/wave. Both LDS stages are pure 16B copies.
// D: col=lane&15, row=4*(lane>>4)+reg (HW-verified).
// Segments by bn>>8: 0=Q(*0.125) 1=K 2,3=V(frag-major) 4,5=G(silu).
// ---------------------------------------------------------------------------
__global__ __launch_bounds__(256) void proj_gemm_k(
    const f16* __restrict__ A, const f16* __restrict__ Wt,
    bf16* __restrict__ Qb, bf16* __restrict__ Kb,
    bf16* __restrict__ VF, bf16* __restrict__ GOb)
{
    __shared__ __align__(16) f16 As[128][40];
    __shared__ __align__(16) f16 Bs[128][40];
    const int bm = blockIdx.x * 128;
    const int bn = blockIdx.y * 128;
    const int tid = threadIdx.x;
    const int lane = tid & 63;
    const int wid = tid >> 6;
    const int wr = wid >> 1, wc = wid & 1;
    const int al = lane & 15;
    const int kg = lane >> 4;

    f32x4 acc[4][4];
#pragma unroll
    for (int m = 0; m < 4; ++m)
#pragma unroll
        for (int n = 0; n < 4; ++n)
#pragma unroll
            for (int r = 0; r < 4; ++r) acc[m][n][r] = 0.f;

    const int ar = tid >> 1;
    const int ac = (tid & 1) * 16;

    for (int k0 = 0; k0 < 512; k0 += 32) {
        {
            const f16* ap = A + (size_t)(bm + ar) * 512 + k0 + ac;
            *(half8*)&As[ar][ac] = *(const half8*)ap;
            *(half8*)&As[ar][ac + 8] = *(const half8*)(ap + 8);
        }
        {
            const f16* bp = Wt + (size_t)(bn + ar) * 512 + k0 + ac;
            *(half8*)&Bs[ar][ac] = *(const half8*)bp;
            *(half8*)&Bs[ar][ac + 8] = *(const half8*)(bp + 8);
        }
        __syncthreads();
        half8 af[4], bfr[4];
#pragma unroll
        for (int m = 0; m < 4; ++m)
            af[m] = *(const half8*)&As[wr * 64 + m * 16 + al][kg * 8];
#pragma unroll
        for (int n = 0; n < 4; ++n)
            bfr[n] = *(const half8*)&Bs[wc * 64 + n * 16 + al][kg * 8];
#pragma unroll
        for (int m = 0; m < 4; ++m)
#pragma unroll
            for (int n = 0; n < 4; ++n)
                acc[m][n] = mfma_h(af[m], bfr[n], acc[m][n]);
        __syncthreads();
    }

    const int r00 = bm + wr * 64 + kg * 4;
    const int c00 = bn + wc * 64 + al;
    const int seg = bn >> 8;
    if (seg == 0) {            // Q, scale 1/8
#pragma unroll
        for (int m = 0; m < 4; ++m)
#pragma unroll
            for (int n = 0; n < 4; ++n)
#pragma unroll
                for (int r = 0; r < 4; ++r)
                    stf(&Qb[(size_t)(r00 + m * 16 + r) * 256 + c00 + n * 16],
                        acc[m][n][r] * 0.125f);
    } else if (seg == 1) {     // K
#pragma unroll
        for (int m = 0; m < 4; ++m)
#pragma unroll
            for (int n = 0; n < 4; ++n)
#pragma unroll
                for (int r = 0; r < 4; ++r)
                    stf(&Kb[(size_t)(r00 + m * 16 + r) * 256 + (c00 - 256) + n * 16],
                        acc[m][n][r]);
    } else if (seg <= 3) {     // V, fragment-major packed store
#pragma unroll
        for (int m = 0; m < 4; ++m) {
            const int row0 = r00 + m * 16;
            const int bi = row0 >> 14;
            const int chunk = (row0 >> 6) & 255;
            const int tc = row0 & 63;
#pragma unroll
            for (int n = 0; n < 4; ++n) {
                const int col = c00 - 512 + n * 16;
                const int h = col >> 7, v = col & 127;
                bf16* dst = VF + (size_t)((bi * 4 + h) * 256 + chunk) * 8192
                               + voff(v, tc);
                ushort4 pk;
                pk.x = f2bu(acc[m][n][0]); pk.y = f2bu(acc[m][n][1]);
                pk.z = f2bu(acc[m][n][2]); pk.w = f2bu(acc[m][n][3]);
                *(ushort4*)dst = pk;
            }
        }
    } else {                   // G, silu
#pragma unroll
        for (int m = 0; m < 4; ++m)
#pragma unroll
            for (int n = 0; n < 4; ++n)
#pragma unroll
                for (int r = 0; r < 4; ++r) {
                    const float v = acc[m][n][r];
                    const float sil = v * fast_rcp(1.f + __expf(-v));
                    stf(&GOb[(size_t)(r00 + m * 16 + r) * 512 + (c00 - 1024) + n * 16],
                        sil);
                }
    }
}

// ---------------------------------------------------------------------------
// Output GEMM: C[M,512] = A[M,512] @ Wo via Wt rows [1536,2048). fp32 out.
// ---------------------------------------------------------------------------
__global__ __launch_bounds__(256) void gemm_bt_k(
    const bf16* __restrict__ A, const f16* __restrict__ Bt,
    float* __restrict__ C, int M, int N, int K)
{
    __shared__ __align__(16) f16 As[128][40];
    __shared__ __align__(16) f16 Bs[128][40];
    const int bm = blockIdx.x * 128;
    const int bn = blockIdx.y * 128;
    const int tid = threadIdx.x;
    const int lane = tid & 63;
    const int wid = tid >> 6;
    const int wr = wid >> 1, wc = wid & 1;
    const int al = lane & 15;
    const int kg = lane >> 4;

    f32x4 acc[4][4];
#pragma unroll
    for (int m = 0; m < 4; ++m)
#pragma unroll
        for (int n = 0; n < 4; ++n)
#pragma unroll
            for (int r = 0; r < 4; ++r) acc[m][n][r] = 0.f;

    const int ar = tid >> 1;
    const int ac = (tid & 1) * 16;

    for (int k0 = 0; k0 < K; k0 += 32) {
        {
            const bf16* ap = A + (size_t)(bm + ar) * K + k0 + ac;
            *(half8*)&As[ar][ac] = ld8h(ap);
            *(half8*)&As[ar][ac + 8] = ld8h(ap + 8);
        }
        {
            const f16* bp = Bt + (size_t)(bn + ar) * K + k0 + ac;
            *(half8*)&Bs[ar][ac] = *(const half8*)bp;
            *(half8*)&Bs[ar][ac + 8] = *(const half8*)(bp + 8);
        }
        __syncthreads();
        half8 af[4], bfr[4];
#pragma unroll
        for (int m = 0; m < 4; ++m)
            af[m] = *(const half8*)&As[wr * 64 + m * 16 + al][kg * 8];
#pragma unroll
        for (int n = 0; n < 4; ++n)
            bfr[n] = *(const half8*)&Bs[wc * 64 + n * 16 + al][kg * 8];
#pragma unroll
        for (int m = 0; m < 4; ++m)
#pragma unroll
            for (int n = 0; n < 4; ++n)
                acc[m][n] = mfma_h(af[m], bfr[n], acc[m][n]);
        __syncthreads();
    }
    const int r0 = bm + wr * 64 + kg * 4;
    const int c0 = bn + wc * 64 + al;
#pragma unroll
    for (int m = 0; m < 4; ++m)
#pragma unroll
        for (int n = 0; n < 4; ++n)
#pragma unroll
            for (int r = 0; r < 4; ++r)
                C[(size_t)(r0 + m * 16 + r) * N + c0 + n * 16] = acc[m][n][r];
}

// ---------------------------------------------------------------------------
// gate: gk = log_sigmoid((xh @ Wgk1) @ Wgk2 + bgk2) / 16
// Block = 128 rows. Stage 1 (K=512, N=16) on f16 MFMA, Wgk1 in LDS [n][k].
// Stage 2: thread owns column c=tid; Wgk2 reads coalesced.
// ---------------------------------------------------------------------------
template <typename GKT>
__global__ __launch_bounds__(256) void gate_mfma_k(
    const f16* __restrict__ xh, const float* __restrict__ Wgk1,
    const float* __restrict__ Wgk2, const float* __restrict__ bgk2,
    GKT* __restrict__ GK)
{
    __shared__ __align__(16) f16 As[128][40];
    __shared__ __align__(16) f16 w1s[16][520];   // Wgk1^T [n][k], padded
    __shared__ float tls[128][17];               // tl fp32
    const int bm = blockIdx.x * 128;
    const int tid = threadIdx.x;
    const int lane = tid & 63;
    const int wid = tid >> 6;
    const int al = lane & 15;
    const int kg = lane >> 4;
    const int kg8 = kg * 8;

    for (int e = tid; e < 8192; e += 256) {
        const int kk = e >> 4, n = e & 15;
        w1s[n][kk] = (f16)Wgk1[e];
    }

    f32x4 acc[2];
#pragma unroll
    for (int m = 0; m < 2; ++m)
#pragma unroll
        for (int r = 0; r < 4; ++r) acc[m][r] = 0.f;

    const int ar = tid >> 1;
    const int ac = (tid & 1) * 16;
    for (int k0 = 0; k0 < 512; k0 += 32) {
        {
            const f16* ap = xh + (size_t)(bm + ar) * 512 + k0 + ac;
            *(half8*)&As[ar][ac] = *(const half8*)ap;
            *(half8*)&As[ar][ac + 8] = *(const half8*)(ap + 8);
        }
        __syncthreads();
        const half8 bfr = *(const half8*)&w1s[al][k0 + kg8];
#pragma unroll
        for (int m = 0; m < 2; ++m) {
            const half8 af = *(const half8*)&As[wid * 32 + m * 16 + al][kg8];
            acc[m] = mfma_h(af, bfr, acc[m]);
        }
        __syncthreads();
    }
#pragma unroll
    for (int m = 0; m < 2; ++m)
#pragma unroll
        for (int r = 0; r < 4; ++r)
            tls[wid * 32 + m * 16 + kg * 4 + r][al] = acc[m][r];
    __syncthreads();

    float w2[16];
#pragma unroll
    for (int r = 0; r < 16; ++r) w2[r] = Wgk2[r * 256 + tid];
    const float bb = bgk2[tid];
    GKT* gout = GK + (size_t)bm * 256 + tid;
    for (int m = 0; m < 128; ++m) {
        float z = bb;
#pragma unroll
        for (int r = 0; r < 16; ++r) z = fmaf(tls[m][r], w2[r], z);
        const float ls = fminf(z, 0.f) - __logf(1.f + __expf(-fabsf(z)));
        stf(&gout[(size_t)m * 256], ls * (1.f / 16.f));
    }
}

// ---------------------------------------------------------------------------
// Per-chunk local state via MFMA: CS[blk][v*64+k] = S^T[v][k]
//   = sum_t V[t][v] * (k_t[k] e^{d63[k]-g_t[k]}) ; DD[blk][k] = e^{d63[k]}.
// ---------------------------------------------------------------------------
template <typename GKT, typename CST>
__global__ __launch_bounds__(256) void chunk_state_k(
    const bf16* __restrict__ Km, const bf16* __restrict__ VF,
    const GKT* __restrict__ GKm, CST* __restrict__ CS,
    float* __restrict__ DD)
{
    __shared__ __align__(16) short k2t[64][72];   // [k][t] bf16
    __shared__ float cpart[4][64];
    const int blk = blockIdx.x;
    const int chunk = blk & 255;
    const int bh = blk >> 8;
    const int bi = bh >> 2, h = bh & 3;
    const int rowbase = bi * 16384 + chunk * 64;
    const int tid = threadIdx.x;
    const int k = tid & 63, tg = tid >> 6;

    float g[16];
    {
        float run = 0.f;
#pragma unroll
        for (int j = 0; j < 16; ++j) {
            run += ldf(&GKm[(size_t)(rowbase + tg * 16 + j) * 256 + h * 64 + k]);
            g[j] = run;
        }
        cpart[tg][k] = run;
    }
    __syncthreads();
    float off = 0.f;
#pragma unroll
    for (int s = 0; s < 3; ++s) if (s < tg) off += cpart[s][k];
    const float tot = cpart[0][k] + cpart[1][k] + cpart[2][k] + cpart[3][k];
    if (tg == 0) DD[(size_t)blk * 64 + k] = __expf(tot);

    {
        short8 p0, p1;
#pragma unroll
        for (int j = 0; j < 16; ++j) {
            const float kv = ldf(&Km[(size_t)(rowbase + tg * 16 + j) * 256 + h * 64 + k]);
            const float w = kv * __expf(tot - (g[j] + off));   // decay <= 1
            if (j < 8) p0[j] = f2bs(w); else p1[j - 8] = f2bs(w);
        }
        *(short8*)&k2t[k][tg * 16] = p0;
        *(short8*)&k2t[k][tg * 16 + 8] = p1;
    }
    __syncthreads();

    const int lane = tid & 63, wid = tid >> 6;
    const int al = lane & 15, kg = lane >> 4, kg8 = kg * 8;
    const bf16* Vtb = VF + (size_t)blk * 8192;

    short8 xf[2][2];
#pragma unroll
    for (int m = 0; m < 2; ++m)
#pragma unroll
        for (int ks = 0; ks < 2; ++ks)
            xf[m][ks] = *(const short8*)&Vtb[(size_t)(((wid * 2 + m) * 2 + ks) * 64 + lane) * 8];
    short8 yf[2][4];
#pragma unroll
    for (int ks = 0; ks < 2; ++ks)
#pragma unroll
        for (int n = 0; n < 4; ++n)
            yf[ks][n] = *(const short8*)&k2t[n * 16 + al][ks * 32 + kg8];

    f32x4 acc[2][4];
#pragma unroll
    for (int m = 0; m < 2; ++m)
#pragma unroll
        for (int n = 0; n < 4; ++n)
#pragma unroll
            for (int r = 0; r < 4; ++r) acc[m][n][r] = 0.f;
#pragma unroll
    for (int ks = 0; ks < 2; ++ks)
#pragma unroll
        for (int m = 0; m < 2; ++m)
#pragma unroll
            for (int n = 0; n < 4; ++n)
                acc[m][n] = mfma_bf(xf[m][ks], yf[ks][n], acc[m][n]);

    CST* out = CS + (size_t)blk * 8192;
#pragma unroll
    for (int m = 0; m < 2; ++m)
#pragma unroll
        for (int n = 0; n < 4; ++n)
#pragma unroll
            for (int r = 0; r < 4; ++r)
                stf(&out[(size_t)(wid * 32 + m * 16 + kg * 4 + r) * 64 + n * 16 + al],
                    acc[m][n][r]);
}

// ---------------------------------------------------------------------------
// Affine scan over chunks: H_{n+1}=D_n H_n+S_n. Writes H_n to Hf (bf16,
// fragment-major).
// ---------------------------------------------------------------------------
template <typename CST>
__global__ __launch_bounds__(256) void scan_k(
    const CST* __restrict__ CS, const float* __restrict__ DD,
    bf16* __restrict__ HF)
{
    const int bh = blockIdx.x >> 5;
    const int slice = blockIdx.x & 31;
    const int tid = threadIdx.x;
    const int e = slice * 256 + tid;
    const int v = e >> 6, k = e & 63;
    float H = 0.f;
    const CST* base = CS + (size_t)bh * 256 * 8192 + e;
    bf16* hbase = HF + (size_t)bh * 256 * 8192 + voff(v, k);
    const float* dbase = DD + (size_t)bh * 256 * 64 + k;
#pragma unroll 4
    for (int n = 0; n < 256; ++n) {
        const float s = ldf(&base[(size_t)n * 8192]);
        const float d = dbase[(size_t)n * 64];
        stf(&hbase[(size_t)n * 8192], H);
        H = fmaf(d, H, s);
    }
}

// ---------------------------------------------------------------------------
// Per-chunk output via MFMA + fused LayerNorm * precomputed silu(g).
// ---------------------------------------------------------------------------
template <typename GKT>
__global__ __launch_bounds__(256) void chunk_out_k(
    const bf16* __restrict__ Qm, const bf16* __restrict__ Km,
    const bf16* __restrict__ VF, const GKT* __restrict__ GKm,
    const bf16* __restrict__ HF, bf16* GO)
{
    __shared__ __align__(16) short qs[64][72];   // q*e^g   (bf16)
    __shared__ __align__(16) short ks[64][72];   // k*e^-g  (bf16)
    __shared__ __align__(16) short ab[64][72];   // causal A (bf16)
    __shared__ float cpart[4][64];

    const int blk = blockIdx.x;
    const int chunk = blk & 255;
    const int bh = blk >> 8;
    const int bi = bh >> 2, h = bh & 3;
    const int rowbase = bi * 16384 + chunk * 64;
    const int tid = threadIdx.x;
    const int k = tid & 63, tg = tid >> 6;

    float g[16];
    {
        float run = 0.f;
#pragma unroll
        for (int j = 0; j < 16; ++j) {
            run += ldf(&GKm[(size_t)(rowbase + tg * 16 + j) * 256 + h * 64 + k]);
            g[j] = run;
        }
        cpart[tg][k] = run;
    }
    __syncthreads();
    float off = 0.f;
#pragma unroll
    for (int s = 0; s < 3; ++s) if (s < tg) off += cpart[s][k];

#pragma unroll
    for (int j = 0; j < 16; ++j) {
        const int t = tg * 16 + j;
        const size_t idx = (size_t)(rowbase + t) * 256 + h * 64 + k;
        const float gc = g[j] + off;
        const float eg = __expf(gc);
        qs[t][k] = f2bs(ldf(&Qm[idx]) * eg);
        ks[t][k] = f2bs(ldf(&Km[idx]) * fast_rcp(eg));
    }
    __syncthreads();

    const int lane = tid & 63, wid = tid >> 6;
    const int al = lane & 15, kg = lane >> 4;
    const int w16 = wid * 16, kg8 = kg * 8;

    short8 xq[2];
    xq[0] = *(const short8*)&qs[w16 + al][kg8];
    xq[1] = *(const short8*)&qs[w16 + al][32 + kg8];

    f32x4 aacc[4];
#pragma unroll
    for (int n = 0; n < 4; ++n)
#pragma unroll
        for (int r = 0; r < 4; ++r) aacc[n][r] = 0.f;
#pragma unroll
    for (int ksb = 0; ksb < 2; ++ksb)
#pragma unroll
        for (int n = 0; n < 4; ++n) {
            const short8 y = *(const short8*)&ks[n * 16 + al][ksb * 32 + kg8];
            aacc[n] = mfma_bf(xq[ksb], y, aacc[n]);
        }
#pragma unroll
    for (int n = 0; n < 4; ++n)
#pragma unroll
        for (int r = 0; r < 4; ++r) {
            const int tt = w16 + kg * 4 + r;
            const int ii = n * 16 + al;
            ab[tt][ii] = (ii <= tt) ? f2bs(aacc[n][r]) : (short)0;
        }
    short8 xa[2];
    xa[0] = *(const short8*)&ab[w16 + al][kg8];
    xa[1] = *(const short8*)&ab[w16 + al][32 + kg8];

    const bf16* Vtb = VF + (size_t)blk * 8192;
    const bf16* Hb = HF + (size_t)blk * 8192;
    f32x4 oacc[8];
#pragma unroll
    for (int n = 0; n < 8; ++n)
#pragma unroll
        for (int r = 0; r < 4; ++r) oacc[n][r] = 0.f;
#pragma unroll
    for (int n = 0; n < 8; ++n) {
        const size_t f0 = (size_t)((n * 2 + 0) * 64 + lane) * 8;
        const size_t f1 = (size_t)((n * 2 + 1) * 64 + lane) * 8;
        const short8 yv0 = *(const short8*)&Vtb[f0];
        const short8 yv1 = *(const short8*)&Vtb[f1];
        const short8 yh0 = *(const short8*)&Hb[f0];
        const short8 yh1 = *(const short8*)&Hb[f1];
        oacc[n] = mfma_bf(xa[0], yv0, oacc[n]);
        oacc[n] = mfma_bf(xa[1], yv1, oacc[n]);
        oacc[n] = mfma_bf(xq[0], yh0, oacc[n]);
        oacc[n] = mfma_bf(xq[1], yh1, oacc[n]);
    }

    float psum[4] = {0.f, 0.f, 0.f, 0.f}, psq[4] = {0.f, 0.f, 0.f, 0.f};
#pragma unroll
    for (int n = 0; n < 8; ++n)
#pragma unroll
        for (int r = 0; r < 4; ++r) {
            const float v = oacc[n][r];
            psum[r] += v; psq[r] = fmaf(v, v, psq[r]);
        }
#pragma unroll
    for (int offx = 1; offx < 16; offx <<= 1)
#pragma unroll
        for (int r = 0; r < 4; ++r) {
            psum[r] += __shfl_xor(psum[r], offx);
            psq[r] += __shfl_xor(psq[r], offx);
        }
#pragma unroll
    for (int r = 0; r < 4; ++r) {
        const float mu = psum[r] * (1.f / 128.f);
        const float var = psq[r] * (1.f / 128.f) - mu * mu;
        const float rstd = rsqrtf(fmaxf(var, 0.f) + 1e-5f);
        const int row = rowbase + w16 + kg * 4 + r;
        bf16* gop = GO + (size_t)row * 512 + h * 128 + al;
#pragma unroll
        for (int n = 0; n < 8; ++n) {
            const float sil = b2f(gop[n * 16]);          // silu(g), precomputed
            gop[n * 16] = f2b((oacc[n][r] - mu) * rstd * sil);
        }
    }
}

__global__ __launch_bounds__(256) void zero_k(float* out, int n) {
    const int i = blockIdx.x * 256 + threadIdx.x;
    if (i < n) out[i] = 0.f;
}

// ---------------------------------------------------------------------------
template <typename GKT, typename CST>
static void run_all(const float* x, const float* Wq, const float* Wk,
                    const float* Wv, const float* Wg, const float* Wgk1,
                    const float* Wgk2, const float* bgk2, const float* Wo,
                    float* out, char* ws, hipStream_t stream)
{
    const int M = 32768;  // B*S
    auto aln = [](size_t v) { return (v + 255) & ~(size_t)255; };
    char* cur = ws;
    bf16* Qb = (bf16*)cur;  cur += aln((size_t)M * 256 * 2);
    bf16* Kb = (bf16*)cur;  cur += aln((size_t)M * 256 * 2);
    bf16* Vfb = (bf16*)cur; cur += aln((size_t)M * 512 * 2);   // fragment-major V
    bf16* GOb = (bf16*)cur; cur += aln((size_t)M * 512 * 2);   // silu(g), then OL
    bf16* Hfb = (bf16*)cur; cur += aln((size_t)2048 * 8192 * 2); // fragment-major H
    float* DDb = (float*)cur; cur += aln((size_t)2048 * 64 * 4);
    f16* Wtb = (f16*)cur;   cur += aln((size_t)2048 * 512 * 2);  // weights f16 [n][k]
    GKT* GKb = (GKT*)cur;   cur += aln((size_t)M * 256 * sizeof(GKT));
    CST* CSb = (CST*)cur;
    f16* xh = (f16*)CSb;    // aliases CS: dead until chunk_state_k writes it

    const dim3 blk(256);
    cvt_xh_k<<<dim3(8192), blk, 0, stream>>>(x, xh);
    cvt_wt_k<<<dim3(32), blk, 0, stream>>>(Wq, Wk, Wv, Wg, Wo, Wtb);
    proj_gemm_k<<<dim3(M / 128, 12), blk, 0, stream>>>(xh, Wtb, Qb, Kb, Vfb, GOb);
    gate_mfma_k<<<dim3(M / 128), blk, 0, stream>>>(xh, Wgk1, Wgk2, bgk2, GKb);
    chunk_state_k<<<dim3(2048), blk, 0, stream>>>(Kb, Vfb, GKb, CSb, DDb);
    scan_k<<<dim3(256), blk, 0, stream>>>(CSb, DDb, Hfb);
    chunk_out_k<<<dim3(2048), blk, 0, stream>>>(Qb, Kb, Vfb, GKb, Hfb, GOb);
    gemm_bt_k<<<dim3(M / 128, 4), blk, 0, stream>>>(GOb, Wtb + (size_t)1536 * 512,
                                                    out, M, 512, 512);
}

extern "C" void kernel_launch(void* const* d_in, const int* in_sizes, int n_in,
                              void* d_out, int out_size, void* d_ws, size_t ws_size,
                              hipStream_t stream)
{
    const float* x    = (const float*)d_in[0];
    const float* Wq   = (const float*)d_in[1];
    const float* Wk   = (const float*)d_in[2];
    const float* Wv   = (const float*)d_in[3];
    const float* Wg   = (const float*)d_in[4];
    const float* Wgk1 = (const float*)d_in[5];
    const float* Wgk2 = (const float*)d_in[6];
    const float* bgk2 = (const float*)d_in[7];
    const float* Wo   = (const float*)d_in[8];
    float* out = (float*)d_out;

    const size_t M = 32768;
    const size_t slack = 8192;
    // fixed: Q,K (bf16) + Vf + GO + Hf + DD + Wt
    const size_t base = 2 * M * 256 * 2 + 2 * M * 512 * 2
                      + (size_t)2048 * 8192 * 2 + 2048 * 64 * 4
                      + (size_t)2048 * 512 * 2 + slack;
    const size_t gk_f = M * 256 * 4, gk_b = M * 256 * 2;
    const size_t cs_f = (size_t)2048 * 8192 * 4, cs_b = (size_t)2048 * 8192 * 2;
    const size_t needA = base + gk_f + cs_f;   // ~237 MB
    const size_t needB = base + gk_b + cs_b;   // ~187 MB

    if (ws_size >= needA) {
        run_all<float, float>(x, Wq, Wk, Wv, Wg, Wgk1, Wgk2, bgk2, Wo,
                              out, (char*)d_ws, stream);
    } else if (ws_size >= needB) {
        run_all<bf16, bf16>(x, Wq, Wk, Wv, Wg, Wgk1, Wgk2, bgk2, Wo,
                            out, (char*)d_ws, stream);
    } else {
        zero_k<<<dim3((out_size + 255) / 256), dim3(256), 0, stream>>>(out, out_size);
    }
}

// Round 8
// 368.904 us; speedup vs baseline: 3.6678x; 1.0556x over previous
//
#include <hip/hip_runtime.h>
#include <hip/hip_bf16.h>

// GLA forward for MI355X. Inputs fp32, OUTPUT fp32. Pipeline:
//  0) cvt_xh_k: x (fp32) -> xh (f16) once; xh aliases CS workspace.
//     cvt_wt_k: [Wq|Wk|Wv|Wg|Wo] fp32 [k][n] -> Wt f16 [n][k] (2048x512, 2MB)
//  1) proj_gemm_k: ONE GEMM M=32768 x N=1536 over Wt rows 0..1535 with
//     per-segment epilogue: Q(scale 1/8)->bf16, K->bf16,
//     V->FRAGMENT-MAJOR Vf, G->silu->bf16.
//     Staging via __builtin_amdgcn_global_load_lds (16B/lane, zero ds_write,
//     zero staging VALU) with both-sides XOR swizzle: source addr slot ^=
//     (row&7), fragment ds_read applies same XOR -> conflict-free.
//  2) gate_mfma_k: gk = log_sigmoid((xh@Wgk1)@Wgk2 + b)/16 (stage-1 MFMA)
//  3) chunk_state_k: per-(b,h,chunk=64) local state S^T[v][k] (CST) + D
//  4) scan_k: affine scan over chunks -> chunk-start states H_n -> Hf
//     (bf16 FRAGMENT-MAJOR); CS keeps S
//  5) chunk_out_k: o = q*e^B @ H + causal intra attention @ V (bf16 MFMA),
//     fused per-head LayerNorm * precomputed silu(g) -> OL (F16, same buffer)
//  6) gemm_bt_k: out = OL(f16) @ Wo (Wt rows 1536..2047, fp32 out), same
//     global_load_lds core.
// Fragment-major layout for a [v][t] (128x64) bf16 matrix consumed as MFMA
// B/A operands: off(v,t) = frag*512 + lane*8 + elem -> per-wave fragment load
// is one contiguous 1KB transaction. Same convention on both MFMA operands
// => contraction exact regardless of HW k-ordering.

typedef __hip_bfloat16 bf16;
typedef _Float16 f16;
typedef _Float16 half8 __attribute__((ext_vector_type(8)));
typedef float f32x4 __attribute__((ext_vector_type(4)));
typedef short short8 __attribute__((ext_vector_type(8)));

#define DEV static __device__ __forceinline__

DEV float b2f(bf16 v) { return __bfloat162float(v); }
DEV bf16 f2b(float v) { return __float2bfloat16(v); }
DEV float bits2f(unsigned int u16) {
    union { unsigned int u; float f; } c; c.u = u16 << 16; return c.f;
}
DEV short f2bs(float v) {
    union { bf16 h; short s; } u; u.h = __float2bfloat16(v); return u.s;
}
DEV unsigned short f2bu(float v) {
    union { bf16 h; unsigned short s; } u; u.h = __float2bfloat16(v); return u.s;
}
DEV short f2hs(float v) {                 // fp32 -> f16 bits
    union { f16 h; short s; } u; u.h = (f16)v; return u.s;
}
DEV float fast_rcp(float v) { return __builtin_amdgcn_rcpf(v); }

DEV float ldf(const float* p) { return *p; }
DEV float ldf(const bf16* p) { return b2f(*p); }
DEV void stf(float* p, float v) { *p = v; }
DEV void stf(bf16* p, float v) { *p = f2b(v); }

DEV float4 ld4(const float* p) { return *(const float4*)p; }
DEV float4 ld4(const bf16* p) {
    const uint2 r = *(const uint2*)p;
    return make_float4(bits2f(r.x & 0xffffu), bits2f(r.x >> 16),
                       bits2f(r.y & 0xffffu), bits2f(r.y >> 16));
}

DEV half8 ld8h(const float* p) {
    const float4 a = *(const float4*)p, b = *(const float4*)(p + 4);
    half8 h;
    h[0] = (f16)a.x; h[1] = (f16)a.y; h[2] = (f16)a.z; h[3] = (f16)a.w;
    h[4] = (f16)b.x; h[5] = (f16)b.y; h[6] = (f16)b.z; h[7] = (f16)b.w;
    return h;
}
DEV half8 ld8h(const f16* p) { return *(const half8*)p; }

DEV f32x4 mfma_bf(short8 a, short8 b, f32x4 c) {
    return __builtin_amdgcn_mfma_f32_16x16x32_bf16(a, b, c, 0, 0, 0);
}
DEV f32x4 mfma_h(half8 a, half8 b, f32x4 c) {
    return __builtin_amdgcn_mfma_f32_16x16x32_f16(a, b, c, 0, 0, 0);
}

// async global->LDS copy, 16B per lane; LDS dest is wave-uniform base +
// lane*16, global src is per-lane.
DEV void gl_lds16(const f16* g, f16* l) {
    __builtin_amdgcn_global_load_lds(
        (const __attribute__((address_space(1))) void*)g,
        (__attribute__((address_space(3))) void*)l, 16, 0, 0);
}

// fragment-major offset for a 128x64 [v][t] operand matrix
DEV size_t voff(int v, int t) {
    return (size_t)(((((v >> 4) * 2 + (t >> 5)) * 4 + ((t >> 3) & 3)) * 16
                     + (v & 15)) * 8 + (t & 7));
}

// ---------------------------------------------------------------------------
// x (fp32) -> xh (f16), 8 elems/thread
// ---------------------------------------------------------------------------
__global__ __launch_bounds__(256) void cvt_xh_k(
    const float* __restrict__ x, f16* __restrict__ xh)
{
    const size_t i = ((size_t)blockIdx.x * 256 + threadIdx.x) * 8;
    *(half8*)&xh[i] = ld8h(&x[i]);
}

// ---------------------------------------------------------------------------
// Weights -> Wt f16 [n][k] (2048 rows): [0,256)=Wq [256,512)=Wk
// [512,1024)=Wv [1024,1536)=Wg [1536,2048)=Wo. LDS transpose, 64-row blocks.
// ---------------------------------------------------------------------------
__global__ __launch_bounds__(256) void cvt_wt_k(
    const float* __restrict__ Wq, const float* __restrict__ Wk,
    const float* __restrict__ Wv, const float* __restrict__ Wg,
    const float* __restrict__ Wo, f16* __restrict__ Wt)
{
    __shared__ float tile[64][65];
    const int nb = blockIdx.x * 64;
    const int tid = threadIdx.x;
    const float* src; int nloc, N;
    if (nb < 256)       { src = Wq; N = 256; nloc = nb; }
    else if (nb < 512)  { src = Wk; N = 256; nloc = nb - 256; }
    else if (nb < 1024) { src = Wv; N = 512; nloc = nb - 512; }
    else if (nb < 1536) { src = Wg; N = 512; nloc = nb - 1024; }
    else                { src = Wo; N = 512; nloc = nb - 1536; }
    for (int k0 = 0; k0 < 512; k0 += 64) {
        for (int e = tid; e < 4096; e += 256) {
            const int i = e >> 6, j = e & 63;           // i: k, j: n
            tile[i][j] = src[(size_t)(k0 + i) * N + nloc + j];
        }
        __syncthreads();
        for (int e = tid; e < 4096; e += 256) {
            const int j = e >> 6, i = e & 63;           // coalesced over k
            Wt[(size_t)(nb + j) * 512 + k0 + i] = (f16)tile[i][j];
        }
        __syncthreads();
    }
}

// ---------------------------------------------------------------------------
// Combined projection GEMM: C_seg = xh @ Wt_seg. Tile 128x128, BK=64,
// 4 waves (2x2), 4x4 16x16 frags/wave. Staging = global_load_lds, LDS linear
// [128][64] f16, XOR swizzle slot^=(row&7) applied on the global SOURCE addr
// and on the fragment ds_read (row&7 == lane&7 in both cases).
// D: col=lane&15, row=4*(lane>>4)+reg (HW-verified).
// Segments by bn>>8: 0=Q(*0.125) 1=K 2,3=V(frag-major) 4,5=G(silu).
// ---------------------------------------------------------------------------
__global__ __launch_bounds__(256) void proj_gemm_k(
    const f16* __restrict__ A, const f16* __restrict__ Wt,
    bf16* __restrict__ Qb, bf16* __restrict__ Kb,
    bf16* __restrict__ VF, bf16* __restrict__ GOb)
{
    __shared__ __align__(16) f16 As[128][64];
    __shared__ __align__(16) f16 Bs[128][64];
    const int bm = blockIdx.x * 128;
    const int bn = blockIdx.y * 128;
    const int tid = threadIdx.x;
    const int lane = tid & 63;
    const int wid = tid >> 6;
    const int wr = wid >> 1, wc = wid & 1;
    const int al = lane & 15;
    const int kg = lane >> 4;
    const int al7 = al & 7;

    f32x4 acc[4][4];
#pragma unroll
    for (int m = 0; m < 4; ++m)
#pragma unroll
        for (int n = 0; n < 4; ++n)
#pragma unroll
            for (int r = 0; r < 4; ++r) acc[m][n][r] = 0.f;

    // staging: wave w covers rows w*32..w*32+31 (4 instrs x 8 rows);
    // lane -> row w*32+i*8+(lane>>3), slot (lane&7); src slot ^= row&7.
    const int srow = wid * 32 + (lane >> 3);
    const int sswz = ((lane & 7) ^ (lane >> 3)) << 3;   // f16 elements
    const f16* ap = A + (size_t)(bm + srow) * 512 + sswz;
    const f16* bp = Wt + (size_t)(bn + srow) * 512 + sswz;

    for (int k0 = 0; k0 < 512; k0 += 64) {
        if (k0) __syncthreads();          // readers of previous tile done
#pragma unroll
        for (int i = 0; i < 4; ++i) {
            gl_lds16(ap + (size_t)i * 8 * 512 + k0, &As[wid * 32 + i * 8][0]);
            gl_lds16(bp + (size_t)i * 8 * 512 + k0, &Bs[wid * 32 + i * 8][0]);
        }
        __syncthreads();                  // vmcnt drained before barrier
#pragma unroll
        for (int ks = 0; ks < 2; ++ks) {
            half8 af[4], bfr[4];
            const int sp = ((ks * 4 + kg) ^ al7) << 3;
#pragma unroll
            for (int m = 0; m < 4; ++m)
                af[m] = *(const half8*)&As[wr * 64 + m * 16 + al][sp];
#pragma unroll
            for (int n = 0; n < 4; ++n)
                bfr[n] = *(const half8*)&Bs[wc * 64 + n * 16 + al][sp];
#pragma unroll
            for (int m = 0; m < 4; ++m)
#pragma unroll
                for (int n = 0; n < 4; ++n)
                    acc[m][n] = mfma_h(af[m], bfr[n], acc[m][n]);
        }
    }

    const int r00 = bm + wr * 64 + kg * 4;
    const int c00 = bn + wc * 64 + al;
    const int seg = bn >> 8;
    if (seg == 0) {            // Q, scale 1/8
#pragma unroll
        for (int m = 0; m < 4; ++m)
#pragma unroll
            for (int n = 0; n < 4; ++n)
#pragma unroll
                for (int r = 0; r < 4; ++r)
                    stf(&Qb[(size_t)(r00 + m * 16 + r) * 256 + c00 + n * 16],
                        acc[m][n][r] * 0.125f);
    } else if (seg == 1) {     // K
#pragma unroll
        for (int m = 0; m < 4; ++m)
#pragma unroll
            for (int n = 0; n < 4; ++n)
#pragma unroll
                for (int r = 0; r < 4; ++r)
                    stf(&Kb[(size_t)(r00 + m * 16 + r) * 256 + (c00 - 256) + n * 16],
                        acc[m][n][r]);
    } else if (seg <= 3) {     // V, fragment-major packed store
#pragma unroll
        for (int m = 0; m < 4; ++m) {
            const int row0 = r00 + m * 16;
            const int bi = row0 >> 14;
            const int chunk = (row0 >> 6) & 255;
            const int tc = row0 & 63;
#pragma unroll
            for (int n = 0; n < 4; ++n) {
                const int col = c00 - 512 + n * 16;
                const int h = col >> 7, v = col & 127;
                bf16* dst = VF + (size_t)((bi * 4 + h) * 256 + chunk) * 8192
                               + voff(v, tc);
                ushort4 pk;
                pk.x = f2bu(acc[m][n][0]); pk.y = f2bu(acc[m][n][1]);
                pk.z = f2bu(acc[m][n][2]); pk.w = f2bu(acc[m][n][3]);
                *(ushort4*)dst = pk;
            }
        }
    } else {                   // G, silu
#pragma unroll
        for (int m = 0; m < 4; ++m)
#pragma unroll
            for (int n = 0; n < 4; ++n)
#pragma unroll
                for (int r = 0; r < 4; ++r) {
                    const float v = acc[m][n][r];
                    const float sil = v * fast_rcp(1.f + __expf(-v));
                    stf(&GOb[(size_t)(r00 + m * 16 + r) * 512 + (c00 - 1024) + n * 16],
                        sil);
                }
    }
}

// ---------------------------------------------------------------------------
// Output GEMM: C[M,512] = OL(f16)[M,512] @ Wo via Wt rows [1536,2048).
// Same global_load_lds + swizzle core. fp32 out.
// ---------------------------------------------------------------------------
__global__ __launch_bounds__(256) void gemm_bt_k(
    const f16* __restrict__ A, const f16* __restrict__ Bt,
    float* __restrict__ C)
{
    __shared__ __align__(16) f16 As[128][64];
    __shared__ __align__(16) f16 Bs[128][64];
    const int bm = blockIdx.x * 128;
    const int bn = blockIdx.y * 128;
    const int tid = threadIdx.x;
    const int lane = tid & 63;
    const int wid = tid >> 6;
    const int wr = wid >> 1, wc = wid & 1;
    const int al = lane & 15;
    const int kg = lane >> 4;
    const int al7 = al & 7;

    f32x4 acc[4][4];
#pragma unroll
    for (int m = 0; m < 4; ++m)
#pragma unroll
        for (int n = 0; n < 4; ++n)
#pragma unroll
            for (int r = 0; r < 4; ++r) acc[m][n][r] = 0.f;

    const int srow = wid * 32 + (lane >> 3);
    const int sswz = ((lane & 7) ^ (lane >> 3)) << 3;
    const f16* ap = A + (size_t)(bm + srow) * 512 + sswz;
    const f16* bp = Bt + (size_t)(bn + srow) * 512 + sswz;

    for (int k0 = 0; k0 < 512; k0 += 64) {
        if (k0) __syncthreads();
#pragma unroll
        for (int i = 0; i < 4; ++i) {
            gl_lds16(ap + (size_t)i * 8 * 512 + k0, &As[wid * 32 + i * 8][0]);
            gl_lds16(bp + (size_t)i * 8 * 512 + k0, &Bs[wid * 32 + i * 8][0]);
        }
        __syncthreads();
#pragma unroll
        for (int ks = 0; ks < 2; ++ks) {
            half8 af[4], bfr[4];
            const int sp = ((ks * 4 + kg) ^ al7) << 3;
#pragma unroll
            for (int m = 0; m < 4; ++m)
                af[m] = *(const half8*)&As[wr * 64 + m * 16 + al][sp];
#pragma unroll
            for (int n = 0; n < 4; ++n)
                bfr[n] = *(const half8*)&Bs[wc * 64 + n * 16 + al][sp];
#pragma unroll
            for (int m = 0; m < 4; ++m)
#pragma unroll
                for (int n = 0; n < 4; ++n)
                    acc[m][n] = mfma_h(af[m], bfr[n], acc[m][n]);
        }
    }
    const int r0 = bm + wr * 64 + kg * 4;
    const int c0 = bn + wc * 64 + al;
#pragma unroll
    for (int m = 0; m < 4; ++m)
#pragma unroll
        for (int n = 0; n < 4; ++n)
#pragma unroll
            for (int r = 0; r < 4; ++r)
                C[(size_t)(r0 + m * 16 + r) * 512 + c0 + n * 16] = acc[m][n][r];
}

// ---------------------------------------------------------------------------
// gate: gk = log_sigmoid((xh @ Wgk1) @ Wgk2 + bgk2) / 16
// Block = 128 rows. Stage 1 (K=512, N=16) on f16 MFMA, Wgk1 in LDS [n][k].
// Stage 2: thread owns column c=tid; Wgk2 reads coalesced.
// ---------------------------------------------------------------------------
template <typename GKT>
__global__ __launch_bounds__(256) void gate_mfma_k(
    const f16* __restrict__ xh, const float* __restrict__ Wgk1,
    const float* __restrict__ Wgk2, const float* __restrict__ bgk2,
    GKT* __restrict__ GK)
{
    __shared__ __align__(16) f16 As[128][40];
    __shared__ __align__(16) f16 w1s[16][520];   // Wgk1^T [n][k], padded
    __shared__ float tls[128][17];               // tl fp32
    const int bm = blockIdx.x * 128;
    const int tid = threadIdx.x;
    const int lane = tid & 63;
    const int wid = tid >> 6;
    const int al = lane & 15;
    const int kg = lane >> 4;
    const int kg8 = kg * 8;

    for (int e = tid; e < 8192; e += 256) {
        const int kk = e >> 4, n = e & 15;
        w1s[n][kk] = (f16)Wgk1[e];
    }

    f32x4 acc[2];
#pragma unroll
    for (int m = 0; m < 2; ++m)
#pragma unroll
        for (int r = 0; r < 4; ++r) acc[m][r] = 0.f;

    const int ar = tid >> 1;
    const int ac = (tid & 1) * 16;
    for (int k0 = 0; k0 < 512; k0 += 32) {
        {
            const f16* ap = xh + (size_t)(bm + ar) * 512 + k0 + ac;
            *(half8*)&As[ar][ac] = *(const half8*)ap;
            *(half8*)&As[ar][ac + 8] = *(const half8*)(ap + 8);
        }
        __syncthreads();
        const half8 bfr = *(const half8*)&w1s[al][k0 + kg8];
#pragma unroll
        for (int m = 0; m < 2; ++m) {
            const half8 af = *(const half8*)&As[wid * 32 + m * 16 + al][kg8];
            acc[m] = mfma_h(af, bfr, acc[m]);
        }
        __syncthreads();
    }
#pragma unroll
    for (int m = 0; m < 2; ++m)
#pragma unroll
        for (int r = 0; r < 4; ++r)
            tls[wid * 32 + m * 16 + kg * 4 + r][al] = acc[m][r];
    __syncthreads();

    float w2[16];
#pragma unroll
    for (int r = 0; r < 16; ++r) w2[r] = Wgk2[r * 256 + tid];
    const float bb = bgk2[tid];
    GKT* gout = GK + (size_t)bm * 256 + tid;
    for (int m = 0; m < 128; ++m) {
        float z = bb;
#pragma unroll
        for (int r = 0; r < 16; ++r) z = fmaf(tls[m][r], w2[r], z);
        const float ls = fminf(z, 0.f) - __logf(1.f + __expf(-fabsf(z)));
        stf(&gout[(size_t)m * 256], ls * (1.f / 16.f));
    }
}

// ---------------------------------------------------------------------------
// Per-chunk local state via MFMA: CS[blk][v*64+k] = S^T[v][k]
//   = sum_t V[t][v] * (k_t[k] e^{d63[k]-g_t[k]}) ; DD[blk][k] = e^{d63[k]}.
// ---------------------------------------------------------------------------
template <typename GKT, typename CST>
__global__ __launch_bounds__(256) void chunk_state_k(
    const bf16* __restrict__ Km, const bf16* __restrict__ VF,
    const GKT* __restrict__ GKm, CST* __restrict__ CS,
    float* __restrict__ DD)
{
    __shared__ __align__(16) short k2t[64][72];   // [k][t] bf16
    __shared__ float cpart[4][64];
    const int blk = blockIdx.x;
    const int chunk = blk & 255;
    const int bh = blk >> 8;
    const int bi = bh >> 2, h = bh & 3;
    const int rowbase = bi * 16384 + chunk * 64;
    const int tid = threadIdx.x;
    const int k = tid & 63, tg = tid >> 6;

    float g[16];
    {
        float run = 0.f;
#pragma unroll
        for (int j = 0; j < 16; ++j) {
            run += ldf(&GKm[(size_t)(rowbase + tg * 16 + j) * 256 + h * 64 + k]);
            g[j] = run;
        }
        cpart[tg][k] = run;
    }
    __syncthreads();
    float off = 0.f;
#pragma unroll
    for (int s = 0; s < 3; ++s) if (s < tg) off += cpart[s][k];
    const float tot = cpart[0][k] + cpart[1][k] + cpart[2][k] + cpart[3][k];
    if (tg == 0) DD[(size_t)blk * 64 + k] = __expf(tot);

    {
        short8 p0, p1;
#pragma unroll
        for (int j = 0; j < 16; ++j) {
            const float kv = ldf(&Km[(size_t)(rowbase + tg * 16 + j) * 256 + h * 64 + k]);
            const float w = kv * __expf(tot - (g[j] + off));   // decay <= 1
            if (j < 8) p0[j] = f2bs(w); else p1[j - 8] = f2bs(w);
        }
        *(short8*)&k2t[k][tg * 16] = p0;
        *(short8*)&k2t[k][tg * 16 + 8] = p1;
    }
    __syncthreads();

    const int lane = tid & 63, wid = tid >> 6;
    const int al = lane & 15, kg = lane >> 4, kg8 = kg * 8;
    const bf16* Vtb = VF + (size_t)blk * 8192;

    short8 xf[2][2];
#pragma unroll
    for (int m = 0; m < 2; ++m)
#pragma unroll
        for (int ks = 0; ks < 2; ++ks)
            xf[m][ks] = *(const short8*)&Vtb[(size_t)(((wid * 2 + m) * 2 + ks) * 64 + lane) * 8];
    short8 yf[2][4];
#pragma unroll
    for (int ks = 0; ks < 2; ++ks)
#pragma unroll
        for (int n = 0; n < 4; ++n)
            yf[ks][n] = *(const short8*)&k2t[n * 16 + al][ks * 32 + kg8];

    f32x4 acc[2][4];
#pragma unroll
    for (int m = 0; m < 2; ++m)
#pragma unroll
        for (int n = 0; n < 4; ++n)
#pragma unroll
            for (int r = 0; r < 4; ++r) acc[m][n][r] = 0.f;
#pragma unroll
    for (int ks = 0; ks < 2; ++ks)
#pragma unroll
        for (int m = 0; m < 2; ++m)
#pragma unroll
            for (int n = 0; n < 4; ++n)
                acc[m][n] = mfma_bf(xf[m][ks], yf[ks][n], acc[m][n]);

    CST* out = CS + (size_t)blk * 8192;
#pragma unroll
    for (int m = 0; m < 2; ++m)
#pragma unroll
        for (int n = 0; n < 4; ++n)
#pragma unroll
            for (int r = 0; r < 4; ++r)
                stf(&out[(size_t)(wid * 32 + m * 16 + kg * 4 + r) * 64 + n * 16 + al],
                    acc[m][n][r]);
}

// ---------------------------------------------------------------------------
// Affine scan over chunks: H_{n+1}=D_n H_n+S_n. Writes H_n to Hf (bf16,
// fragment-major).
// ---------------------------------------------------------------------------
template <typename CST>
__global__ __launch_bounds__(256) void scan_k(
    const CST* __restrict__ CS, const float* __restrict__ DD,
    bf16* __restrict__ HF)
{
    const int bh = blockIdx.x >> 5;
    const int slice = blockIdx.x & 31;
    const int tid = threadIdx.x;
    const int e = slice * 256 + tid;
    const int v = e >> 6, k = e & 63;
    float H = 0.f;
    const CST* base = CS + (size_t)bh * 256 * 8192 + e;
    bf16* hbase = HF + (size_t)bh * 256 * 8192 + voff(v, k);
    const float* dbase = DD + (size_t)bh * 256 * 64 + k;
#pragma unroll 4
    for (int n = 0; n < 256; ++n) {
        const float s = ldf(&base[(size_t)n * 8192]);
        const float d = dbase[(size_t)n * 64];
        stf(&hbase[(size_t)n * 8192], H);
        H = fmaf(d, H, s);
    }
}

// ---------------------------------------------------------------------------
// Per-chunk output via MFMA + fused LayerNorm * precomputed silu(g).
// Writes OL as F16 bits into the GO buffer (consumed by gemm_bt_k as f16).
// ---------------------------------------------------------------------------
template <typename GKT>
__global__ __launch_bounds__(256) void chunk_out_k(
    const bf16* __restrict__ Qm, const bf16* __restrict__ Km,
    const bf16* __restrict__ VF, const GKT* __restrict__ GKm,
    const bf16* __restrict__ HF, bf16* GO)
{
    __shared__ __align__(16) short qs[64][72];   // q*e^g   (bf16)
    __shared__ __align__(16) short ks[64][72];   // k*e^-g  (bf16)
    __shared__ __align__(16) short ab[64][72];   // causal A (bf16)
    __shared__ float cpart[4][64];

    const int blk = blockIdx.x;
    const int chunk = blk & 255;
    const int bh = blk >> 8;
    const int bi = bh >> 2, h = bh & 3;
    const int rowbase = bi * 16384 + chunk * 64;
    const int tid = threadIdx.x;
    const int k = tid & 63, tg = tid >> 6;

    float g[16];
    {
        float run = 0.f;
#pragma unroll
        for (int j = 0; j < 16; ++j) {
            run += ldf(&GKm[(size_t)(rowbase + tg * 16 + j) * 256 + h * 64 + k]);
            g[j] = run;
        }
        cpart[tg][k] = run;
    }
    __syncthreads();
    float off = 0.f;
#pragma unroll
    for (int s = 0; s < 3; ++s) if (s < tg) off += cpart[s][k];

#pragma unroll
    for (int j = 0; j < 16; ++j) {
        const int t = tg * 16 + j;
        const size_t idx = (size_t)(rowbase + t) * 256 + h * 64 + k;
        const float gc = g[j] + off;
        const float eg = __expf(gc);
        qs[t][k] = f2bs(ldf(&Qm[idx]) * eg);
        ks[t][k] = f2bs(ldf(&Km[idx]) * fast_rcp(eg));
    }
    __syncthreads();

    const int lane = tid & 63, wid = tid >> 6;
    const int al = lane & 15, kg = lane >> 4;
    const int w16 = wid * 16, kg8 = kg * 8;

    short8 xq[2];
    xq[0] = *(const short8*)&qs[w16 + al][kg8];
    xq[1] = *(const short8*)&qs[w16 + al][32 + kg8];

    f32x4 aacc[4];
#pragma unroll
    for (int n = 0; n < 4; ++n)
#pragma unroll
        for (int r = 0; r < 4; ++r) aacc[n][r] = 0.f;
#pragma unroll
    for (int ksb = 0; ksb < 2; ++ksb)
#pragma unroll
        for (int n = 0; n < 4; ++n) {
            const short8 y = *(const short8*)&ks[n * 16 + al][ksb * 32 + kg8];
            aacc[n] = mfma_bf(xq[ksb], y, aacc[n]);
        }
#pragma unroll
    for (int n = 0; n < 4; ++n)
#pragma unroll
        for (int r = 0; r < 4; ++r) {
            const int tt = w16 + kg * 4 + r;
            const int ii = n * 16 + al;
            ab[tt][ii] = (ii <= tt) ? f2bs(aacc[n][r]) : (short)0;
        }
    short8 xa[2];
    xa[0] = *(const short8*)&ab[w16 + al][kg8];
    xa[1] = *(const short8*)&ab[w16 + al][32 + kg8];

    const bf16* Vtb = VF + (size_t)blk * 8192;
    const bf16* Hb = HF + (size_t)blk * 8192;
    f32x4 oacc[8];
#pragma unroll
    for (int n = 0; n < 8; ++n)
#pragma unroll
        for (int r = 0; r < 4; ++r) oacc[n][r] = 0.f;
#pragma unroll
    for (int n = 0; n < 8; ++n) {
        const size_t f0 = (size_t)((n * 2 + 0) * 64 + lane) * 8;
        const size_t f1 = (size_t)((n * 2 + 1) * 64 + lane) * 8;
        const short8 yv0 = *(const short8*)&Vtb[f0];
        const short8 yv1 = *(const short8*)&Vtb[f1];
        const short8 yh0 = *(const short8*)&Hb[f0];
        const short8 yh1 = *(const short8*)&Hb[f1];
        oacc[n] = mfma_bf(xa[0], yv0, oacc[n]);
        oacc[n] = mfma_bf(xa[1], yv1, oacc[n]);
        oacc[n] = mfma_bf(xq[0], yh0, oacc[n]);
        oacc[n] = mfma_bf(xq[1], yh1, oacc[n]);
    }

    float psum[4] = {0.f, 0.f, 0.f, 0.f}, psq[4] = {0.f, 0.f, 0.f, 0.f};
#pragma unroll
    for (int n = 0; n < 8; ++n)
#pragma unroll
        for (int r = 0; r < 4; ++r) {
            const float v = oacc[n][r];
            psum[r] += v; psq[r] = fmaf(v, v, psq[r]);
        }
#pragma unroll
    for (int offx = 1; offx < 16; offx <<= 1)
#pragma unroll
        for (int r = 0; r < 4; ++r) {
            psum[r] += __shfl_xor(psum[r], offx);
            psq[r] += __shfl_xor(psq[r], offx);
        }
#pragma unroll
    for (int r = 0; r < 4; ++r) {
        const float mu = psum[r] * (1.f / 128.f);
        const float var = psq[r] * (1.f / 128.f) - mu * mu;
        const float rstd = rsqrtf(fmaxf(var, 0.f) + 1e-5f);
        const int row = rowbase + w16 + kg * 4 + r;
        short* gop = (short*)(GO + (size_t)row * 512 + h * 128 + al);
#pragma unroll
        for (int n = 0; n < 8; ++n) {
            const bf16 gb = *(const bf16*)&gop[n * 16];
            const float sil = b2f(gb);                  // silu(g), precomputed
            gop[n * 16] = f2hs((oacc[n][r] - mu) * rstd * sil);  // OL as f16
        }
    }
}

__global__ __launch_bounds__(256) void zero_k(float* out, int n) {
    const int i = blockIdx.x * 256 + threadIdx.x;
    if (i < n) out[i] = 0.f;
}

// ---------------------------------------------------------------------------
template <typename GKT, typename CST>
static void run_all(const float* x, const float* Wq, const float* Wk,
                    const float* Wv, const float* Wg, const float* Wgk1,
                    const float* Wgk2, const float* bgk2, const float* Wo,
                    float* out, char* ws, hipStream_t stream)
{
    const int M = 32768;  // B*S
    auto aln = [](size_t v) { return (v + 255) & ~(size_t)255; };
    char* cur = ws;
    bf16* Qb = (bf16*)cur;  cur += aln((size_t)M * 256 * 2);
    bf16* Kb = (bf16*)cur;  cur += aln((size_t)M * 256 * 2);
    bf16* Vfb = (bf16*)cur; cur += aln((size_t)M * 512 * 2);   // fragment-major V
    bf16* GOb = (bf16*)cur; cur += aln((size_t)M * 512 * 2);   // silu(g) bf16, then OL f16
    bf16* Hfb = (bf16*)cur; cur += aln((size_t)2048 * 8192 * 2); // fragment-major H
    float* DDb = (float*)cur; cur += aln((size_t)2048 * 64 * 4);
    f16* Wtb = (f16*)cur;   cur += aln((size_t)2048 * 512 * 2);  // weights f16 [n][k]
    GKT* GKb = (GKT*)cur;   cur += aln((size_t)M * 256 * sizeof(GKT));
    CST* CSb = (CST*)cur;
    f16* xh = (f16*)CSb;    // aliases CS: dead until chunk_state_k writes it

    const dim3 blk(256);
    cvt_xh_k<<<dim3(8192), blk, 0, stream>>>(x, xh);
    cvt_wt_k<<<dim3(32), blk, 0, stream>>>(Wq, Wk, Wv, Wg, Wo, Wtb);
    proj_gemm_k<<<dim3(M / 128, 12), blk, 0, stream>>>(xh, Wtb, Qb, Kb, Vfb, GOb);
    gate_mfma_k<<<dim3(M / 128), blk, 0, stream>>>(xh, Wgk1, Wgk2, bgk2, GKb);
    chunk_state_k<<<dim3(2048), blk, 0, stream>>>(Kb, Vfb, GKb, CSb, DDb);
    scan_k<<<dim3(256), blk, 0, stream>>>(CSb, DDb, Hfb);
    chunk_out_k<<<dim3(2048), blk, 0, stream>>>(Qb, Kb, Vfb, GKb, Hfb, GOb);
    gemm_bt_k<<<dim3(M / 128, 4), blk, 0, stream>>>((const f16*)GOb,
                                                    Wtb + (size_t)1536 * 512, out);
}

extern "C" void kernel_launch(void* const* d_in, const int* in_sizes, int n_in,
                              void* d_out, int out_size, void* d_ws, size_t ws_size,
                              hipStream_t stream)
{
    const float* x    = (const float*)d_in[0];
    const float* Wq   = (const float*)d_in[1];
    const float* Wk   = (const float*)d_in[2];
    const float* Wv   = (const float*)d_in[3];
    const float* Wg   = (const float*)d_in[4];
    const float* Wgk1 = (const float*)d_in[5];
    const float* Wgk2 = (const float*)d_in[6];
    const float* bgk2 = (const float*)d_in[7];
    const float* Wo   = (const float*)d_in[8];
    float* out = (float*)d_out;

    const size_t M = 32768;
    const size_t slack = 8192;
    // fixed: Q,K (bf16) + Vf + GO + Hf + DD + Wt
    const size_t base = 2 * M * 256 * 2 + 2 * M * 512 * 2
                      + (size_t)2048 * 8192 * 2 + 2048 * 64 * 4
                      + (size_t)2048 * 512 * 2 + slack;
    const size_t gk_f = M * 256 * 4, gk_b = M * 256 * 2;
    const size_t cs_f = (size_t)2048 * 8192 * 4, cs_b = (size_t)2048 * 8192 * 2;
    const size_t needA = base + gk_f + cs_f;   // ~237 MB
    const size_t needB = base + gk_b + cs_b;   // ~187 MB

    if (ws_size >= needA) {
        run_all<float, float>(x, Wq, Wk, Wv, Wg, Wgk1, Wgk2, bgk2, Wo,
                              out, (char*)d_ws, stream);
    } else if (ws_size >= needB) {
        run_all<bf16, bf16>(x, Wq, Wk, Wv, Wg, Wgk1, Wgk2, bgk2, Wo,
                            out, (char*)d_ws, stream);
    } else {
        zero_k<<<dim3((out_size + 255) / 256), dim3(256), 0, stream>>>(out, out_size);
    }
}

// Round 9
// 365.686 us; speedup vs baseline: 3.7001x; 1.0088x over previous
//
#include <hip/hip_runtime.h>
#include <hip/hip_bf16.h>

// GLA forward for MI355X. Inputs fp32, OUTPUT fp32. Pipeline:
//  0) cvt_xh_k: x (fp32) -> xh (f16) once; xh aliases CS workspace.
//     cvt_wt_k: [Wq|Wk|Wv|Wg|Wo] fp32 [k][n] -> Wt f16 [n][k] (2048x512, 2MB)
//  1) proj_gemm_k: ONE GEMM M=32768 x N=1536 over Wt rows 0..1535, m97
//     geometry (128x128 tile, BK=32, 16KB LDS, global_load_lds staging,
//     both-sides XOR swizzle, XCD-swizzled block ids). Per-segment epilogue:
//     Q(*1/8)->bf16, K->bf16, V->FRAGMENT-MAJOR Vf, G->silu->bf16.
//  2) gate_mfma_k: gk = log_sigmoid((xh@Wgk1)@Wgk2 + b)/16 -> bf16
//  3) chunk_state_k: per-(b,h,chunk=64) local state S^T[v][k] (bf16) + D
//  4) scan_k: affine scan over chunks -> chunk-start states H_n -> Hf
//     (bf16 FRAGMENT-MAJOR); fp32 accumulation in-register
//  5) chunk_out_k: o = q*e^B @ H + causal intra attention @ V (bf16 MFMA),
//     fused per-head LayerNorm * precomputed silu(g) -> OL (f16, same buffer)
//  6) gemm_bt_k: out = OL(f16) @ Wo (Wt rows 1536..2047, fp32 out), same core
// Fragment-major layout for a [v][t] (128x64) bf16 matrix consumed as MFMA
// operands: off(v,t) = frag*512 + lane*8 + elem -> per-wave fragment load is
// one contiguous 1KB transaction. Same convention on both MFMA operands =>
// contraction exact regardless of HW k-ordering.
// BK=32 swizzle derivation: LDS row = 32 f16 = 4 slots of 16B. Stored slot
// lslot = gslot ^ ((row>>1)&3). gl_lds writes linearly (lane -> row lane>>2,
// lslot lane&3), so source fetches gslot = (lane&3)^((lane>>3)&3). Fragment
// read wants gslot=kg at row m*16+al -> lslot = kg^((al>>1)&3). Collisions
// only for rows 8 apart (2-way = free).

typedef __hip_bfloat16 bf16;
typedef _Float16 f16;
typedef _Float16 half8 __attribute__((ext_vector_type(8)));
typedef float f32x4 __attribute__((ext_vector_type(4)));
typedef short short8 __attribute__((ext_vector_type(8)));

#define DEV static __device__ __forceinline__

DEV float b2f(bf16 v) { return __bfloat162float(v); }
DEV bf16 f2b(float v) { return __float2bfloat16(v); }
DEV float bits2f(unsigned int u16) {
    union { unsigned int u; float f; } c; c.u = u16 << 16; return c.f;
}
DEV short f2bs(float v) {
    union { bf16 h; short s; } u; u.h = __float2bfloat16(v); return u.s;
}
DEV unsigned short f2bu(float v) {
    union { bf16 h; unsigned short s; } u; u.h = __float2bfloat16(v); return u.s;
}
DEV short f2hs(float v) {                 // fp32 -> f16 bits
    union { f16 h; short s; } u; u.h = (f16)v; return u.s;
}
DEV float fast_rcp(float v) { return __builtin_amdgcn_rcpf(v); }

DEV float ldf(const float* p) { return *p; }
DEV float ldf(const bf16* p) { return b2f(*p); }
DEV void stf(float* p, float v) { *p = v; }
DEV void stf(bf16* p, float v) { *p = f2b(v); }

DEV float4 ld4(const float* p) { return *(const float4*)p; }
DEV float4 ld4(const bf16* p) {
    const uint2 r = *(const uint2*)p;
    return make_float4(bits2f(r.x & 0xffffu), bits2f(r.x >> 16),
                       bits2f(r.y & 0xffffu), bits2f(r.y >> 16));
}

DEV half8 ld8h(const float* p) {
    const float4 a = *(const float4*)p, b = *(const float4*)(p + 4);
    half8 h;
    h[0] = (f16)a.x; h[1] = (f16)a.y; h[2] = (f16)a.z; h[3] = (f16)a.w;
    h[4] = (f16)b.x; h[5] = (f16)b.y; h[6] = (f16)b.z; h[7] = (f16)b.w;
    return h;
}
DEV half8 ld8h(const f16* p) { return *(const half8*)p; }

DEV f32x4 mfma_bf(short8 a, short8 b, f32x4 c) {
    return __builtin_amdgcn_mfma_f32_16x16x32_bf16(a, b, c, 0, 0, 0);
}
DEV f32x4 mfma_h(half8 a, half8 b, f32x4 c) {
    return __builtin_amdgcn_mfma_f32_16x16x32_f16(a, b, c, 0, 0, 0);
}

// async global->LDS copy, 16B/lane; LDS dest wave-uniform base + lane*16.
DEV void gl_lds16(const f16* g, f16* l) {
    __builtin_amdgcn_global_load_lds(
        (const __attribute__((address_space(1))) void*)g,
        (__attribute__((address_space(3))) void*)l, 16, 0, 0);
}

// fragment-major offset for a 128x64 [v][t] operand matrix
DEV size_t voff(int v, int t) {
    return (size_t)(((((v >> 4) * 2 + (t >> 5)) * 4 + ((t >> 3) & 3)) * 16
                     + (v & 15)) * 8 + (t & 7));
}

// ---------------------------------------------------------------------------
// x (fp32) -> xh (f16), 8 elems/thread
// ---------------------------------------------------------------------------
__global__ __launch_bounds__(256) void cvt_xh_k(
    const float* __restrict__ x, f16* __restrict__ xh)
{
    const size_t i = ((size_t)blockIdx.x * 256 + threadIdx.x) * 8;
    *(half8*)&xh[i] = ld8h(&x[i]);
}

// ---------------------------------------------------------------------------
// Weights -> Wt f16 [n][k] (2048 rows): [0,256)=Wq [256,512)=Wk
// [512,1024)=Wv [1024,1536)=Wg [1536,2048)=Wo. LDS transpose, 64-row blocks.
// ---------------------------------------------------------------------------
__global__ __launch_bounds__(256) void cvt_wt_k(
    const float* __restrict__ Wq, const float* __restrict__ Wk,
    const float* __restrict__ Wv, const float* __restrict__ Wg,
    const float* __restrict__ Wo, f16* __restrict__ Wt)
{
    __shared__ float tile[64][65];
    const int nb = blockIdx.x * 64;
    const int tid = threadIdx.x;
    const float* src; int nloc, N;
    if (nb < 256)       { src = Wq; N = 256; nloc = nb; }
    else if (nb < 512)  { src = Wk; N = 256; nloc = nb - 256; }
    else if (nb < 1024) { src = Wv; N = 512; nloc = nb - 512; }
    else if (nb < 1536) { src = Wg; N = 512; nloc = nb - 1024; }
    else                { src = Wo; N = 512; nloc = nb - 1536; }
    for (int k0 = 0; k0 < 512; k0 += 64) {
        for (int e = tid; e < 4096; e += 256) {
            const int i = e >> 6, j = e & 63;           // i: k, j: n
            tile[i][j] = src[(size_t)(k0 + i) * N + nloc + j];
        }
        __syncthreads();
        for (int e = tid; e < 4096; e += 256) {
            const int j = e >> 6, i = e & 63;           // coalesced over k
            Wt[(size_t)(nb + j) * 512 + k0 + i] = (f16)tile[i][j];
        }
        __syncthreads();
    }
}

// ---------------------------------------------------------------------------
// Combined projection GEMM: C_seg = xh @ Wt_seg. Tile 128x128, BK=32,
// 4 waves (2x2), 4x4 16x16 frags/wave, 16KB LDS, global_load_lds staging.
// D: col=lane&15, row=4*(lane>>4)+reg (HW-verified).
// Segments by bn>>8: 0=Q(*0.125) 1=K 2,3=V(frag-major) 4,5=G(silu).
// Bijective XCD swizzle on the flat block id (nwg=3072 % 8 == 0).
// ---------------------------------------------------------------------------
__global__ __launch_bounds__(256) void proj_gemm_k(
    const f16* __restrict__ A, const f16* __restrict__ Wt,
    bf16* __restrict__ Qb, bf16* __restrict__ Kb,
    bf16* __restrict__ VF, bf16* __restrict__ GOb)
{
    __shared__ __align__(128) f16 As[128][32];
    __shared__ __align__(128) f16 Bs[128][32];
    const int flat = blockIdx.y * 256 + blockIdx.x;       // 0..3071
    const int fs = (flat & 7) * 384 + (flat >> 3);        // XCD swizzle
    const int bm = (fs & 255) * 128;
    const int bn = (fs >> 8) * 128;
    const int tid = threadIdx.x;
    const int lane = tid & 63;
    const int wid = tid >> 6;
    const int wr = wid >> 1, wc = wid & 1;
    const int al = lane & 15;
    const int kg = lane >> 4;

    f32x4 acc[4][4];
#pragma unroll
    for (int m = 0; m < 4; ++m)
#pragma unroll
        for (int n = 0; n < 4; ++n)
#pragma unroll
            for (int r = 0; r < 4; ++r) acc[m][n][r] = 0.f;

    // staging: instr i covers rows wave*32+i*16+(lane>>2), slot lane&3;
    // source slot pre-swizzled: gslot = (lane&3) ^ ((lane>>3)&3).
    const int srow = wid * 32 + (lane >> 2);
    const int gsw = (((lane & 3) ^ ((lane >> 3) & 3))) << 3;   // f16 elems
    const f16* ap = A + (size_t)(bm + srow) * 512 + gsw;
    const f16* bp = Wt + (size_t)(bn + srow) * 512 + gsw;
    const int sp = (kg ^ ((al >> 1) & 3)) << 3;                // read slot

    for (int k0 = 0; k0 < 512; k0 += 32) {
        if (k0) __syncthreads();          // readers of previous tile done
        gl_lds16(ap + k0, &As[wid * 32][0]);
        gl_lds16(ap + (size_t)16 * 512 + k0, &As[wid * 32 + 16][0]);
        gl_lds16(bp + k0, &Bs[wid * 32][0]);
        gl_lds16(bp + (size_t)16 * 512 + k0, &Bs[wid * 32 + 16][0]);
        __syncthreads();                  // vmcnt drained before barrier
        half8 af[4], bfr[4];
#pragma unroll
        for (int m = 0; m < 4; ++m)
            af[m] = *(const half8*)&As[wr * 64 + m * 16 + al][sp];
#pragma unroll
        for (int n = 0; n < 4; ++n)
            bfr[n] = *(const half8*)&Bs[wc * 64 + n * 16 + al][sp];
#pragma unroll
        for (int m = 0; m < 4; ++m)
#pragma unroll
            for (int n = 0; n < 4; ++n)
                acc[m][n] = mfma_h(af[m], bfr[n], acc[m][n]);
    }

    const int r00 = bm + wr * 64 + kg * 4;
    const int c00 = bn + wc * 64 + al;
    const int seg = bn >> 8;
    if (seg == 0) {            // Q, scale 1/8
#pragma unroll
        for (int m = 0; m < 4; ++m)
#pragma unroll
            for (int n = 0; n < 4; ++n)
#pragma unroll
                for (int r = 0; r < 4; ++r)
                    stf(&Qb[(size_t)(r00 + m * 16 + r) * 256 + c00 + n * 16],
                        acc[m][n][r] * 0.125f);
    } else if (seg == 1) {     // K
#pragma unroll
        for (int m = 0; m < 4; ++m)
#pragma unroll
            for (int n = 0; n < 4; ++n)
#pragma unroll
                for (int r = 0; r < 4; ++r)
                    stf(&Kb[(size_t)(r00 + m * 16 + r) * 256 + (c00 - 256) + n * 16],
                        acc[m][n][r]);
    } else if (seg <= 3) {     // V, fragment-major packed store
#pragma unroll
        for (int m = 0; m < 4; ++m) {
            const int row0 = r00 + m * 16;
            const int bi = row0 >> 14;
            const int chunk = (row0 >> 6) & 255;
            const int tc = row0 & 63;
#pragma unroll
            for (int n = 0; n < 4; ++n) {
                const int col = c00 - 512 + n * 16;
                const int h = col >> 7, v = col & 127;
                bf16* dst = VF + (size_t)((bi * 4 + h) * 256 + chunk) * 8192
                               + voff(v, tc);
                ushort4 pk;
                pk.x = f2bu(acc[m][n][0]); pk.y = f2bu(acc[m][n][1]);
                pk.z = f2bu(acc[m][n][2]); pk.w = f2bu(acc[m][n][3]);
                *(ushort4*)dst = pk;
            }
        }
    } else {                   // G, silu
#pragma unroll
        for (int m = 0; m < 4; ++m)
#pragma unroll
            for (int n = 0; n < 4; ++n)
#pragma unroll
                for (int r = 0; r < 4; ++r) {
                    const float v = acc[m][n][r];
                    const float sil = v * fast_rcp(1.f + __expf(-v));
                    stf(&GOb[(size_t)(r00 + m * 16 + r) * 512 + (c00 - 1024) + n * 16],
                        sil);
                }
    }
}

// ---------------------------------------------------------------------------
// Output GEMM: C[M,512] = OL(f16)[M,512] @ Wo via Wt rows [1536,2048).
// Same BK=32 global_load_lds core. fp32 out. nwg=1024 XCD swizzle.
// ---------------------------------------------------------------------------
__global__ __launch_bounds__(256) void gemm_bt_k(
    const f16* __restrict__ A, const f16* __restrict__ Bt,
    float* __restrict__ C)
{
    __shared__ __align__(128) f16 As[128][32];
    __shared__ __align__(128) f16 Bs[128][32];
    const int flat = blockIdx.y * 256 + blockIdx.x;       // 0..1023
    const int fs = (flat & 7) * 128 + (flat >> 3);
    const int bm = (fs & 255) * 128;
    const int bn = (fs >> 8) * 128;
    const int tid = threadIdx.x;
    const int lane = tid & 63;
    const int wid = tid >> 6;
    const int wr = wid >> 1, wc = wid & 1;
    const int al = lane & 15;
    const int kg = lane >> 4;

    f32x4 acc[4][4];
#pragma unroll
    for (int m = 0; m < 4; ++m)
#pragma unroll
        for (int n = 0; n < 4; ++n)
#pragma unroll
            for (int r = 0; r < 4; ++r) acc[m][n][r] = 0.f;

    const int srow = wid * 32 + (lane >> 2);
    const int gsw = (((lane & 3) ^ ((lane >> 3) & 3))) << 3;
    const f16* ap = A + (size_t)(bm + srow) * 512 + gsw;
    const f16* bp = Bt + (size_t)(bn + srow) * 512 + gsw;
    const int sp = (kg ^ ((al >> 1) & 3)) << 3;

    for (int k0 = 0; k0 < 512; k0 += 32) {
        if (k0) __syncthreads();
        gl_lds16(ap + k0, &As[wid * 32][0]);
        gl_lds16(ap + (size_t)16 * 512 + k0, &As[wid * 32 + 16][0]);
        gl_lds16(bp + k0, &Bs[wid * 32][0]);
        gl_lds16(bp + (size_t)16 * 512 + k0, &Bs[wid * 32 + 16][0]);
        __syncthreads();
        half8 af[4], bfr[4];
#pragma unroll
        for (int m = 0; m < 4; ++m)
            af[m] = *(const half8*)&As[wr * 64 + m * 16 + al][sp];
#pragma unroll
        for (int n = 0; n < 4; ++n)
            bfr[n] = *(const half8*)&Bs[wc * 64 + n * 16 + al][sp];
#pragma unroll
        for (int m = 0; m < 4; ++m)
#pragma unroll
            for (int n = 0; n < 4; ++n)
                acc[m][n] = mfma_h(af[m], bfr[n], acc[m][n]);
    }
    const int r0 = bm + wr * 64 + kg * 4;
    const int c0 = bn + wc * 64 + al;
#pragma unroll
    for (int m = 0; m < 4; ++m)
#pragma unroll
        for (int n = 0; n < 4; ++n)
#pragma unroll
            for (int r = 0; r < 4; ++r)
                C[(size_t)(r0 + m * 16 + r) * 512 + c0 + n * 16] = acc[m][n][r];
}

// ---------------------------------------------------------------------------
// gate: gk = log_sigmoid((xh @ Wgk1) @ Wgk2 + bgk2) / 16 -> bf16
// Block = 128 rows. Stage 1 (K=512, N=16) on f16 MFMA, Wgk1 in LDS [n][k].
// Stage 2: thread owns column c=tid; Wgk2 reads coalesced.
// ---------------------------------------------------------------------------
__global__ __launch_bounds__(256) void gate_mfma_k(
    const f16* __restrict__ xh, const float* __restrict__ Wgk1,
    const float* __restrict__ Wgk2, const float* __restrict__ bgk2,
    bf16* __restrict__ GK)
{
    __shared__ __align__(16) f16 As[128][40];
    __shared__ __align__(16) f16 w1s[16][520];   // Wgk1^T [n][k], padded
    __shared__ float tls[128][17];               // tl fp32
    const int bm = blockIdx.x * 128;
    const int tid = threadIdx.x;
    const int lane = tid & 63;
    const int wid = tid >> 6;
    const int al = lane & 15;
    const int kg = lane >> 4;
    const int kg8 = kg * 8;

    for (int e = tid; e < 8192; e += 256) {
        const int kk = e >> 4, n = e & 15;
        w1s[n][kk] = (f16)Wgk1[e];
    }

    f32x4 acc[2];
#pragma unroll
    for (int m = 0; m < 2; ++m)
#pragma unroll
        for (int r = 0; r < 4; ++r) acc[m][r] = 0.f;

    const int ar = tid >> 1;
    const int ac = (tid & 1) * 16;
    for (int k0 = 0; k0 < 512; k0 += 32) {
        {
            const f16* ap = xh + (size_t)(bm + ar) * 512 + k0 + ac;
            *(half8*)&As[ar][ac] = *(const half8*)ap;
            *(half8*)&As[ar][ac + 8] = *(const half8*)(ap + 8);
        }
        __syncthreads();
        const half8 bfr = *(const half8*)&w1s[al][k0 + kg8];
#pragma unroll
        for (int m = 0; m < 2; ++m) {
            const half8 af = *(const half8*)&As[wid * 32 + m * 16 + al][kg8];
            acc[m] = mfma_h(af, bfr, acc[m]);
        }
        __syncthreads();
    }
#pragma unroll
    for (int m = 0; m < 2; ++m)
#pragma unroll
        for (int r = 0; r < 4; ++r)
            tls[wid * 32 + m * 16 + kg * 4 + r][al] = acc[m][r];
    __syncthreads();

    float w2[16];
#pragma unroll
    for (int r = 0; r < 16; ++r) w2[r] = Wgk2[r * 256 + tid];
    const float bb = bgk2[tid];
    bf16* gout = GK + (size_t)bm * 256 + tid;
    for (int m = 0; m < 128; ++m) {
        float z = bb;
#pragma unroll
        for (int r = 0; r < 16; ++r) z = fmaf(tls[m][r], w2[r], z);
        const float ls = fminf(z, 0.f) - __logf(1.f + __expf(-fabsf(z)));
        stf(&gout[(size_t)m * 256], ls * (1.f / 16.f));
    }
}

// ---------------------------------------------------------------------------
// Per-chunk local state via MFMA: CS[blk][v*64+k] = S^T[v][k] (bf16)
//   = sum_t V[t][v] * (k_t[k] e^{d63[k]-g_t[k]}) ; DD[blk][k] = e^{d63[k]}.
// ---------------------------------------------------------------------------
__global__ __launch_bounds__(256) void chunk_state_k(
    const bf16* __restrict__ Km, const bf16* __restrict__ VF,
    const bf16* __restrict__ GKm, bf16* __restrict__ CS,
    float* __restrict__ DD)
{
    __shared__ __align__(16) short k2t[64][72];   // [k][t] bf16
    __shared__ float cpart[4][64];
    const int blk = blockIdx.x;
    const int chunk = blk & 255;
    const int bh = blk >> 8;
    const int bi = bh >> 2, h = bh & 3;
    const int rowbase = bi * 16384 + chunk * 64;
    const int tid = threadIdx.x;
    const int k = tid & 63, tg = tid >> 6;

    float g[16];
    {
        float run = 0.f;
#pragma unroll
        for (int j = 0; j < 16; ++j) {
            run += ldf(&GKm[(size_t)(rowbase + tg * 16 + j) * 256 + h * 64 + k]);
            g[j] = run;
        }
        cpart[tg][k] = run;
    }
    __syncthreads();
    float off = 0.f;
#pragma unroll
    for (int s = 0; s < 3; ++s) if (s < tg) off += cpart[s][k];
    const float tot = cpart[0][k] + cpart[1][k] + cpart[2][k] + cpart[3][k];
    if (tg == 0) DD[(size_t)blk * 64 + k] = __expf(tot);

    {
        short8 p0, p1;
#pragma unroll
        for (int j = 0; j < 16; ++j) {
            const float kv = ldf(&Km[(size_t)(rowbase + tg * 16 + j) * 256 + h * 64 + k]);
            const float w = kv * __expf(tot - (g[j] + off));   // decay <= 1
            if (j < 8) p0[j] = f2bs(w); else p1[j - 8] = f2bs(w);
        }
        *(short8*)&k2t[k][tg * 16] = p0;
        *(short8*)&k2t[k][tg * 16 + 8] = p1;
    }
    __syncthreads();

    const int lane = tid & 63, wid = tid >> 6;
    const int al = lane & 15, kg = lane >> 4, kg8 = kg * 8;
    const bf16* Vtb = VF + (size_t)blk * 8192;

    short8 xf[2][2];
#pragma unroll
    for (int m = 0; m < 2; ++m)
#pragma unroll
        for (int ks = 0; ks < 2; ++ks)
            xf[m][ks] = *(const short8*)&Vtb[(size_t)(((wid * 2 + m) * 2 + ks) * 64 + lane) * 8];
    short8 yf[2][4];
#pragma unroll
    for (int ks = 0; ks < 2; ++ks)
#pragma unroll
        for (int n = 0; n < 4; ++n)
            yf[ks][n] = *(const short8*)&k2t[n * 16 + al][ks * 32 + kg8];

    f32x4 acc[2][4];
#pragma unroll
    for (int m = 0; m < 2; ++m)
#pragma unroll
        for (int n = 0; n < 4; ++n)
#pragma unroll
            for (int r = 0; r < 4; ++r) acc[m][n][r] = 0.f;
#pragma unroll
    for (int ks = 0; ks < 2; ++ks)
#pragma unroll
        for (int m = 0; m < 2; ++m)
#pragma unroll
            for (int n = 0; n < 4; ++n)
                acc[m][n] = mfma_bf(xf[m][ks], yf[ks][n], acc[m][n]);

    bf16* out = CS + (size_t)blk * 8192;
#pragma unroll
    for (int m = 0; m < 2; ++m)
#pragma unroll
        for (int n = 0; n < 4; ++n)
#pragma unroll
            for (int r = 0; r < 4; ++r)
                stf(&out[(size_t)(wid * 32 + m * 16 + kg * 4 + r) * 64 + n * 16 + al],
                    acc[m][n][r]);
}

// ---------------------------------------------------------------------------
// Affine scan over chunks: H_{n+1}=D_n H_n+S_n. Reads S (bf16), accumulates
// fp32 in-register, writes H_n to Hf (bf16, fragment-major).
// ---------------------------------------------------------------------------
__global__ __launch_bounds__(256) void scan_k(
    const bf16* __restrict__ CS, const float* __restrict__ DD,
    bf16* __restrict__ HF)
{
    const int bh = blockIdx.x >> 5;
    const int slice = blockIdx.x & 31;
    const int tid = threadIdx.x;
    const int e = slice * 256 + tid;
    const int v = e >> 6, k = e & 63;
    float H = 0.f;
    const bf16* base = CS + (size_t)bh * 256 * 8192 + e;
    bf16* hbase = HF + (size_t)bh * 256 * 8192 + voff(v, k);
    const float* dbase = DD + (size_t)bh * 256 * 64 + k;
#pragma unroll 4
    for (int n = 0; n < 256; ++n) {
        const float s = ldf(&base[(size_t)n * 8192]);
        const float d = dbase[(size_t)n * 64];
        stf(&hbase[(size_t)n * 8192], H);
        H = fmaf(d, H, s);
    }
}

// ---------------------------------------------------------------------------
// Per-chunk output via MFMA + fused LayerNorm * precomputed silu(g).
// Writes OL as F16 bits into the GO buffer (consumed by gemm_bt_k as f16).
// ---------------------------------------------------------------------------
__global__ __launch_bounds__(256) void chunk_out_k(
    const bf16* __restrict__ Qm, const bf16* __restrict__ Km,
    const bf16* __restrict__ VF, const bf16* __restrict__ GKm,
    const bf16* __restrict__ HF, bf16* GO)
{
    __shared__ __align__(16) short qs[64][72];   // q*e^g   (bf16)
    __shared__ __align__(16) short ks[64][72];   // k*e^-g  (bf16)
    __shared__ __align__(16) short ab[64][72];   // causal A (bf16)
    __shared__ float cpart[4][64];

    const int blk = blockIdx.x;
    const int chunk = blk & 255;
    const int bh = blk >> 8;
    const int bi = bh >> 2, h = bh & 3;
    const int rowbase = bi * 16384 + chunk * 64;
    const int tid = threadIdx.x;
    const int k = tid & 63, tg = tid >> 6;

    float g[16];
    {
        float run = 0.f;
#pragma unroll
        for (int j = 0; j < 16; ++j) {
            run += ldf(&GKm[(size_t)(rowbase + tg * 16 + j) * 256 + h * 64 + k]);
            g[j] = run;
        }
        cpart[tg][k] = run;
    }
    __syncthreads();
    float off = 0.f;
#pragma unroll
    for (int s = 0; s < 3; ++s) if (s < tg) off += cpart[s][k];

#pragma unroll
    for (int j = 0; j < 16; ++j) {
        const int t = tg * 16 + j;
        const size_t idx = (size_t)(rowbase + t) * 256 + h * 64 + k;
        const float gc = g[j] + off;
        const float eg = __expf(gc);
        qs[t][k] = f2bs(ldf(&Qm[idx]) * eg);
        ks[t][k] = f2bs(ldf(&Km[idx]) * fast_rcp(eg));
    }
    __syncthreads();

    const int lane = tid & 63, wid = tid >> 6;
    const int al = lane & 15, kg = lane >> 4;
    const int w16 = wid * 16, kg8 = kg * 8;

    short8 xq[2];
    xq[0] = *(const short8*)&qs[w16 + al][kg8];
    xq[1] = *(const short8*)&qs[w16 + al][32 + kg8];

    f32x4 aacc[4];
#pragma unroll
    for (int n = 0; n < 4; ++n)
#pragma unroll
        for (int r = 0; r < 4; ++r) aacc[n][r] = 0.f;
#pragma unroll
    for (int ksb = 0; ksb < 2; ++ksb)
#pragma unroll
        for (int n = 0; n < 4; ++n) {
            const short8 y = *(const short8*)&ks[n * 16 + al][ksb * 32 + kg8];
            aacc[n] = mfma_bf(xq[ksb], y, aacc[n]);
        }
#pragma unroll
    for (int n = 0; n < 4; ++n)
#pragma unroll
        for (int r = 0; r < 4; ++r) {
            const int tt = w16 + kg * 4 + r;
            const int ii = n * 16 + al;
            ab[tt][ii] = (ii <= tt) ? f2bs(aacc[n][r]) : (short)0;
        }
    short8 xa[2];
    xa[0] = *(const short8*)&ab[w16 + al][kg8];
    xa[1] = *(const short8*)&ab[w16 + al][32 + kg8];

    const bf16* Vtb = VF + (size_t)blk * 8192;
    const bf16* Hb = HF + (size_t)blk * 8192;
    f32x4 oacc[8];
#pragma unroll
    for (int n = 0; n < 8; ++n)
#pragma unroll
        for (int r = 0; r < 4; ++r) oacc[n][r] = 0.f;
#pragma unroll
    for (int n = 0; n < 8; ++n) {
        const size_t f0 = (size_t)((n * 2 + 0) * 64 + lane) * 8;
        const size_t f1 = (size_t)((n * 2 + 1) * 64 + lane) * 8;
        const short8 yv0 = *(const short8*)&Vtb[f0];
        const short8 yv1 = *(const short8*)&Vtb[f1];
        const short8 yh0 = *(const short8*)&Hb[f0];
        const short8 yh1 = *(const short8*)&Hb[f1];
        oacc[n] = mfma_bf(xa[0], yv0, oacc[n]);
        oacc[n] = mfma_bf(xa[1], yv1, oacc[n]);
        oacc[n] = mfma_bf(xq[0], yh0, oacc[n]);
        oacc[n] = mfma_bf(xq[1], yh1, oacc[n]);
    }

    float psum[4] = {0.f, 0.f, 0.f, 0.f}, psq[4] = {0.f, 0.f, 0.f, 0.f};
#pragma unroll
    for (int n = 0; n < 8; ++n)
#pragma unroll
        for (int r = 0; r < 4; ++r) {
            const float v = oacc[n][r];
            psum[r] += v; psq[r] = fmaf(v, v, psq[r]);
        }
#pragma unroll
    for (int offx = 1; offx < 16; offx <<= 1)
#pragma unroll
        for (int r = 0; r < 4; ++r) {
            psum[r] += __shfl_xor(psum[r], offx);
            psq[r] += __shfl_xor(psq[r], offx);
        }
#pragma unroll
    for (int r = 0; r < 4; ++r) {
        const float mu = psum[r] * (1.f / 128.f);
        const float var = psq[r] * (1.f / 128.f) - mu * mu;
        const float rstd = rsqrtf(fmaxf(var, 0.f) + 1e-5f);
        const int row = rowbase + w16 + kg * 4 + r;
        short* gop = (short*)(GO + (size_t)row * 512 + h * 128 + al);
#pragma unroll
        for (int n = 0; n < 8; ++n) {
            const bf16 gb = *(const bf16*)&gop[n * 16];
            const float sil = b2f(gb);                  // silu(g), precomputed
            gop[n * 16] = f2hs((oacc[n][r] - mu) * rstd * sil);  // OL as f16
        }
    }
}

__global__ __launch_bounds__(256) void zero_k(float* out, int n) {
    const int i = blockIdx.x * 256 + threadIdx.x;
    if (i < n) out[i] = 0.f;
}

// ---------------------------------------------------------------------------
static void run_all(const float* x, const float* Wq, const float* Wk,
                    const float* Wv, const float* Wg, const float* Wgk1,
                    const float* Wgk2, const float* bgk2, const float* Wo,
                    float* out, char* ws, hipStream_t stream)
{
    const int M = 32768;  // B*S
    auto aln = [](size_t v) { return (v + 255) & ~(size_t)255; };
    char* cur = ws;
    bf16* Qb = (bf16*)cur;  cur += aln((size_t)M * 256 * 2);
    bf16* Kb = (bf16*)cur;  cur += aln((size_t)M * 256 * 2);
    bf16* Vfb = (bf16*)cur; cur += aln((size_t)M * 512 * 2);   // fragment-major V
    bf16* GOb = (bf16*)cur; cur += aln((size_t)M * 512 * 2);   // silu(g) bf16, then OL f16
    bf16* Hfb = (bf16*)cur; cur += aln((size_t)2048 * 8192 * 2); // fragment-major H
    float* DDb = (float*)cur; cur += aln((size_t)2048 * 64 * 4);
    f16* Wtb = (f16*)cur;   cur += aln((size_t)2048 * 512 * 2);  // weights f16 [n][k]
    bf16* GKb = (bf16*)cur; cur += aln((size_t)M * 256 * 2);
    bf16* CSb = (bf16*)cur;                                     // 32 MB (S, bf16)
    f16* xh = (f16*)CSb;    // aliases CS: dead until chunk_state_k writes it

    const dim3 blk(256);
    cvt_xh_k<<<dim3(8192), blk, 0, stream>>>(x, xh);
    cvt_wt_k<<<dim3(32), blk, 0, stream>>>(Wq, Wk, Wv, Wg, Wo, Wtb);
    proj_gemm_k<<<dim3(256, 12), blk, 0, stream>>>(xh, Wtb, Qb, Kb, Vfb, GOb);
    gate_mfma_k<<<dim3(M / 128), blk, 0, stream>>>(xh, Wgk1, Wgk2, bgk2, GKb);
    chunk_state_k<<<dim3(2048), blk, 0, stream>>>(Kb, Vfb, GKb, CSb, DDb);
    scan_k<<<dim3(256), blk, 0, stream>>>(CSb, DDb, Hfb);
    chunk_out_k<<<dim3(2048), blk, 0, stream>>>(Qb, Kb, Vfb, GKb, Hfb, GOb);
    gemm_bt_k<<<dim3(256, 4), blk, 0, stream>>>((const f16*)GOb,
                                                Wtb + (size_t)1536 * 512, out);
}

extern "C" void kernel_launch(void* const* d_in, const int* in_sizes, int n_in,
                              void* d_out, int out_size, void* d_ws, size_t ws_size,
                              hipStream_t stream)
{
    const float* x    = (const float*)d_in[0];
    const float* Wq   = (const float*)d_in[1];
    const float* Wk   = (const float*)d_in[2];
    const float* Wv   = (const float*)d_in[3];
    const float* Wg   = (const float*)d_in[4];
    const float* Wgk1 = (const float*)d_in[5];
    const float* Wgk2 = (const float*)d_in[6];
    const float* bgk2 = (const float*)d_in[7];
    const float* Wo   = (const float*)d_in[8];
    float* out = (float*)d_out;

    const size_t M = 32768;
    const size_t slack = 8192;
    // Q,K + Vf + GO + Hf + DD + Wt + GK(bf16) + CS(bf16) ~ 179 MB
    const size_t need = 2 * M * 256 * 2 + 2 * M * 512 * 2
                      + (size_t)2048 * 8192 * 2 + 2048 * 64 * 4
                      + (size_t)2048 * 512 * 2 + M * 256 * 2
                      + (size_t)2048 * 8192 * 2 + slack;

    if (ws_size >= need) {
        run_all(x, Wq, Wk, Wv, Wg, Wgk1, Wgk2, bgk2, Wo,
                out, (char*)d_ws, stream);
    } else {
        zero_k<<<dim3((out_size + 255) / 256), dim3(256), 0, stream>>>(out, out_size);
    }
}

// Round 10
// 358.465 us; speedup vs baseline: 3.7746x; 1.0201x over previous
//
#include <hip/hip_runtime.h>
#include <hip/hip_bf16.h>

// GLA forward for MI355X. Inputs fp32, OUTPUT fp32. Pipeline:
//  0) cvt_xh_k: x (fp32) -> xh (f16) once; xh aliases CS workspace.
//     cvt_wt_k: [Wq|Wk|Wv|Wg|Wo] fp32 [k][n] -> Wt f16 [n][k] (2048x512, 2MB)
//  1) proj_gemm_k: ONE GEMM M=32768 x N=1536 over Wt rows 0..1535, BK=64,
//     global_load_lds staging, both-sides XOR swizzle, DEFAULT block order
//     (same-bm blocks land on same XCD since 256%8==0 -> A-panel L2 affinity;
//     round-9 XCD swizzle broke this: fetch 86->199MB). Per-segment epilogue:
//     Q(*1/8)->bf16, K->bf16, V->FRAGMENT-MAJOR Vf, G->silu->bf16.
//  2) gate_mfma_k: gk = log_sigmoid((xh@Wgk1)@Wgk2 + b)/16 -> bf16
//  3) chunk_state_k: per-(b,h,chunk=64) local state S^T[v][k] (bf16) + D
//  4) scan_k: affine scan over chunks -> chunk-start states H_n -> Hf
//     (bf16 FRAGMENT-MAJOR); fp32 accumulation in-register
//  5) chunk_out_k: o = q*e^B @ H + causal intra attention @ V (bf16 MFMA),
//     fused per-head LayerNorm * precomputed silu(g) -> OL (f16, same buffer)
//  6) gemm_bt_k: out = OL(f16) @ Wo (Wt rows 1536..2047, fp32 out), same core
// Fragment-major layout for a [v][t] (128x64) bf16 matrix consumed as MFMA
// operands: off(v,t) = frag*512 + lane*8 + elem -> per-wave fragment load is
// one contiguous 1KB transaction. Same convention on both MFMA operands =>
// contraction exact regardless of HW k-ordering.

typedef __hip_bfloat16 bf16;
typedef _Float16 f16;
typedef _Float16 half8 __attribute__((ext_vector_type(8)));
typedef float f32x4 __attribute__((ext_vector_type(4)));
typedef short short8 __attribute__((ext_vector_type(8)));

#define DEV static __device__ __forceinline__

DEV float b2f(bf16 v) { return __bfloat162float(v); }
DEV bf16 f2b(float v) { return __float2bfloat16(v); }
DEV float bits2f(unsigned int u16) {
    union { unsigned int u; float f; } c; c.u = u16 << 16; return c.f;
}
DEV short f2bs(float v) {
    union { bf16 h; short s; } u; u.h = __float2bfloat16(v); return u.s;
}
DEV unsigned short f2bu(float v) {
    union { bf16 h; unsigned short s; } u; u.h = __float2bfloat16(v); return u.s;
}
DEV short f2hs(float v) {                 // fp32 -> f16 bits
    union { f16 h; short s; } u; u.h = (f16)v; return u.s;
}
DEV float fast_rcp(float v) { return __builtin_amdgcn_rcpf(v); }

DEV float ldf(const float* p) { return *p; }
DEV float ldf(const bf16* p) { return b2f(*p); }
DEV void stf(float* p, float v) { *p = v; }
DEV void stf(bf16* p, float v) { *p = f2b(v); }

DEV float4 ld4(const float* p) { return *(const float4*)p; }
DEV float4 ld4(const bf16* p) {
    const uint2 r = *(const uint2*)p;
    return make_float4(bits2f(r.x & 0xffffu), bits2f(r.x >> 16),
                       bits2f(r.y & 0xffffu), bits2f(r.y >> 16));
}

DEV half8 ld8h(const float* p) {
    const float4 a = *(const float4*)p, b = *(const float4*)(p + 4);
    half8 h;
    h[0] = (f16)a.x; h[1] = (f16)a.y; h[2] = (f16)a.z; h[3] = (f16)a.w;
    h[4] = (f16)b.x; h[5] = (f16)b.y; h[6] = (f16)b.z; h[7] = (f16)b.w;
    return h;
}
DEV half8 ld8h(const f16* p) { return *(const half8*)p; }

DEV f32x4 mfma_bf(short8 a, short8 b, f32x4 c) {
    return __builtin_amdgcn_mfma_f32_16x16x32_bf16(a, b, c, 0, 0, 0);
}
DEV f32x4 mfma_h(half8 a, half8 b, f32x4 c) {
    return __builtin_amdgcn_mfma_f32_16x16x32_f16(a, b, c, 0, 0, 0);
}

// async global->LDS copy, 16B/lane; LDS dest wave-uniform base + lane*16.
DEV void gl_lds16(const f16* g, f16* l) {
    __builtin_amdgcn_global_load_lds(
        (const __attribute__((address_space(1))) void*)g,
        (__attribute__((address_space(3))) void*)l, 16, 0, 0);
}

// fragment-major offset for a 128x64 [v][t] operand matrix
DEV size_t voff(int v, int t) {
    return (size_t)(((((v >> 4) * 2 + (t >> 5)) * 4 + ((t >> 3) & 3)) * 16
                     + (v & 15)) * 8 + (t & 7));
}

// ---------------------------------------------------------------------------
// x (fp32) -> xh (f16), 8 elems/thread
// ---------------------------------------------------------------------------
__global__ __launch_bounds__(256) void cvt_xh_k(
    const float* __restrict__ x, f16* __restrict__ xh)
{
    const size_t i = ((size_t)blockIdx.x * 256 + threadIdx.x) * 8;
    *(half8*)&xh[i] = ld8h(&x[i]);
}

// ---------------------------------------------------------------------------
// Weights -> Wt f16 [n][k] (2048 rows): [0,256)=Wq [256,512)=Wk
// [512,1024)=Wv [1024,1536)=Wg [1536,2048)=Wo. LDS transpose, 64-row blocks.
// ---------------------------------------------------------------------------
__global__ __launch_bounds__(256) void cvt_wt_k(
    const float* __restrict__ Wq, const float* __restrict__ Wk,
    const float* __restrict__ Wv, const float* __restrict__ Wg,
    const float* __restrict__ Wo, f16* __restrict__ Wt)
{
    __shared__ float tile[64][65];
    const int nb = blockIdx.x * 64;
    const int tid = threadIdx.x;
    const float* src; int nloc, N;
    if (nb < 256)       { src = Wq; N = 256; nloc = nb; }
    else if (nb < 512)  { src = Wk; N = 256; nloc = nb - 256; }
    else if (nb < 1024) { src = Wv; N = 512; nloc = nb - 512; }
    else if (nb < 1536) { src = Wg; N = 512; nloc = nb - 1024; }
    else                { src = Wo; N = 512; nloc = nb - 1536; }
    for (int k0 = 0; k0 < 512; k0 += 64) {
        for (int e = tid; e < 4096; e += 256) {
            const int i = e >> 6, j = e & 63;           // i: k, j: n
            tile[i][j] = src[(size_t)(k0 + i) * N + nloc + j];
        }
        __syncthreads();
        for (int e = tid; e < 4096; e += 256) {
            const int j = e >> 6, i = e & 63;           // coalesced over k
            Wt[(size_t)(nb + j) * 512 + k0 + i] = (f16)tile[i][j];
        }
        __syncthreads();
    }
}

// ---------------------------------------------------------------------------
// Combined projection GEMM: C_seg = xh @ Wt_seg. Tile 128x128, BK=64,
// 4 waves (2x2), 4x4 16x16 frags/wave. Staging = global_load_lds, LDS linear
// [128][64] f16, XOR swizzle slot^=(row&7) applied on the global SOURCE addr
// and on the fragment ds_read (row&7 == lane&7 in both cases).
// D: col=lane&15, row=4*(lane>>4)+reg (HW-verified).
// Segments by bn>>8: 0=Q(*0.125) 1=K 2,3=V(frag-major) 4,5=G(silu).
// DEFAULT block order (no XCD swizzle): same-bm blocks are 256 apart in flat
// id, 256%8==0 -> same XCD -> A-panel reuse stays in one L2.
// ---------------------------------------------------------------------------
__global__ __launch_bounds__(256) void proj_gemm_k(
    const f16* __restrict__ A, const f16* __restrict__ Wt,
    bf16* __restrict__ Qb, bf16* __restrict__ Kb,
    bf16* __restrict__ VF, bf16* __restrict__ GOb)
{
    __shared__ __align__(16) f16 As[128][64];
    __shared__ __align__(16) f16 Bs[128][64];
    const int bm = blockIdx.x * 128;
    const int bn = blockIdx.y * 128;
    const int tid = threadIdx.x;
    const int lane = tid & 63;
    const int wid = tid >> 6;
    const int wr = wid >> 1, wc = wid & 1;
    const int al = lane & 15;
    const int kg = lane >> 4;
    const int al7 = al & 7;

    f32x4 acc[4][4];
#pragma unroll
    for (int m = 0; m < 4; ++m)
#pragma unroll
        for (int n = 0; n < 4; ++n)
#pragma unroll
            for (int r = 0; r < 4; ++r) acc[m][n][r] = 0.f;

    // staging: wave w covers rows w*32..w*32+31 (4 instrs x 8 rows);
    // lane -> row w*32+i*8+(lane>>3), slot (lane&7); src slot ^= row&7.
    const int srow = wid * 32 + (lane >> 3);
    const int sswz = ((lane & 7) ^ (lane >> 3)) << 3;   // f16 elements
    const f16* ap = A + (size_t)(bm + srow) * 512 + sswz;
    const f16* bp = Wt + (size_t)(bn + srow) * 512 + sswz;

    for (int k0 = 0; k0 < 512; k0 += 64) {
        if (k0) __syncthreads();          // readers of previous tile done
#pragma unroll
        for (int i = 0; i < 4; ++i) {
            gl_lds16(ap + (size_t)i * 8 * 512 + k0, &As[wid * 32 + i * 8][0]);
            gl_lds16(bp + (size_t)i * 8 * 512 + k0, &Bs[wid * 32 + i * 8][0]);
        }
        __syncthreads();                  // vmcnt drained before barrier
#pragma unroll
        for (int ks = 0; ks < 2; ++ks) {
            half8 af[4], bfr[4];
            const int sp = ((ks * 4 + kg) ^ al7) << 3;
#pragma unroll
            for (int m = 0; m < 4; ++m)
                af[m] = *(const half8*)&As[wr * 64 + m * 16 + al][sp];
#pragma unroll
            for (int n = 0; n < 4; ++n)
                bfr[n] = *(const half8*)&Bs[wc * 64 + n * 16 + al][sp];
#pragma unroll
            for (int m = 0; m < 4; ++m)
#pragma unroll
                for (int n = 0; n < 4; ++n)
                    acc[m][n] = mfma_h(af[m], bfr[n], acc[m][n]);
        }
    }

    const int r00 = bm + wr * 64 + kg * 4;
    const int c00 = bn + wc * 64 + al;
    const int seg = bn >> 8;
    if (seg == 0) {            // Q, scale 1/8
#pragma unroll
        for (int m = 0; m < 4; ++m)
#pragma unroll
            for (int n = 0; n < 4; ++n)
#pragma unroll
                for (int r = 0; r < 4; ++r)
                    stf(&Qb[(size_t)(r00 + m * 16 + r) * 256 + c00 + n * 16],
                        acc[m][n][r] * 0.125f);
    } else if (seg == 1) {     // K
#pragma unroll
        for (int m = 0; m < 4; ++m)
#pragma unroll
            for (int n = 0; n < 4; ++n)
#pragma unroll
                for (int r = 0; r < 4; ++r)
                    stf(&Kb[(size_t)(r00 + m * 16 + r) * 256 + (c00 - 256) + n * 16],
                        acc[m][n][r]);
    } else if (seg <= 3) {     // V, fragment-major packed store
#pragma unroll
        for (int m = 0; m < 4; ++m) {
            const int row0 = r00 + m * 16;
            const int bi = row0 >> 14;
            const int chunk = (row0 >> 6) & 255;
            const int tc = row0 & 63;
#pragma unroll
            for (int n = 0; n < 4; ++n) {
                const int col = c00 - 512 + n * 16;
                const int h = col >> 7, v = col & 127;
                bf16* dst = VF + (size_t)((bi * 4 + h) * 256 + chunk) * 8192
                               + voff(v, tc);
                ushort4 pk;
                pk.x = f2bu(acc[m][n][0]); pk.y = f2bu(acc[m][n][1]);
                pk.z = f2bu(acc[m][n][2]); pk.w = f2bu(acc[m][n][3]);
                *(ushort4*)dst = pk;
            }
        }
    } else {                   // G, silu
#pragma unroll
        for (int m = 0; m < 4; ++m)
#pragma unroll
            for (int n = 0; n < 4; ++n)
#pragma unroll
                for (int r = 0; r < 4; ++r) {
                    const float v = acc[m][n][r];
                    const float sil = v * fast_rcp(1.f + __expf(-v));
                    stf(&GOb[(size_t)(r00 + m * 16 + r) * 512 + (c00 - 1024) + n * 16],
                        sil);
                }
    }
}

// ---------------------------------------------------------------------------
// Output GEMM: C[M,512] = OL(f16)[M,512] @ Wo via Wt rows [1536,2048).
// Same BK=64 global_load_lds + swizzle core, default block order. fp32 out.
// ---------------------------------------------------------------------------
__global__ __launch_bounds__(256) void gemm_bt_k(
    const f16* __restrict__ A, const f16* __restrict__ Bt,
    float* __restrict__ C)
{
    __shared__ __align__(16) f16 As[128][64];
    __shared__ __align__(16) f16 Bs[128][64];
    const int bm = blockIdx.x * 128;
    const int bn = blockIdx.y * 128;
    const int tid = threadIdx.x;
    const int lane = tid & 63;
    const int wid = tid >> 6;
    const int wr = wid >> 1, wc = wid & 1;
    const int al = lane & 15;
    const int kg = lane >> 4;
    const int al7 = al & 7;

    f32x4 acc[4][4];
#pragma unroll
    for (int m = 0; m < 4; ++m)
#pragma unroll
        for (int n = 0; n < 4; ++n)
#pragma unroll
            for (int r = 0; r < 4; ++r) acc[m][n][r] = 0.f;

    const int srow = wid * 32 + (lane >> 3);
    const int sswz = ((lane & 7) ^ (lane >> 3)) << 3;
    const f16* ap = A + (size_t)(bm + srow) * 512 + sswz;
    const f16* bp = Bt + (size_t)(bn + srow) * 512 + sswz;

    for (int k0 = 0; k0 < 512; k0 += 64) {
        if (k0) __syncthreads();
#pragma unroll
        for (int i = 0; i < 4; ++i) {
            gl_lds16(ap + (size_t)i * 8 * 512 + k0, &As[wid * 32 + i * 8][0]);
            gl_lds16(bp + (size_t)i * 8 * 512 + k0, &Bs[wid * 32 + i * 8][0]);
        }
        __syncthreads();
#pragma unroll
        for (int ks = 0; ks < 2; ++ks) {
            half8 af[4], bfr[4];
            const int sp = ((ks * 4 + kg) ^ al7) << 3;
#pragma unroll
            for (int m = 0; m < 4; ++m)
                af[m] = *(const half8*)&As[wr * 64 + m * 16 + al][sp];
#pragma unroll
            for (int n = 0; n < 4; ++n)
                bfr[n] = *(const half8*)&Bs[wc * 64 + n * 16 + al][sp];
#pragma unroll
            for (int m = 0; m < 4; ++m)
#pragma unroll
                for (int n = 0; n < 4; ++n)
                    acc[m][n] = mfma_h(af[m], bfr[n], acc[m][n]);
        }
    }
    const int r0 = bm + wr * 64 + kg * 4;
    const int c0 = bn + wc * 64 + al;
#pragma unroll
    for (int m = 0; m < 4; ++m)
#pragma unroll
        for (int n = 0; n < 4; ++n)
#pragma unroll
            for (int r = 0; r < 4; ++r)
                C[(size_t)(r0 + m * 16 + r) * 512 + c0 + n * 16] = acc[m][n][r];
}

// ---------------------------------------------------------------------------
// gate: gk = log_sigmoid((xh @ Wgk1) @ Wgk2 + bgk2) / 16 -> bf16
// Block = 128 rows. Stage 1 (K=512, N=16) on f16 MFMA, Wgk1 in LDS [n][k].
// Stage 2: thread owns column c=tid; Wgk2 reads coalesced.
// ---------------------------------------------------------------------------
__global__ __launch_bounds__(256) void gate_mfma_k(
    const f16* __restrict__ xh, const float* __restrict__ Wgk1,
    const float* __restrict__ Wgk2, const float* __restrict__ bgk2,
    bf16* __restrict__ GK)
{
    __shared__ __align__(16) f16 As[128][40];
    __shared__ __align__(16) f16 w1s[16][520];   // Wgk1^T [n][k], padded
    __shared__ float tls[128][17];               // tl fp32
    const int bm = blockIdx.x * 128;
    const int tid = threadIdx.x;
    const int lane = tid & 63;
    const int wid = tid >> 6;
    const int al = lane & 15;
    const int kg = lane >> 4;
    const int kg8 = kg * 8;

    for (int e = tid; e < 8192; e += 256) {
        const int kk = e >> 4, n = e & 15;
        w1s[n][kk] = (f16)Wgk1[e];
    }

    f32x4 acc[2];
#pragma unroll
    for (int m = 0; m < 2; ++m)
#pragma unroll
        for (int r = 0; r < 4; ++r) acc[m][r] = 0.f;

    const int ar = tid >> 1;
    const int ac = (tid & 1) * 16;
    for (int k0 = 0; k0 < 512; k0 += 32) {
        {
            const f16* ap = xh + (size_t)(bm + ar) * 512 + k0 + ac;
            *(half8*)&As[ar][ac] = *(const half8*)ap;
            *(half8*)&As[ar][ac + 8] = *(const half8*)(ap + 8);
        }
        __syncthreads();
        const half8 bfr = *(const half8*)&w1s[al][k0 + kg8];
#pragma unroll
        for (int m = 0; m < 2; ++m) {
            const half8 af = *(const half8*)&As[wid * 32 + m * 16 + al][kg8];
            acc[m] = mfma_h(af, bfr, acc[m]);
        }
        __syncthreads();
    }
#pragma unroll
    for (int m = 0; m < 2; ++m)
#pragma unroll
        for (int r = 0; r < 4; ++r)
            tls[wid * 32 + m * 16 + kg * 4 + r][al] = acc[m][r];
    __syncthreads();

    float w2[16];
#pragma unroll
    for (int r = 0; r < 16; ++r) w2[r] = Wgk2[r * 256 + tid];
    const float bb = bgk2[tid];
    bf16* gout = GK + (size_t)bm * 256 + tid;
    for (int m = 0; m < 128; ++m) {
        float z = bb;
#pragma unroll
        for (int r = 0; r < 16; ++r) z = fmaf(tls[m][r], w2[r], z);
        const float ls = fminf(z, 0.f) - __logf(1.f + __expf(-fabsf(z)));
        stf(&gout[(size_t)m * 256], ls * (1.f / 16.f));
    }
}

// ---------------------------------------------------------------------------
// Per-chunk local state via MFMA: CS[blk][v*64+k] = S^T[v][k] (bf16)
//   = sum_t V[t][v] * (k_t[k] e^{d63[k]-g_t[k]}) ; DD[blk][k] = e^{d63[k]}.
// ---------------------------------------------------------------------------
__global__ __launch_bounds__(256) void chunk_state_k(
    const bf16* __restrict__ Km, const bf16* __restrict__ VF,
    const bf16* __restrict__ GKm, bf16* __restrict__ CS,
    float* __restrict__ DD)
{
    __shared__ __align__(16) short k2t[64][72];   // [k][t] bf16
    __shared__ float cpart[4][64];
    const int blk = blockIdx.x;
    const int chunk = blk & 255;
    const int bh = blk >> 8;
    const int bi = bh >> 2, h = bh & 3;
    const int rowbase = bi * 16384 + chunk * 64;
    const int tid = threadIdx.x;
    const int k = tid & 63, tg = tid >> 6;

    float g[16];
    {
        float run = 0.f;
#pragma unroll
        for (int j = 0; j < 16; ++j) {
            run += ldf(&GKm[(size_t)(rowbase + tg * 16 + j) * 256 + h * 64 + k]);
            g[j] = run;
        }
        cpart[tg][k] = run;
    }
    __syncthreads();
    float off = 0.f;
#pragma unroll
    for (int s = 0; s < 3; ++s) if (s < tg) off += cpart[s][k];
    const float tot = cpart[0][k] + cpart[1][k] + cpart[2][k] + cpart[3][k];
    if (tg == 0) DD[(size_t)blk * 64 + k] = __expf(tot);

    {
        short8 p0, p1;
#pragma unroll
        for (int j = 0; j < 16; ++j) {
            const float kv = ldf(&Km[(size_t)(rowbase + tg * 16 + j) * 256 + h * 64 + k]);
            const float w = kv * __expf(tot - (g[j] + off));   // decay <= 1
            if (j < 8) p0[j] = f2bs(w); else p1[j - 8] = f2bs(w);
        }
        *(short8*)&k2t[k][tg * 16] = p0;
        *(short8*)&k2t[k][tg * 16 + 8] = p1;
    }
    __syncthreads();

    const int lane = tid & 63, wid = tid >> 6;
    const int al = lane & 15, kg = lane >> 4, kg8 = kg * 8;
    const bf16* Vtb = VF + (size_t)blk * 8192;

    short8 xf[2][2];
#pragma unroll
    for (int m = 0; m < 2; ++m)
#pragma unroll
        for (int ks = 0; ks < 2; ++ks)
            xf[m][ks] = *(const short8*)&Vtb[(size_t)(((wid * 2 + m) * 2 + ks) * 64 + lane) * 8];
    short8 yf[2][4];
#pragma unroll
    for (int ks = 0; ks < 2; ++ks)
#pragma unroll
        for (int n = 0; n < 4; ++n)
            yf[ks][n] = *(const short8*)&k2t[n * 16 + al][ks * 32 + kg8];

    f32x4 acc[2][4];
#pragma unroll
    for (int m = 0; m < 2; ++m)
#pragma unroll
        for (int n = 0; n < 4; ++n)
#pragma unroll
            for (int r = 0; r < 4; ++r) acc[m][n][r] = 0.f;
#pragma unroll
    for (int ks = 0; ks < 2; ++ks)
#pragma unroll
        for (int m = 0; m < 2; ++m)
#pragma unroll
            for (int n = 0; n < 4; ++n)
                acc[m][n] = mfma_bf(xf[m][ks], yf[ks][n], acc[m][n]);

    bf16* out = CS + (size_t)blk * 8192;
#pragma unroll
    for (int m = 0; m < 2; ++m)
#pragma unroll
        for (int n = 0; n < 4; ++n)
#pragma unroll
            for (int r = 0; r < 4; ++r)
                stf(&out[(size_t)(wid * 32 + m * 16 + kg * 4 + r) * 64 + n * 16 + al],
                    acc[m][n][r]);
}

// ---------------------------------------------------------------------------
// Affine scan over chunks: H_{n+1}=D_n H_n+S_n. Reads S (bf16), accumulates
// fp32 in-register, writes H_n to Hf (bf16, fragment-major).
// ---------------------------------------------------------------------------
__global__ __launch_bounds__(256) void scan_k(
    const bf16* __restrict__ CS, const float* __restrict__ DD,
    bf16* __restrict__ HF)
{
    const int bh = blockIdx.x >> 5;
    const int slice = blockIdx.x & 31;
    const int tid = threadIdx.x;
    const int e = slice * 256 + tid;
    const int v = e >> 6, k = e & 63;
    float H = 0.f;
    const bf16* base = CS + (size_t)bh * 256 * 8192 + e;
    bf16* hbase = HF + (size_t)bh * 256 * 8192 + voff(v, k);
    const float* dbase = DD + (size_t)bh * 256 * 64 + k;
#pragma unroll 4
    for (int n = 0; n < 256; ++n) {
        const float s = ldf(&base[(size_t)n * 8192]);
        const float d = dbase[(size_t)n * 64];
        stf(&hbase[(size_t)n * 8192], H);
        H = fmaf(d, H, s);
    }
}

// ---------------------------------------------------------------------------
// Per-chunk output via MFMA + fused LayerNorm * precomputed silu(g).
// Writes OL as F16 bits into the GO buffer (consumed by gemm_bt_k as f16).
// ---------------------------------------------------------------------------
__global__ __launch_bounds__(256) void chunk_out_k(
    const bf16* __restrict__ Qm, const bf16* __restrict__ Km,
    const bf16* __restrict__ VF, const bf16* __restrict__ GKm,
    const bf16* __restrict__ HF, bf16* GO)
{
    __shared__ __align__(16) short qs[64][72];   // q*e^g   (bf16)
    __shared__ __align__(16) short ks[64][72];   // k*e^-g  (bf16)
    __shared__ __align__(16) short ab[64][72];   // causal A (bf16)
    __shared__ float cpart[4][64];

    const int blk = blockIdx.x;
    const int chunk = blk & 255;
    const int bh = blk >> 8;
    const int bi = bh >> 2, h = bh & 3;
    const int rowbase = bi * 16384 + chunk * 64;
    const int tid = threadIdx.x;
    const int k = tid & 63, tg = tid >> 6;

    float g[16];
    {
        float run = 0.f;
#pragma unroll
        for (int j = 0; j < 16; ++j) {
            run += ldf(&GKm[(size_t)(rowbase + tg * 16 + j) * 256 + h * 64 + k]);
            g[j] = run;
        }
        cpart[tg][k] = run;
    }
    __syncthreads();
    float off = 0.f;
#pragma unroll
    for (int s = 0; s < 3; ++s) if (s < tg) off += cpart[s][k];

#pragma unroll
    for (int j = 0; j < 16; ++j) {
        const int t = tg * 16 + j;
        const size_t idx = (size_t)(rowbase + t) * 256 + h * 64 + k;
        const float gc = g[j] + off;
        const float eg = __expf(gc);
        qs[t][k] = f2bs(ldf(&Qm[idx]) * eg);
        ks[t][k] = f2bs(ldf(&Km[idx]) * fast_rcp(eg));
    }
    __syncthreads();

    const int lane = tid & 63, wid = tid >> 6;
    const int al = lane & 15, kg = lane >> 4;
    const int w16 = wid * 16, kg8 = kg * 8;

    short8 xq[2];
    xq[0] = *(const short8*)&qs[w16 + al][kg8];
    xq[1] = *(const short8*)&qs[w16 + al][32 + kg8];

    f32x4 aacc[4];
#pragma unroll
    for (int n = 0; n < 4; ++n)
#pragma unroll
        for (int r = 0; r < 4; ++r) aacc[n][r] = 0.f;
#pragma unroll
    for (int ksb = 0; ksb < 2; ++ksb)
#pragma unroll
        for (int n = 0; n < 4; ++n) {
            const short8 y = *(const short8*)&ks[n * 16 + al][ksb * 32 + kg8];
            aacc[n] = mfma_bf(xq[ksb], y, aacc[n]);
        }
#pragma unroll
    for (int n = 0; n < 4; ++n)
#pragma unroll
        for (int r = 0; r < 4; ++r) {
            const int tt = w16 + kg * 4 + r;
            const int ii = n * 16 + al;
            ab[tt][ii] = (ii <= tt) ? f2bs(aacc[n][r]) : (short)0;
        }
    short8 xa[2];
    xa[0] = *(const short8*)&ab[w16 + al][kg8];
    xa[1] = *(const short8*)&ab[w16 + al][32 + kg8];

    const bf16* Vtb = VF + (size_t)blk * 8192;
    const bf16* Hb = HF + (size_t)blk * 8192;
    f32x4 oacc[8];
#pragma unroll
    for (int n = 0; n < 8; ++n)
#pragma unroll
        for (int r = 0; r < 4; ++r) oacc[n][r] = 0.f;
#pragma unroll
    for (int n = 0; n < 8; ++n) {
        const size_t f0 = (size_t)((n * 2 + 0) * 64 + lane) * 8;
        const size_t f1 = (size_t)((n * 2 + 1) * 64 + lane) * 8;
        const short8 yv0 = *(const short8*)&Vtb[f0];
        const short8 yv1 = *(const short8*)&Vtb[f1];
        const short8 yh0 = *(const short8*)&Hb[f0];
        const short8 yh1 = *(const short8*)&Hb[f1];
        oacc[n] = mfma_bf(xa[0], yv0, oacc[n]);
        oacc[n] = mfma_bf(xa[1], yv1, oacc[n]);
        oacc[n] = mfma_bf(xq[0], yh0, oacc[n]);
        oacc[n] = mfma_bf(xq[1], yh1, oacc[n]);
    }

    float psum[4] = {0.f, 0.f, 0.f, 0.f}, psq[4] = {0.f, 0.f, 0.f, 0.f};
#pragma unroll
    for (int n = 0; n < 8; ++n)
#pragma unroll
        for (int r = 0; r < 4; ++r) {
            const float v = oacc[n][r];
            psum[r] += v; psq[r] = fmaf(v, v, psq[r]);
        }
#pragma unroll
    for (int offx = 1; offx < 16; offx <<= 1)
#pragma unroll
        for (int r = 0; r < 4; ++r) {
            psum[r] += __shfl_xor(psum[r], offx);
            psq[r] += __shfl_xor(psq[r], offx);
        }
#pragma unroll
    for (int r = 0; r < 4; ++r) {
        const float mu = psum[r] * (1.f / 128.f);
        const float var = psq[r] * (1.f / 128.f) - mu * mu;
        const float rstd = rsqrtf(fmaxf(var, 0.f) + 1e-5f);
        const int row = rowbase + w16 + kg * 4 + r;
        short* gop = (short*)(GO + (size_t)row * 512 + h * 128 + al);
#pragma unroll
        for (int n = 0; n < 8; ++n) {
            const bf16 gb = *(const bf16*)&gop[n * 16];
            const float sil = b2f(gb);                  // silu(g), precomputed
            gop[n * 16] = f2hs((oacc[n][r] - mu) * rstd * sil);  // OL as f16
        }
    }
}

__global__ __launch_bounds__(256) void zero_k(float* out, int n) {
    const int i = blockIdx.x * 256 + threadIdx.x;
    if (i < n) out[i] = 0.f;
}

// ---------------------------------------------------------------------------
static void run_all(const float* x, const float* Wq, const float* Wk,
                    const float* Wv, const float* Wg, const float* Wgk1,
                    const float* Wgk2, const float* bgk2, const float* Wo,
                    float* out, char* ws, hipStream_t stream)
{
    const int M = 32768;  // B*S
    auto aln = [](size_t v) { return (v + 255) & ~(size_t)255; };
    char* cur = ws;
    bf16* Qb = (bf16*)cur;  cur += aln((size_t)M * 256 * 2);
    bf16* Kb = (bf16*)cur;  cur += aln((size_t)M * 256 * 2);
    bf16* Vfb = (bf16*)cur; cur += aln((size_t)M * 512 * 2);   // fragment-major V
    bf16* GOb = (bf16*)cur; cur += aln((size_t)M * 512 * 2);   // silu(g) bf16, then OL f16
    bf16* Hfb = (bf16*)cur; cur += aln((size_t)2048 * 8192 * 2); // fragment-major H
    float* DDb = (float*)cur; cur += aln((size_t)2048 * 64 * 4);
    f16* Wtb = (f16*)cur;   cur += aln((size_t)2048 * 512 * 2);  // weights f16 [n][k]
    bf16* GKb = (bf16*)cur; cur += aln((size_t)M * 256 * 2);
    bf16* CSb = (bf16*)cur;                                     // 32 MB (S, bf16)
    f16* xh = (f16*)CSb;    // aliases CS: dead until chunk_state_k writes it

    const dim3 blk(256);
    cvt_xh_k<<<dim3(8192), blk, 0, stream>>>(x, xh);
    cvt_wt_k<<<dim3(32), blk, 0, stream>>>(Wq, Wk, Wv, Wg, Wo, Wtb);
    proj_gemm_k<<<dim3(M / 128, 12), blk, 0, stream>>>(xh, Wtb, Qb, Kb, Vfb, GOb);
    gate_mfma_k<<<dim3(M / 128), blk, 0, stream>>>(xh, Wgk1, Wgk2, bgk2, GKb);
    chunk_state_k<<<dim3(2048), blk, 0, stream>>>(Kb, Vfb, GKb, CSb, DDb);
    scan_k<<<dim3(256), blk, 0, stream>>>(CSb, DDb, Hfb);
    chunk_out_k<<<dim3(2048), blk, 0, stream>>>(Qb, Kb, Vfb, GKb, Hfb, GOb);
    gemm_bt_k<<<dim3(M / 128, 4), blk, 0, stream>>>((const f16*)GOb,
                                                    Wtb + (size_t)1536 * 512, out);
}

extern "C" void kernel_launch(void* const* d_in, const int* in_sizes, int n_in,
                              void* d_out, int out_size, void* d_ws, size_t ws_size,
                              hipStream_t stream)
{
    const float* x    = (const float*)d_in[0];
    const float* Wq   = (const float*)d_in[1];
    const float* Wk   = (const float*)d_in[2];
    const float* Wv   = (const float*)d_in[3];
    const float* Wg   = (const float*)d_in[4];
    const float* Wgk1 = (const float*)d_in[5];
    const float* Wgk2 = (const float*)d_in[6];
    const float* bgk2 = (const float*)d_in[7];
    const float* Wo   = (const float*)d_in[8];
    float* out = (float*)d_out;

    const size_t M = 32768;
    const size_t slack = 8192;
    // Q,K + Vf + GO + Hf + DD + Wt + GK(bf16) + CS(bf16) ~ 179 MB
    const size_t need = 2 * M * 256 * 2 + 2 * M * 512 * 2
                      + (size_t)2048 * 8192 * 2 + 2048 * 64 * 4
                      + (size_t)2048 * 512 * 2 + M * 256 * 2
                      + (size_t)2048 * 8192 * 2 + slack;

    if (ws_size >= need) {
        run_all(x, Wq, Wk, Wv, Wg, Wgk1, Wgk2, bgk2, Wo,
                out, (char*)d_ws, stream);
    } else {
        zero_k<<<dim3((out_size + 255) / 256), dim3(256), 0, stream>>>(out, out_size);
    }
}

// Round 11
// 353.654 us; speedup vs baseline: 3.8259x; 1.0136x over previous
//
#include <hip/hip_runtime.h>
#include <hip/hip_bf16.h>

// GLA forward for MI355X. Inputs fp32, OUTPUT fp32. Pipeline:
//  0) cvt_xh_k: x (fp32) -> xh (f16) once; xh aliases CS workspace.
//     cvt_wt_k: [Wq|Wk|Wv|Wg|Wo] fp32 [k][n] -> Wf f16 FRAGMENT-MAJOR:
//     flat(n,k) = (((pan*8+kstep)*2+ks)*8+nblk)*512 + (kg*16+al)*8 + e
//     (pan=n>>7, nblk=(n>>4)&7, al=n&15; kstep=k>>6, ks=(k>>5)&1, kg=(k>>3)&3,
//      e=k&7) -> per-wave B-fragment load = one contiguous 1KB transaction,
//     L2-hot (2MB total). B never goes through LDS.
//  1) proj_gemm_k: ONE GEMM M=32768 x N=1536 (pans 0..11), BK=64. A staged
//     via global_load_lds (16KB LDS, both-sides XOR swizzle); B fragments
//     straight from Wf. DEFAULT block order (same-bm blocks 256 apart in
//     flat id -> same XCD -> A-panel L2 affinity; round-9 lesson).
//     Per-segment epilogue: Q(*1/8)->bf16, K->bf16, V->frag-major Vf,
//     G->silu->bf16.
//  2) gate_mfma_k: gk = log_sigmoid((xh@Wgk1)@Wgk2 + b)/16 -> bf16
//  3) chunk_state_k: per-(b,h,chunk=64) local state S^T[v][k] (bf16) + D
//  4) scan_k: affine scan over chunks -> chunk-start states H_n -> Hf
//     (bf16 FRAGMENT-MAJOR); fp32 accumulation in-register
//  5) chunk_out_k: o = q*e^B @ H + causal intra attention @ V (bf16 MFMA),
//     fused per-head LayerNorm * precomputed silu(g) -> OL (f16, same buffer)
//  6) gemm_bt_k: out = OL(f16) @ Wo (pans 12..15 of Wf, fp32 out), same core
// Fragment-major layout for a [v][t] (128x64) bf16 matrix consumed as MFMA
// operands: off(v,t) = frag*512 + lane*8 + elem. Same per-lane k permutation
// on both MFMA operands => contraction exact regardless of HW k-ordering.

typedef __hip_bfloat16 bf16;
typedef _Float16 f16;
typedef _Float16 half8 __attribute__((ext_vector_type(8)));
typedef float f32x4 __attribute__((ext_vector_type(4)));
typedef short short8 __attribute__((ext_vector_type(8)));

#define DEV static __device__ __forceinline__

DEV float b2f(bf16 v) { return __bfloat162float(v); }
DEV bf16 f2b(float v) { return __float2bfloat16(v); }
DEV float bits2f(unsigned int u16) {
    union { unsigned int u; float f; } c; c.u = u16 << 16; return c.f;
}
DEV short f2bs(float v) {
    union { bf16 h; short s; } u; u.h = __float2bfloat16(v); return u.s;
}
DEV unsigned short f2bu(float v) {
    union { bf16 h; unsigned short s; } u; u.h = __float2bfloat16(v); return u.s;
}
DEV short f2hs(float v) {                 // fp32 -> f16 bits
    union { f16 h; short s; } u; u.h = (f16)v; return u.s;
}
DEV float fast_rcp(float v) { return __builtin_amdgcn_rcpf(v); }

DEV float ldf(const float* p) { return *p; }
DEV float ldf(const bf16* p) { return b2f(*p); }
DEV void stf(float* p, float v) { *p = v; }
DEV void stf(bf16* p, float v) { *p = f2b(v); }

DEV float4 ld4(const float* p) { return *(const float4*)p; }
DEV float4 ld4(const bf16* p) {
    const uint2 r = *(const uint2*)p;
    return make_float4(bits2f(r.x & 0xffffu), bits2f(r.x >> 16),
                       bits2f(r.y & 0xffffu), bits2f(r.y >> 16));
}

DEV half8 ld8h(const float* p) {
    const float4 a = *(const float4*)p, b = *(const float4*)(p + 4);
    half8 h;
    h[0] = (f16)a.x; h[1] = (f16)a.y; h[2] = (f16)a.z; h[3] = (f16)a.w;
    h[4] = (f16)b.x; h[5] = (f16)b.y; h[6] = (f16)b.z; h[7] = (f16)b.w;
    return h;
}
DEV half8 ld8h(const f16* p) { return *(const half8*)p; }

DEV f32x4 mfma_bf(short8 a, short8 b, f32x4 c) {
    return __builtin_amdgcn_mfma_f32_16x16x32_bf16(a, b, c, 0, 0, 0);
}
DEV f32x4 mfma_h(half8 a, half8 b, f32x4 c) {
    return __builtin_amdgcn_mfma_f32_16x16x32_f16(a, b, c, 0, 0, 0);
}

// async global->LDS copy, 16B/lane; LDS dest wave-uniform base + lane*16.
DEV void gl_lds16(const f16* g, f16* l) {
    __builtin_amdgcn_global_load_lds(
        (const __attribute__((address_space(1))) void*)g,
        (__attribute__((address_space(3))) void*)l, 16, 0, 0);
}

// fragment-major offset for a 128x64 [v][t] operand matrix
DEV size_t voff(int v, int t) {
    return (size_t)(((((v >> 4) * 2 + (t >> 5)) * 4 + ((t >> 3) & 3)) * 16
                     + (v & 15)) * 8 + (t & 7));
}

// ---------------------------------------------------------------------------
// x (fp32) -> xh (f16), 8 elems/thread
// ---------------------------------------------------------------------------
__global__ __launch_bounds__(256) void cvt_xh_k(
    const float* __restrict__ x, f16* __restrict__ xh)
{
    const size_t i = ((size_t)blockIdx.x * 256 + threadIdx.x) * 8;
    *(half8*)&xh[i] = ld8h(&x[i]);
}

// ---------------------------------------------------------------------------
// Weights -> Wf f16 FRAGMENT-MAJOR (16 pans x 8 ksteps x 2 ks x 8 nblk x
// 64 lanes x 8 elems = 1M f16 = 2MB). Pan rows: [0,2)=Wq [2,4)=Wk
// [4,8)=Wv [8,12)=Wg [12,16)=Wo. LDS transpose per 64-n x 64-k tile.
// ---------------------------------------------------------------------------
__global__ __launch_bounds__(256) void cvt_wt_k(
    const float* __restrict__ Wq, const float* __restrict__ Wk,
    const float* __restrict__ Wv, const float* __restrict__ Wg,
    const float* __restrict__ Wo, f16* __restrict__ Wf)
{
    __shared__ float tile[64][65];
    const int nb = blockIdx.x * 64;     // global n base (0..2047, 64-aligned)
    const int tid = threadIdx.x;
    const float* src; int nloc, N;
    if (nb < 256)       { src = Wq; N = 256; nloc = nb; }
    else if (nb < 512)  { src = Wk; N = 256; nloc = nb - 256; }
    else if (nb < 1024) { src = Wv; N = 512; nloc = nb - 512; }
    else if (nb < 1536) { src = Wg; N = 512; nloc = nb - 1024; }
    else                { src = Wo; N = 512; nloc = nb - 1536; }
    for (int k0 = 0; k0 < 512; k0 += 64) {
        for (int e = tid; e < 4096; e += 256) {
            const int i = e >> 6, j = e & 63;           // i: k-local, j: n-local
            tile[i][j] = src[(size_t)(k0 + i) * N + nloc + j];
        }
        __syncthreads();
        const int kstep = k0 >> 6;
        for (int ow = tid; ow < 512; ow += 256) {
            const int j = ow >> 3;                      // n-local
            const int i8 = ow & 7;                      // k-octet: ks=i8>>2, kg=i8&3
            const int n = nb + j;
            const int pan = n >> 7, nblk = (n >> 4) & 7, al = n & 15;
            half8 hv;
#pragma unroll
            for (int e = 0; e < 8; ++e) hv[e] = (f16)tile[i8 * 8 + e][j];
            const size_t flat =
                ((size_t)(((pan * 8 + kstep) * 2 + (i8 >> 2)) * 8 + nblk)) * 512
                + (size_t)(((i8 & 3) * 16 + al)) * 8;
            *(half8*)&Wf[flat] = hv;
        }
        __syncthreads();
    }
}

// ---------------------------------------------------------------------------
// Combined projection GEMM: C_seg = xh @ W_seg. Tile 128x128, BK=64,
// 4 waves (2x2), 4x4 16x16 frags/wave. A staged via global_load_lds into
// 16KB LDS with both-sides XOR swizzle (src slot ^= row&7; read slot
// (ks*4+kg)^(al&7)). B fragments read straight from frag-major Wf (L2-hot,
// barrier-free). D: col=lane&15, row=4*(lane>>4)+reg (HW-verified).
// Segments by bn>>8: 0=Q(*0.125) 1=K 2,3=V(frag-major) 4,5=G(silu).
// DEFAULT block order (no XCD swizzle) -> A-panel L2 affinity.
// ---------------------------------------------------------------------------
__global__ __launch_bounds__(256) void proj_gemm_k(
    const f16* __restrict__ A, const f16* __restrict__ Wf,
    bf16* __restrict__ Qb, bf16* __restrict__ Kb,
    bf16* __restrict__ VF, bf16* __restrict__ GOb)
{
    __shared__ __align__(16) f16 As[128][64];
    const int bm = blockIdx.x * 128;
    const int bn = blockIdx.y * 128;
    const int pan = bn >> 7;
    const int tid = threadIdx.x;
    const int lane = tid & 63;
    const int wid = tid >> 6;
    const int wr = wid >> 1, wc = wid & 1;
    const int al = lane & 15;
    const int kg = lane >> 4;
    const int al7 = al & 7;

    f32x4 acc[4][4];
#pragma unroll
    for (int m = 0; m < 4; ++m)
#pragma unroll
        for (int n = 0; n < 4; ++n)
#pragma unroll
            for (int r = 0; r < 4; ++r) acc[m][n][r] = 0.f;

    // A staging: wave w covers rows w*32..w*32+31 (4 instrs x 8 rows);
    // lane -> row w*32+i*8+(lane>>3), slot (lane&7); src slot ^= row&7.
    const int srow = wid * 32 + (lane >> 3);
    const int sswz = ((lane & 7) ^ (lane >> 3)) << 3;   // f16 elements
    const f16* ap = A + (size_t)(bm + srow) * 512 + sswz;
    // B fragment base for this wave-column
    const f16* wfb = Wf + (size_t)lane * 8;

    for (int k0 = 0; k0 < 512; k0 += 64) {
        if (k0) __syncthreads();          // readers of previous tile done
#pragma unroll
        for (int i = 0; i < 4; ++i)
            gl_lds16(ap + (size_t)i * 8 * 512 + k0, &As[wid * 32 + i * 8][0]);
        // B fragments from global (overlap with A DMA; drained by barrier)
        half8 bfr[2][4];
        const int kstep = k0 >> 6;
#pragma unroll
        for (int ks = 0; ks < 2; ++ks)
#pragma unroll
            for (int n = 0; n < 4; ++n)
                bfr[ks][n] = *(const half8*)&wfb[
                    (size_t)(((pan * 8 + kstep) * 2 + ks) * 8 + wc * 4 + n) * 512];
        __syncthreads();                  // vmcnt drained before barrier
#pragma unroll
        for (int ks = 0; ks < 2; ++ks) {
            half8 af[4];
            const int sp = ((ks * 4 + kg) ^ al7) << 3;
#pragma unroll
            for (int m = 0; m < 4; ++m)
                af[m] = *(const half8*)&As[wr * 64 + m * 16 + al][sp];
#pragma unroll
            for (int m = 0; m < 4; ++m)
#pragma unroll
                for (int n = 0; n < 4; ++n)
                    acc[m][n] = mfma_h(af[m], bfr[ks][n], acc[m][n]);
        }
    }

    const int r00 = bm + wr * 64 + kg * 4;
    const int c00 = bn + wc * 64 + al;
    const int seg = bn >> 8;
    if (seg == 0) {            // Q, scale 1/8
#pragma unroll
        for (int m = 0; m < 4; ++m)
#pragma unroll
            for (int n = 0; n < 4; ++n)
#pragma unroll
                for (int r = 0; r < 4; ++r)
                    stf(&Qb[(size_t)(r00 + m * 16 + r) * 256 + c00 + n * 16],
                        acc[m][n][r] * 0.125f);
    } else if (seg == 1) {     // K
#pragma unroll
        for (int m = 0; m < 4; ++m)
#pragma unroll
            for (int n = 0; n < 4; ++n)
#pragma unroll
                for (int r = 0; r < 4; ++r)
                    stf(&Kb[(size_t)(r00 + m * 16 + r) * 256 + (c00 - 256) + n * 16],
                        acc[m][n][r]);
    } else if (seg <= 3) {     // V, fragment-major packed store
#pragma unroll
        for (int m = 0; m < 4; ++m) {
            const int row0 = r00 + m * 16;
            const int bi = row0 >> 14;
            const int chunk = (row0 >> 6) & 255;
            const int tc = row0 & 63;
#pragma unroll
            for (int n = 0; n < 4; ++n) {
                const int col = c00 - 512 + n * 16;
                const int h = col >> 7, v = col & 127;
                bf16* dst = VF + (size_t)((bi * 4 + h) * 256 + chunk) * 8192
                               + voff(v, tc);
                ushort4 pk;
                pk.x = f2bu(acc[m][n][0]); pk.y = f2bu(acc[m][n][1]);
                pk.z = f2bu(acc[m][n][2]); pk.w = f2bu(acc[m][n][3]);
                *(ushort4*)dst = pk;
            }
        }
    } else {                   // G, silu
#pragma unroll
        for (int m = 0; m < 4; ++m)
#pragma unroll
            for (int n = 0; n < 4; ++n)
#pragma unroll
                for (int r = 0; r < 4; ++r) {
                    const float v = acc[m][n][r];
                    const float sil = v * fast_rcp(1.f + __expf(-v));
                    stf(&GOb[(size_t)(r00 + m * 16 + r) * 512 + (c00 - 1024) + n * 16],
                        sil);
                }
    }
}

// ---------------------------------------------------------------------------
// Output GEMM: C[M,512] = OL(f16)[M,512] @ Wo via Wf pans 12..15.
// Same A-via-LDS + B-from-global core. fp32 out. Default block order.
// ---------------------------------------------------------------------------
__global__ __launch_bounds__(256) void gemm_bt_k(
    const f16* __restrict__ A, const f16* __restrict__ Wf,
    float* __restrict__ C)
{
    __shared__ __align__(16) f16 As[128][64];
    const int bm = blockIdx.x * 128;
    const int bn = blockIdx.y * 128;
    const int pan = 12 + (bn >> 7);
    const int tid = threadIdx.x;
    const int lane = tid & 63;
    const int wid = tid >> 6;
    const int wr = wid >> 1, wc = wid & 1;
    const int al = lane & 15;
    const int kg = lane >> 4;
    const int al7 = al & 7;

    f32x4 acc[4][4];
#pragma unroll
    for (int m = 0; m < 4; ++m)
#pragma unroll
        for (int n = 0; n < 4; ++n)
#pragma unroll
            for (int r = 0; r < 4; ++r) acc[m][n][r] = 0.f;

    const int srow = wid * 32 + (lane >> 3);
    const int sswz = ((lane & 7) ^ (lane >> 3)) << 3;
    const f16* ap = A + (size_t)(bm + srow) * 512 + sswz;
    const f16* wfb = Wf + (size_t)lane * 8;

    for (int k0 = 0; k0 < 512; k0 += 64) {
        if (k0) __syncthreads();
#pragma unroll
        for (int i = 0; i < 4; ++i)
            gl_lds16(ap + (size_t)i * 8 * 512 + k0, &As[wid * 32 + i * 8][0]);
        half8 bfr[2][4];
        const int kstep = k0 >> 6;
#pragma unroll
        for (int ks = 0; ks < 2; ++ks)
#pragma unroll
            for (int n = 0; n < 4; ++n)
                bfr[ks][n] = *(const half8*)&wfb[
                    (size_t)(((pan * 8 + kstep) * 2 + ks) * 8 + wc * 4 + n) * 512];
        __syncthreads();
#pragma unroll
        for (int ks = 0; ks < 2; ++ks) {
            half8 af[4];
            const int sp = ((ks * 4 + kg) ^ al7) << 3;
#pragma unroll
            for (int m = 0; m < 4; ++m)
                af[m] = *(const half8*)&As[wr * 64 + m * 16 + al][sp];
#pragma unroll
            for (int m = 0; m < 4; ++m)
#pragma unroll
                for (int n = 0; n < 4; ++n)
                    acc[m][n] = mfma_h(af[m], bfr[ks][n], acc[m][n]);
        }
    }
    const int r0 = bm + wr * 64 + kg * 4;
    const int c0 = bn + wc * 64 + al;
#pragma unroll
    for (int m = 0; m < 4; ++m)
#pragma unroll
        for (int n = 0; n < 4; ++n)
#pragma unroll
            for (int r = 0; r < 4; ++r)
                C[(size_t)(r0 + m * 16 + r) * 512 + c0 + n * 16] = acc[m][n][r];
}

// ---------------------------------------------------------------------------
// gate: gk = log_sigmoid((xh @ Wgk1) @ Wgk2 + bgk2) / 16 -> bf16
// Block = 128 rows. Stage 1 (K=512, N=16) on f16 MFMA, Wgk1 in LDS [n][k].
// Stage 2: thread owns column c=tid; Wgk2 reads coalesced.
// ---------------------------------------------------------------------------
__global__ __launch_bounds__(256) void gate_mfma_k(
    const f16* __restrict__ xh, const float* __restrict__ Wgk1,
    const float* __restrict__ Wgk2, const float* __restrict__ bgk2,
    bf16* __restrict__ GK)
{
    __shared__ __align__(16) f16 As[128][40];
    __shared__ __align__(16) f16 w1s[16][520];   // Wgk1^T [n][k], padded
    __shared__ float tls[128][17];               // tl fp32
    const int bm = blockIdx.x * 128;
    const int tid = threadIdx.x;
    const int lane = tid & 63;
    const int wid = tid >> 6;
    const int al = lane & 15;
    const int kg = lane >> 4;
    const int kg8 = kg * 8;

    for (int e = tid; e < 8192; e += 256) {
        const int kk = e >> 4, n = e & 15;
        w1s[n][kk] = (f16)Wgk1[e];
    }

    f32x4 acc[2];
#pragma unroll
    for (int m = 0; m < 2; ++m)
#pragma unroll
        for (int r = 0; r < 4; ++r) acc[m][r] = 0.f;

    const int ar = tid >> 1;
    const int ac = (tid & 1) * 16;
    for (int k0 = 0; k0 < 512; k0 += 32) {
        {
            const f16* ap = xh + (size_t)(bm + ar) * 512 + k0 + ac;
            *(half8*)&As[ar][ac] = *(const half8*)ap;
            *(half8*)&As[ar][ac + 8] = *(const half8*)(ap + 8);
        }
        __syncthreads();
        const half8 bfr = *(const half8*)&w1s[al][k0 + kg8];
#pragma unroll
        for (int m = 0; m < 2; ++m) {
            const half8 af = *(const half8*)&As[wid * 32 + m * 16 + al][kg8];
            acc[m] = mfma_h(af, bfr, acc[m]);
        }
        __syncthreads();
    }
#pragma unroll
    for (int m = 0; m < 2; ++m)
#pragma unroll
        for (int r = 0; r < 4; ++r)
            tls[wid * 32 + m * 16 + kg * 4 + r][al] = acc[m][r];
    __syncthreads();

    float w2[16];
#pragma unroll
    for (int r = 0; r < 16; ++r) w2[r] = Wgk2[r * 256 + tid];
    const float bb = bgk2[tid];
    bf16* gout = GK + (size_t)bm * 256 + tid;
    for (int m = 0; m < 128; ++m) {
        float z = bb;
#pragma unroll
        for (int r = 0; r < 16; ++r) z = fmaf(tls[m][r], w2[r], z);
        const float ls = fminf(z, 0.f) - __logf(1.f + __expf(-fabsf(z)));
        stf(&gout[(size_t)m * 256], ls * (1.f / 16.f));
    }
}

// ---------------------------------------------------------------------------
// Per-chunk local state via MFMA: CS[blk][v*64+k] = S^T[v][k] (bf16)
//   = sum_t V[t][v] * (k_t[k] e^{d63[k]-g_t[k]}) ; DD[blk][k] = e^{d63[k]}.
// ---------------------------------------------------------------------------
__global__ __launch_bounds__(256) void chunk_state_k(
    const bf16* __restrict__ Km, const bf16* __restrict__ VF,
    const bf16* __restrict__ GKm, bf16* __restrict__ CS,
    float* __restrict__ DD)
{
    __shared__ __align__(16) short k2t[64][72];   // [k][t] bf16
    __shared__ float cpart[4][64];
    const int blk = blockIdx.x;
    const int chunk = blk & 255;
    const int bh = blk >> 8;
    const int bi = bh >> 2, h = bh & 3;
    const int rowbase = bi * 16384 + chunk * 64;
    const int tid = threadIdx.x;
    const int k = tid & 63, tg = tid >> 6;

    float g[16];
    {
        float run = 0.f;
#pragma unroll
        for (int j = 0; j < 16; ++j) {
            run += ldf(&GKm[(size_t)(rowbase + tg * 16 + j) * 256 + h * 64 + k]);
            g[j] = run;
        }
        cpart[tg][k] = run;
    }
    __syncthreads();
    float off = 0.f;
#pragma unroll
    for (int s = 0; s < 3; ++s) if (s < tg) off += cpart[s][k];
    const float tot = cpart[0][k] + cpart[1][k] + cpart[2][k] + cpart[3][k];
    if (tg == 0) DD[(size_t)blk * 64 + k] = __expf(tot);

    {
        short8 p0, p1;
#pragma unroll
        for (int j = 0; j < 16; ++j) {
            const float kv = ldf(&Km[(size_t)(rowbase + tg * 16 + j) * 256 + h * 64 + k]);
            const float w = kv * __expf(tot - (g[j] + off));   // decay <= 1
            if (j < 8) p0[j] = f2bs(w); else p1[j - 8] = f2bs(w);
        }
        *(short8*)&k2t[k][tg * 16] = p0;
        *(short8*)&k2t[k][tg * 16 + 8] = p1;
    }
    __syncthreads();

    const int lane = tid & 63, wid = tid >> 6;
    const int al = lane & 15, kg = lane >> 4, kg8 = kg * 8;
    const bf16* Vtb = VF + (size_t)blk * 8192;

    short8 xf[2][2];
#pragma unroll
    for (int m = 0; m < 2; ++m)
#pragma unroll
        for (int ks = 0; ks < 2; ++ks)
            xf[m][ks] = *(const short8*)&Vtb[(size_t)(((wid * 2 + m) * 2 + ks) * 64 + lane) * 8];
    short8 yf[2][4];
#pragma unroll
    for (int ks = 0; ks < 2; ++ks)
#pragma unroll
        for (int n = 0; n < 4; ++n)
            yf[ks][n] = *(const short8*)&k2t[n * 16 + al][ks * 32 + kg8];

    f32x4 acc[2][4];
#pragma unroll
    for (int m = 0; m < 2; ++m)
#pragma unroll
        for (int n = 0; n < 4; ++n)
#pragma unroll
            for (int r = 0; r < 4; ++r) acc[m][n][r] = 0.f;
#pragma unroll
    for (int ks = 0; ks < 2; ++ks)
#pragma unroll
        for (int m = 0; m < 2; ++m)
#pragma unroll
            for (int n = 0; n < 4; ++n)
                acc[m][n] = mfma_bf(xf[m][ks], yf[ks][n], acc[m][n]);

    bf16* out = CS + (size_t)blk * 8192;
#pragma unroll
    for (int m = 0; m < 2; ++m)
#pragma unroll
        for (int n = 0; n < 4; ++n)
#pragma unroll
            for (int r = 0; r < 4; ++r)
                stf(&out[(size_t)(wid * 32 + m * 16 + kg * 4 + r) * 64 + n * 16 + al],
                    acc[m][n][r]);
}

// ---------------------------------------------------------------------------
// Affine scan over chunks: H_{n+1}=D_n H_n+S_n. Reads S (bf16), accumulates
// fp32 in-register, writes H_n to Hf (bf16, fragment-major).
// ---------------------------------------------------------------------------
__global__ __launch_bounds__(256) void scan_k(
    const bf16* __restrict__ CS, const float* __restrict__ DD,
    bf16* __restrict__ HF)
{
    const int bh = blockIdx.x >> 5;
    const int slice = blockIdx.x & 31;
    const int tid = threadIdx.x;
    const int e = slice * 256 + tid;
    const int v = e >> 6, k = e & 63;
    float H = 0.f;
    const bf16* base = CS + (size_t)bh * 256 * 8192 + e;
    bf16* hbase = HF + (size_t)bh * 256 * 8192 + voff(v, k);
    const float* dbase = DD + (size_t)bh * 256 * 64 + k;
#pragma unroll 4
    for (int n = 0; n < 256; ++n) {
        const float s = ldf(&base[(size_t)n * 8192]);
        const float d = dbase[(size_t)n * 64];
        stf(&hbase[(size_t)n * 8192], H);
        H = fmaf(d, H, s);
    }
}

// ---------------------------------------------------------------------------
// Per-chunk output via MFMA + fused LayerNorm * precomputed silu(g).
// Writes OL as F16 bits into the GO buffer (consumed by gemm_bt_k as f16).
// ---------------------------------------------------------------------------
__global__ __launch_bounds__(256) void chunk_out_k(
    const bf16* __restrict__ Qm, const bf16* __restrict__ Km,
    const bf16* __restrict__ VF, const bf16* __restrict__ GKm,
    const bf16* __restrict__ HF, bf16* GO)
{
    __shared__ __align__(16) short qs[64][72];   // q*e^g   (bf16)
    __shared__ __align__(16) short ks[64][72];   // k*e^-g  (bf16)
    __shared__ __align__(16) short ab[64][72];   // causal A (bf16)
    __shared__ float cpart[4][64];

    const int blk = blockIdx.x;
    const int chunk = blk & 255;
    const int bh = blk >> 8;
    const int bi = bh >> 2, h = bh & 3;
    const int rowbase = bi * 16384 + chunk * 64;
    const int tid = threadIdx.x;
    const int k = tid & 63, tg = tid >> 6;

    float g[16];
    {
        float run = 0.f;
#pragma unroll
        for (int j = 0; j < 16; ++j) {
            run += ldf(&GKm[(size_t)(rowbase + tg * 16 + j) * 256 + h * 64 + k]);
            g[j] = run;
        }
        cpart[tg][k] = run;
    }
    __syncthreads();
    float off = 0.f;
#pragma unroll
    for (int s = 0; s < 3; ++s) if (s < tg) off += cpart[s][k];

#pragma unroll
    for (int j = 0; j < 16; ++j) {
        const int t = tg * 16 + j;
        const size_t idx = (size_t)(rowbase + t) * 256 + h * 64 + k;
        const float gc = g[j] + off;
        const float eg = __expf(gc);
        qs[t][k] = f2bs(ldf(&Qm[idx]) * eg);
        ks[t][k] = f2bs(ldf(&Km[idx]) * fast_rcp(eg));
    }
    __syncthreads();

    const int lane = tid & 63, wid = tid >> 6;
    const int al = lane & 15, kg = lane >> 4;
    const int w16 = wid * 16, kg8 = kg * 8;

    short8 xq[2];
    xq[0] = *(const short8*)&qs[w16 + al][kg8];
    xq[1] = *(const short8*)&qs[w16 + al][32 + kg8];

    f32x4 aacc[4];
#pragma unroll
    for (int n = 0; n < 4; ++n)
#pragma unroll
        for (int r = 0; r < 4; ++r) aacc[n][r] = 0.f;
#pragma unroll
    for (int ksb = 0; ksb < 2; ++ksb)
#pragma unroll
        for (int n = 0; n < 4; ++n) {
            const short8 y = *(const short8*)&ks[n * 16 + al][ksb * 32 + kg8];
            aacc[n] = mfma_bf(xq[ksb], y, aacc[n]);
        }
#pragma unroll
    for (int n = 0; n < 4; ++n)
#pragma unroll
        for (int r = 0; r < 4; ++r) {
            const int tt = w16 + kg * 4 + r;
            const int ii = n * 16 + al;
            ab[tt][ii] = (ii <= tt) ? f2bs(aacc[n][r]) : (short)0;
        }
    short8 xa[2];
    xa[0] = *(const short8*)&ab[w16 + al][kg8];
    xa[1] = *(const short8*)&ab[w16 + al][32 + kg8];

    const bf16* Vtb = VF + (size_t)blk * 8192;
    const bf16* Hb = HF + (size_t)blk * 8192;
    f32x4 oacc[8];
#pragma unroll
    for (int n = 0; n < 8; ++n)
#pragma unroll
        for (int r = 0; r < 4; ++r) oacc[n][r] = 0.f;
#pragma unroll
    for (int n = 0; n < 8; ++n) {
        const size_t f0 = (size_t)((n * 2 + 0) * 64 + lane) * 8;
        const size_t f1 = (size_t)((n * 2 + 1) * 64 + lane) * 8;
        const short8 yv0 = *(const short8*)&Vtb[f0];
        const short8 yv1 = *(const short8*)&Vtb[f1];
        const short8 yh0 = *(const short8*)&Hb[f0];
        const short8 yh1 = *(const short8*)&Hb[f1];
        oacc[n] = mfma_bf(xa[0], yv0, oacc[n]);
        oacc[n] = mfma_bf(xa[1], yv1, oacc[n]);
        oacc[n] = mfma_bf(xq[0], yh0, oacc[n]);
        oacc[n] = mfma_bf(xq[1], yh1, oacc[n]);
    }

    float psum[4] = {0.f, 0.f, 0.f, 0.f}, psq[4] = {0.f, 0.f, 0.f, 0.f};
#pragma unroll
    for (int n = 0; n < 8; ++n)
#pragma unroll
        for (int r = 0; r < 4; ++r) {
            const float v = oacc[n][r];
            psum[r] += v; psq[r] = fmaf(v, v, psq[r]);
        }
#pragma unroll
    for (int offx = 1; offx < 16; offx <<= 1)
#pragma unroll
        for (int r = 0; r < 4; ++r) {
            psum[r] += __shfl_xor(psum[r], offx);
            psq[r] += __shfl_xor(psq[r], offx);
        }
#pragma unroll
    for (int r = 0; r < 4; ++r) {
        const float mu = psum[r] * (1.f / 128.f);
        const float var = psq[r] * (1.f / 128.f) - mu * mu;
        const float rstd = rsqrtf(fmaxf(var, 0.f) + 1e-5f);
        const int row = rowbase + w16 + kg * 4 + r;
        short* gop = (short*)(GO + (size_t)row * 512 + h * 128 + al);
#pragma unroll
        for (int n = 0; n < 8; ++n) {
            const bf16 gb = *(const bf16*)&gop[n * 16];
            const float sil = b2f(gb);                  // silu(g), precomputed
            gop[n * 16] = f2hs((oacc[n][r] - mu) * rstd * sil);  // OL as f16
        }
    }
}

__global__ __launch_bounds__(256) void zero_k(float* out, int n) {
    const int i = blockIdx.x * 256 + threadIdx.x;
    if (i < n) out[i] = 0.f;
}

// ---------------------------------------------------------------------------
static void run_all(const float* x, const float* Wq, const float* Wk,
                    const float* Wv, const float* Wg, const float* Wgk1,
                    const float* Wgk2, const float* bgk2, const float* Wo,
                    float* out, char* ws, hipStream_t stream)
{
    const int M = 32768;  // B*S
    auto aln = [](size_t v) { return (v + 255) & ~(size_t)255; };
    char* cur = ws;
    bf16* Qb = (bf16*)cur;  cur += aln((size_t)M * 256 * 2);
    bf16* Kb = (bf16*)cur;  cur += aln((size_t)M * 256 * 2);
    bf16* Vfb = (bf16*)cur; cur += aln((size_t)M * 512 * 2);   // fragment-major V
    bf16* GOb = (bf16*)cur; cur += aln((size_t)M * 512 * 2);   // silu(g) bf16, then OL f16
    bf16* Hfb = (bf16*)cur; cur += aln((size_t)2048 * 8192 * 2); // fragment-major H
    float* DDb = (float*)cur; cur += aln((size_t)2048 * 64 * 4);
    f16* Wfb = (f16*)cur;   cur += aln((size_t)2048 * 512 * 2);  // weights f16 frag-major
    bf16* GKb = (bf16*)cur; cur += aln((size_t)M * 256 * 2);
    bf16* CSb = (bf16*)cur;                                     // 32 MB (S, bf16)
    f16* xh = (f16*)CSb;    // aliases CS: dead until chunk_state_k writes it

    const dim3 blk(256);
    cvt_xh_k<<<dim3(8192), blk, 0, stream>>>(x, xh);
    cvt_wt_k<<<dim3(32), blk, 0, stream>>>(Wq, Wk, Wv, Wg, Wo, Wfb);
    proj_gemm_k<<<dim3(M / 128, 12), blk, 0, stream>>>(xh, Wfb, Qb, Kb, Vfb, GOb);
    gate_mfma_k<<<dim3(M / 128), blk, 0, stream>>>(xh, Wgk1, Wgk2, bgk2, GKb);
    chunk_state_k<<<dim3(2048), blk, 0, stream>>>(Kb, Vfb, GKb, CSb, DDb);
    scan_k<<<dim3(256), blk, 0, stream>>>(CSb, DDb, Hfb);
    chunk_out_k<<<dim3(2048), blk, 0, stream>>>(Qb, Kb, Vfb, GKb, Hfb, GOb);
    gemm_bt_k<<<dim3(M / 128, 4), blk, 0, stream>>>((const f16*)GOb, Wfb, out);
}

extern "C" void kernel_launch(void* const* d_in, const int* in_sizes, int n_in,
                              void* d_out, int out_size, void* d_ws, size_t ws_size,
                              hipStream_t stream)
{
    const float* x    = (const float*)d_in[0];
    const float* Wq   = (const float*)d_in[1];
    const float* Wk   = (const float*)d_in[2];
    const float* Wv   = (const float*)d_in[3];
    const float* Wg   = (const float*)d_in[4];
    const float* Wgk1 = (const float*)d_in[5];
    const float* Wgk2 = (const float*)d_in[6];
    const float* bgk2 = (const float*)d_in[7];
    const float* Wo   = (const float*)d_in[8];
    float* out = (float*)d_out;

    const size_t M = 32768;
    const size_t slack = 8192;
    // Q,K + Vf + GO + Hf + DD + Wf + GK(bf16) + CS(bf16) ~ 179 MB
    const size_t need = 2 * M * 256 * 2 + 2 * M * 512 * 2
                      + (size_t)2048 * 8192 * 2 + 2048 * 64 * 4
                      + (size_t)2048 * 512 * 2 + M * 256 * 2
                      + (size_t)2048 * 8192 * 2 + slack;

    if (ws_size >= need) {
        run_all(x, Wq, Wk, Wv, Wg, Wgk1, Wgk2, bgk2, Wo,
                out, (char*)d_ws, stream);
    } else {
        zero_k<<<dim3((out_size + 255) / 256), dim3(256), 0, stream>>>(out, out_size);
    }
}

// Round 12
// 342.139 us; speedup vs baseline: 3.9547x; 1.0337x over previous
//
#include <hip/hip_runtime.h>
#include <hip/hip_bf16.h>

// GLA forward for MI355X. Inputs fp32, OUTPUT fp32. Pipeline:
//  0) cvt_xh_k: x (fp32) -> xh (f16) once; xh aliases CS workspace.
//     cvt_wt_k: [Wq|Wk|Wv|Wg|Wo] fp32 [k][n] -> Wf f16 FRAGMENT-MAJOR:
//     flat(n,k) = (((pan*8+kstep)*2+ks)*8+nblk)*512 + (kg*16+al)*8 + e
//     -> per-wave B-fragment load = one contiguous 1KB transaction, L2-hot
//     (2MB total). B never goes through LDS.
//  1) proj_gemm_k: ONE GEMM M=32768 x N=1536 (pans 0..11), BK=64. A staged
//     via global_load_lds (16KB LDS, both-sides XOR swizzle); B fragments
//     straight from Wf. 1-D grid with PANEL-GROUPED XCD mapping:
//     f = 8j+xcd -> bm=(j/12)*8+xcd, bn=j%12. The 12 blocks sharing an
//     A-panel are dispatch-adjacent (ids 8 apart => same XCD by id%8) so
//     the panel is HBM-fetched once and L2-served 11x. (Round-11 x-fastest
//     order had them 256 slots apart -> A refetched ~4x, FETCH 130MB.)
//     Per-segment epilogue: Q(*1/8)->bf16, K->bf16, V->frag-major Vf,
//     G->silu->bf16.
//  2) gate_mfma_k: gk = log_sigmoid((xh@Wgk1)@Wgk2 + b)/16 -> bf16
//  3) chunk_state_k: per-(b,h,chunk=64) local state S^T[v][k] (bf16) + D
//  4) scan_k: affine scan over chunks -> chunk-start states H_n -> Hf
//     (bf16 FRAGMENT-MAJOR); fp32 accumulation in-register
//  5) chunk_out_k: o = q*e^B @ H + causal intra attention @ V (bf16 MFMA),
//     fused per-head LayerNorm * precomputed silu(g) -> OL (f16, same buffer)
//  6) gemm_bt_k: out = OL(f16) @ Wo (pans 12..15 of Wf, fp32 out), same core
//     and same panel-grouped mapping (1024 = 8 x 128, groups of 4).
// Fragment-major layout for a [v][t] (128x64) bf16 matrix consumed as MFMA
// operands: off(v,t) = frag*512 + lane*8 + elem. Same per-lane k permutation
// on both MFMA operands => contraction exact regardless of HW k-ordering.

typedef __hip_bfloat16 bf16;
typedef _Float16 f16;
typedef _Float16 half8 __attribute__((ext_vector_type(8)));
typedef float f32x4 __attribute__((ext_vector_type(4)));
typedef short short8 __attribute__((ext_vector_type(8)));

#define DEV static __device__ __forceinline__

DEV float b2f(bf16 v) { return __bfloat162float(v); }
DEV bf16 f2b(float v) { return __float2bfloat16(v); }
DEV float bits2f(unsigned int u16) {
    union { unsigned int u; float f; } c; c.u = u16 << 16; return c.f;
}
DEV short f2bs(float v) {
    union { bf16 h; short s; } u; u.h = __float2bfloat16(v); return u.s;
}
DEV unsigned short f2bu(float v) {
    union { bf16 h; unsigned short s; } u; u.h = __float2bfloat16(v); return u.s;
}
DEV short f2hs(float v) {                 // fp32 -> f16 bits
    union { f16 h; short s; } u; u.h = (f16)v; return u.s;
}
DEV float fast_rcp(float v) { return __builtin_amdgcn_rcpf(v); }

DEV float ldf(const float* p) { return *p; }
DEV float ldf(const bf16* p) { return b2f(*p); }
DEV void stf(float* p, float v) { *p = v; }
DEV void stf(bf16* p, float v) { *p = f2b(v); }

DEV float4 ld4(const float* p) { return *(const float4*)p; }
DEV float4 ld4(const bf16* p) {
    const uint2 r = *(const uint2*)p;
    return make_float4(bits2f(r.x & 0xffffu), bits2f(r.x >> 16),
                       bits2f(r.y & 0xffffu), bits2f(r.y >> 16));
}

DEV half8 ld8h(const float* p) {
    const float4 a = *(const float4*)p, b = *(const float4*)(p + 4);
    half8 h;
    h[0] = (f16)a.x; h[1] = (f16)a.y; h[2] = (f16)a.z; h[3] = (f16)a.w;
    h[4] = (f16)b.x; h[5] = (f16)b.y; h[6] = (f16)b.z; h[7] = (f16)b.w;
    return h;
}
DEV half8 ld8h(const f16* p) { return *(const half8*)p; }

DEV f32x4 mfma_bf(short8 a, short8 b, f32x4 c) {
    return __builtin_amdgcn_mfma_f32_16x16x32_bf16(a, b, c, 0, 0, 0);
}
DEV f32x4 mfma_h(half8 a, half8 b, f32x4 c) {
    return __builtin_amdgcn_mfma_f32_16x16x32_f16(a, b, c, 0, 0, 0);
}

// async global->LDS copy, 16B/lane; LDS dest wave-uniform base + lane*16.
DEV void gl_lds16(const f16* g, f16* l) {
    __builtin_amdgcn_global_load_lds(
        (const __attribute__((address_space(1))) void*)g,
        (__attribute__((address_space(3))) void*)l, 16, 0, 0);
}

// fragment-major offset for a 128x64 [v][t] operand matrix
DEV size_t voff(int v, int t) {
    return (size_t)(((((v >> 4) * 2 + (t >> 5)) * 4 + ((t >> 3) & 3)) * 16
                     + (v & 15)) * 8 + (t & 7));
}

// ---------------------------------------------------------------------------
// x (fp32) -> xh (f16), 8 elems/thread
// ---------------------------------------------------------------------------
__global__ __launch_bounds__(256) void cvt_xh_k(
    const float* __restrict__ x, f16* __restrict__ xh)
{
    const size_t i = ((size_t)blockIdx.x * 256 + threadIdx.x) * 8;
    *(half8*)&xh[i] = ld8h(&x[i]);
}

// ---------------------------------------------------------------------------
// Weights -> Wf f16 FRAGMENT-MAJOR (16 pans x 8 ksteps x 2 ks x 8 nblk x
// 64 lanes x 8 elems = 1M f16 = 2MB). Pan rows: [0,2)=Wq [2,4)=Wk
// [4,8)=Wv [8,12)=Wg [12,16)=Wo. LDS transpose per 64-n x 64-k tile.
// ---------------------------------------------------------------------------
__global__ __launch_bounds__(256) void cvt_wt_k(
    const float* __restrict__ Wq, const float* __restrict__ Wk,
    const float* __restrict__ Wv, const float* __restrict__ Wg,
    const float* __restrict__ Wo, f16* __restrict__ Wf)
{
    __shared__ float tile[64][65];
    const int nb = blockIdx.x * 64;     // global n base (0..2047, 64-aligned)
    const int tid = threadIdx.x;
    const float* src; int nloc, N;
    if (nb < 256)       { src = Wq; N = 256; nloc = nb; }
    else if (nb < 512)  { src = Wk; N = 256; nloc = nb - 256; }
    else if (nb < 1024) { src = Wv; N = 512; nloc = nb - 512; }
    else if (nb < 1536) { src = Wg; N = 512; nloc = nb - 1024; }
    else                { src = Wo; N = 512; nloc = nb - 1536; }
    for (int k0 = 0; k0 < 512; k0 += 64) {
        for (int e = tid; e < 4096; e += 256) {
            const int i = e >> 6, j = e & 63;           // i: k-local, j: n-local
            tile[i][j] = src[(size_t)(k0 + i) * N + nloc + j];
        }
        __syncthreads();
        const int kstep = k0 >> 6;
        for (int ow = tid; ow < 512; ow += 256) {
            const int j = ow >> 3;                      // n-local
            const int i8 = ow & 7;                      // k-octet: ks=i8>>2, kg=i8&3
            const int n = nb + j;
            const int pan = n >> 7, nblk = (n >> 4) & 7, al = n & 15;
            half8 hv;
#pragma unroll
            for (int e = 0; e < 8; ++e) hv[e] = (f16)tile[i8 * 8 + e][j];
            const size_t flat =
                ((size_t)(((pan * 8 + kstep) * 2 + (i8 >> 2)) * 8 + nblk)) * 512
                + (size_t)(((i8 & 3) * 16 + al)) * 8;
            *(half8*)&Wf[flat] = hv;
        }
        __syncthreads();
    }
}

// ---------------------------------------------------------------------------
// Combined projection GEMM: C_seg = xh @ W_seg. Tile 128x128, BK=64,
// 4 waves (2x2), 4x4 16x16 frags/wave. A staged via global_load_lds into
// 16KB LDS with both-sides XOR swizzle (src slot ^= row&7; read slot
// (ks*4+kg)^(al&7)). B fragments read straight from frag-major Wf (L2-hot,
// barrier-free). D: col=lane&15, row=4*(lane>>4)+reg (HW-verified).
// 1-D grid 3072, panel-grouped XCD mapping (see header).
// Segments by bn>>8: 0=Q(*0.125) 1=K 2,3=V(frag-major) 4,5=G(silu).
// ---------------------------------------------------------------------------
__global__ __launch_bounds__(256) void proj_gemm_k(
    const f16* __restrict__ A, const f16* __restrict__ Wf,
    bf16* __restrict__ Qb, bf16* __restrict__ Kb,
    bf16* __restrict__ VF, bf16* __restrict__ GOb)
{
    __shared__ __align__(16) f16 As[128][64];
    const int f = blockIdx.x;                 // 0..3071
    const int xcd = f & 7, j = f >> 3;        // j: 0..383
    const int bm = ((j / 12) * 8 + xcd) * 128;
    const int bn = (j % 12) * 128;
    const int pan = bn >> 7;
    const int tid = threadIdx.x;
    const int lane = tid & 63;
    const int wid = tid >> 6;
    const int wr = wid >> 1, wc = wid & 1;
    const int al = lane & 15;
    const int kg = lane >> 4;
    const int al7 = al & 7;

    f32x4 acc[4][4];
#pragma unroll
    for (int m = 0; m < 4; ++m)
#pragma unroll
        for (int n = 0; n < 4; ++n)
#pragma unroll
            for (int r = 0; r < 4; ++r) acc[m][n][r] = 0.f;

    // A staging: wave w covers rows w*32..w*32+31 (4 instrs x 8 rows);
    // lane -> row w*32+i*8+(lane>>3), slot (lane&7); src slot ^= row&7.
    const int srow = wid * 32 + (lane >> 3);
    const int sswz = ((lane & 7) ^ (lane >> 3)) << 3;   // f16 elements
    const f16* ap = A + (size_t)(bm + srow) * 512 + sswz;
    // B fragment base for this wave-column
    const f16* wfb = Wf + (size_t)lane * 8;

    for (int k0 = 0; k0 < 512; k0 += 64) {
        if (k0) __syncthreads();          // readers of previous tile done
#pragma unroll
        for (int i = 0; i < 4; ++i)
            gl_lds16(ap + (size_t)i * 8 * 512 + k0, &As[wid * 32 + i * 8][0]);
        // B fragments from global (overlap with A DMA; drained by barrier)
        half8 bfr[2][4];
        const int kstep = k0 >> 6;
#pragma unroll
        for (int ks = 0; ks < 2; ++ks)
#pragma unroll
            for (int n = 0; n < 4; ++n)
                bfr[ks][n] = *(const half8*)&wfb[
                    (size_t)(((pan * 8 + kstep) * 2 + ks) * 8 + wc * 4 + n) * 512];
        __syncthreads();                  // vmcnt drained before barrier
#pragma unroll
        for (int ks = 0; ks < 2; ++ks) {
            half8 af[4];
            const int sp = ((ks * 4 + kg) ^ al7) << 3;
#pragma unroll
            for (int m = 0; m < 4; ++m)
                af[m] = *(const half8*)&As[wr * 64 + m * 16 + al][sp];
#pragma unroll
            for (int m = 0; m < 4; ++m)
#pragma unroll
                for (int n = 0; n < 4; ++n)
                    acc[m][n] = mfma_h(af[m], bfr[ks][n], acc[m][n]);
        }
    }

    const int r00 = bm + wr * 64 + kg * 4;
    const int c00 = bn + wc * 64 + al;
    const int seg = bn >> 8;
    if (seg == 0) {            // Q, scale 1/8
#pragma unroll
        for (int m = 0; m < 4; ++m)
#pragma unroll
            for (int n = 0; n < 4; ++n)
#pragma unroll
                for (int r = 0; r < 4; ++r)
                    stf(&Qb[(size_t)(r00 + m * 16 + r) * 256 + c00 + n * 16],
                        acc[m][n][r] * 0.125f);
    } else if (seg == 1) {     // K
#pragma unroll
        for (int m = 0; m < 4; ++m)
#pragma unroll
            for (int n = 0; n < 4; ++n)
#pragma unroll
                for (int r = 0; r < 4; ++r)
                    stf(&Kb[(size_t)(r00 + m * 16 + r) * 256 + (c00 - 256) + n * 16],
                        acc[m][n][r]);
    } else if (seg <= 3) {     // V, fragment-major packed store
#pragma unroll
        for (int m = 0; m < 4; ++m) {
            const int row0 = r00 + m * 16;
            const int bi = row0 >> 14;
            const int chunk = (row0 >> 6) & 255;
            const int tc = row0 & 63;
#pragma unroll
            for (int n = 0; n < 4; ++n) {
                const int col = c00 - 512 + n * 16;
                const int h = col >> 7, v = col & 127;
                bf16* dst = VF + (size_t)((bi * 4 + h) * 256 + chunk) * 8192
                               + voff(v, tc);
                ushort4 pk;
                pk.x = f2bu(acc[m][n][0]); pk.y = f2bu(acc[m][n][1]);
                pk.z = f2bu(acc[m][n][2]); pk.w = f2bu(acc[m][n][3]);
                *(ushort4*)dst = pk;
            }
        }
    } else {                   // G, silu
#pragma unroll
        for (int m = 0; m < 4; ++m)
#pragma unroll
            for (int n = 0; n < 4; ++n)
#pragma unroll
                for (int r = 0; r < 4; ++r) {
                    const float v = acc[m][n][r];
                    const float sil = v * fast_rcp(1.f + __expf(-v));
                    stf(&GOb[(size_t)(r00 + m * 16 + r) * 512 + (c00 - 1024) + n * 16],
                        sil);
                }
    }
}

// ---------------------------------------------------------------------------
// Output GEMM: C[M,512] = OL(f16)[M,512] @ Wo via Wf pans 12..15.
// Same A-via-LDS + B-from-global core. fp32 out. 1-D grid 1024 with
// panel-grouped XCD mapping (groups of 4 bn per bm).
// ---------------------------------------------------------------------------
__global__ __launch_bounds__(256) void gemm_bt_k(
    const f16* __restrict__ A, const f16* __restrict__ Wf,
    float* __restrict__ C)
{
    __shared__ __align__(16) f16 As[128][64];
    const int f = blockIdx.x;                 // 0..1023
    const int xcd = f & 7, j = f >> 3;        // j: 0..127
    const int bm = ((j / 4) * 8 + xcd) * 128;
    const int bn = (j % 4) * 128;
    const int pan = 12 + (bn >> 7);
    const int tid = threadIdx.x;
    const int lane = tid & 63;
    const int wid = tid >> 6;
    const int wr = wid >> 1, wc = wid & 1;
    const int al = lane & 15;
    const int kg = lane >> 4;
    const int al7 = al & 7;

    f32x4 acc[4][4];
#pragma unroll
    for (int m = 0; m < 4; ++m)
#pragma unroll
        for (int n = 0; n < 4; ++n)
#pragma unroll
            for (int r = 0; r < 4; ++r) acc[m][n][r] = 0.f;

    const int srow = wid * 32 + (lane >> 3);
    const int sswz = ((lane & 7) ^ (lane >> 3)) << 3;
    const f16* ap = A + (size_t)(bm + srow) * 512 + sswz;
    const f16* wfb = Wf + (size_t)lane * 8;

    for (int k0 = 0; k0 < 512; k0 += 64) {
        if (k0) __syncthreads();
#pragma unroll
        for (int i = 0; i < 4; ++i)
            gl_lds16(ap + (size_t)i * 8 * 512 + k0, &As[wid * 32 + i * 8][0]);
        half8 bfr[2][4];
        const int kstep = k0 >> 6;
#pragma unroll
        for (int ks = 0; ks < 2; ++ks)
#pragma unroll
            for (int n = 0; n < 4; ++n)
                bfr[ks][n] = *(const half8*)&wfb[
                    (size_t)(((pan * 8 + kstep) * 2 + ks) * 8 + wc * 4 + n) * 512];
        __syncthreads();
#pragma unroll
        for (int ks = 0; ks < 2; ++ks) {
            half8 af[4];
            const int sp = ((ks * 4 + kg) ^ al7) << 3;
#pragma unroll
            for (int m = 0; m < 4; ++m)
                af[m] = *(const half8*)&As[wr * 64 + m * 16 + al][sp];
#pragma unroll
            for (int m = 0; m < 4; ++m)
#pragma unroll
                for (int n = 0; n < 4; ++n)
                    acc[m][n] = mfma_h(af[m], bfr[ks][n], acc[m][n]);
        }
    }
    const int r0 = bm + wr * 64 + kg * 4;
    const int c0 = bn + wc * 64 + al;
#pragma unroll
    for (int m = 0; m < 4; ++m)
#pragma unroll
        for (int n = 0; n < 4; ++n)
#pragma unroll
            for (int r = 0; r < 4; ++r)
                C[(size_t)(r0 + m * 16 + r) * 512 + c0 + n * 16] = acc[m][n][r];
}

// ---------------------------------------------------------------------------
// gate: gk = log_sigmoid((xh @ Wgk1) @ Wgk2 + bgk2) / 16 -> bf16
// Block = 128 rows. Stage 1 (K=512, N=16) on f16 MFMA, Wgk1 in LDS [n][k].
// Stage 2: thread owns column c=tid; Wgk2 reads coalesced.
// ---------------------------------------------------------------------------
__global__ __launch_bounds__(256) void gate_mfma_k(
    const f16* __restrict__ xh, const float* __restrict__ Wgk1,
    const float* __restrict__ Wgk2, const float* __restrict__ bgk2,
    bf16* __restrict__ GK)
{
    __shared__ __align__(16) f16 As[128][40];
    __shared__ __align__(16) f16 w1s[16][520];   // Wgk1^T [n][k], padded
    __shared__ float tls[128][17];               // tl fp32
    const int bm = blockIdx.x * 128;
    const int tid = threadIdx.x;
    const int lane = tid & 63;
    const int wid = tid >> 6;
    const int al = lane & 15;
    const int kg = lane >> 4;
    const int kg8 = kg * 8;

    for (int e = tid; e < 8192; e += 256) {
        const int kk = e >> 4, n = e & 15;
        w1s[n][kk] = (f16)Wgk1[e];
    }

    f32x4 acc[2];
#pragma unroll
    for (int m = 0; m < 2; ++m)
#pragma unroll
        for (int r = 0; r < 4; ++r) acc[m][r] = 0.f;

    const int ar = tid >> 1;
    const int ac = (tid & 1) * 16;
    for (int k0 = 0; k0 < 512; k0 += 32) {
        {
            const f16* ap = xh + (size_t)(bm + ar) * 512 + k0 + ac;
            *(half8*)&As[ar][ac] = *(const half8*)ap;
            *(half8*)&As[ar][ac + 8] = *(const half8*)(ap + 8);
        }
        __syncthreads();
        const half8 bfr = *(const half8*)&w1s[al][k0 + kg8];
#pragma unroll
        for (int m = 0; m < 2; ++m) {
            const half8 af = *(const half8*)&As[wid * 32 + m * 16 + al][kg8];
            acc[m] = mfma_h(af, bfr, acc[m]);
        }
        __syncthreads();
    }
#pragma unroll
    for (int m = 0; m < 2; ++m)
#pragma unroll
        for (int r = 0; r < 4; ++r)
            tls[wid * 32 + m * 16 + kg * 4 + r][al] = acc[m][r];
    __syncthreads();

    float w2[16];
#pragma unroll
    for (int r = 0; r < 16; ++r) w2[r] = Wgk2[r * 256 + tid];
    const float bb = bgk2[tid];
    bf16* gout = GK + (size_t)bm * 256 + tid;
    for (int m = 0; m < 128; ++m) {
        float z = bb;
#pragma unroll
        for (int r = 0; r < 16; ++r) z = fmaf(tls[m][r], w2[r], z);
        const float ls = fminf(z, 0.f) - __logf(1.f + __expf(-fabsf(z)));
        stf(&gout[(size_t)m * 256], ls * (1.f / 16.f));
    }
}

// ---------------------------------------------------------------------------
// Per-chunk local state via MFMA: CS[blk][v*64+k] = S^T[v][k] (bf16)
//   = sum_t V[t][v] * (k_t[k] e^{d63[k]-g_t[k]}) ; DD[blk][k] = e^{d63[k]}.
// ---------------------------------------------------------------------------
__global__ __launch_bounds__(256) void chunk_state_k(
    const bf16* __restrict__ Km, const bf16* __restrict__ VF,
    const bf16* __restrict__ GKm, bf16* __restrict__ CS,
    float* __restrict__ DD)
{
    __shared__ __align__(16) short k2t[64][72];   // [k][t] bf16
    __shared__ float cpart[4][64];
    const int blk = blockIdx.x;
    const int chunk = blk & 255;
    const int bh = blk >> 8;
    const int bi = bh >> 2, h = bh & 3;
    const int rowbase = bi * 16384 + chunk * 64;
    const int tid = threadIdx.x;
    const int k = tid & 63, tg = tid >> 6;

    float g[16];
    {
        float run = 0.f;
#pragma unroll
        for (int j = 0; j < 16; ++j) {
            run += ldf(&GKm[(size_t)(rowbase + tg * 16 + j) * 256 + h * 64 + k]);
            g[j] = run;
        }
        cpart[tg][k] = run;
    }
    __syncthreads();
    float off = 0.f;
#pragma unroll
    for (int s = 0; s < 3; ++s) if (s < tg) off += cpart[s][k];
    const float tot = cpart[0][k] + cpart[1][k] + cpart[2][k] + cpart[3][k];
    if (tg == 0) DD[(size_t)blk * 64 + k] = __expf(tot);

    {
        short8 p0, p1;
#pragma unroll
        for (int j = 0; j < 16; ++j) {
            const float kv = ldf(&Km[(size_t)(rowbase + tg * 16 + j) * 256 + h * 64 + k]);
            const float w = kv * __expf(tot - (g[j] + off));   // decay <= 1
            if (j < 8) p0[j] = f2bs(w); else p1[j - 8] = f2bs(w);
        }
        *(short8*)&k2t[k][tg * 16] = p0;
        *(short8*)&k2t[k][tg * 16 + 8] = p1;
    }
    __syncthreads();

    const int lane = tid & 63, wid = tid >> 6;
    const int al = lane & 15, kg = lane >> 4, kg8 = kg * 8;
    const bf16* Vtb = VF + (size_t)blk * 8192;

    short8 xf[2][2];
#pragma unroll
    for (int m = 0; m < 2; ++m)
#pragma unroll
        for (int ks = 0; ks < 2; ++ks)
            xf[m][ks] = *(const short8*)&Vtb[(size_t)(((wid * 2 + m) * 2 + ks) * 64 + lane) * 8];
    short8 yf[2][4];
#pragma unroll
    for (int ks = 0; ks < 2; ++ks)
#pragma unroll
        for (int n = 0; n < 4; ++n)
            yf[ks][n] = *(const short8*)&k2t[n * 16 + al][ks * 32 + kg8];

    f32x4 acc[2][4];
#pragma unroll
    for (int m = 0; m < 2; ++m)
#pragma unroll
        for (int n = 0; n < 4; ++n)
#pragma unroll
            for (int r = 0; r < 4; ++r) acc[m][n][r] = 0.f;
#pragma unroll
    for (int ks = 0; ks < 2; ++ks)
#pragma unroll
        for (int m = 0; m < 2; ++m)
#pragma unroll
            for (int n = 0; n < 4; ++n)
                acc[m][n] = mfma_bf(xf[m][ks], yf[ks][n], acc[m][n]);

    bf16* out = CS + (size_t)blk * 8192;
#pragma unroll
    for (int m = 0; m < 2; ++m)
#pragma unroll
        for (int n = 0; n < 4; ++n)
#pragma unroll
            for (int r = 0; r < 4; ++r)
                stf(&out[(size_t)(wid * 32 + m * 16 + kg * 4 + r) * 64 + n * 16 + al],
                    acc[m][n][r]);
}

// ---------------------------------------------------------------------------
// Affine scan over chunks: H_{n+1}=D_n H_n+S_n. Reads S (bf16), accumulates
// fp32 in-register, writes H_n to Hf (bf16, fragment-major).
// ---------------------------------------------------------------------------
__global__ __launch_bounds__(256) void scan_k(
    const bf16* __restrict__ CS, const float* __restrict__ DD,
    bf16* __restrict__ HF)
{
    const int bh = blockIdx.x >> 5;
    const int slice = blockIdx.x & 31;
    const int tid = threadIdx.x;
    const int e = slice * 256 + tid;
    const int v = e >> 6, k = e & 63;
    float H = 0.f;
    const bf16* base = CS + (size_t)bh * 256 * 8192 + e;
    bf16* hbase = HF + (size_t)bh * 256 * 8192 + voff(v, k);
    const float* dbase = DD + (size_t)bh * 256 * 64 + k;
#pragma unroll 4
    for (int n = 0; n < 256; ++n) {
        const float s = ldf(&base[(size_t)n * 8192]);
        const float d = dbase[(size_t)n * 64];
        stf(&hbase[(size_t)n * 8192], H);
        H = fmaf(d, H, s);
    }
}

// ---------------------------------------------------------------------------
// Per-chunk output via MFMA + fused LayerNorm * precomputed silu(g).
// Writes OL as F16 bits into the GO buffer (consumed by gemm_bt_k as f16).
// ---------------------------------------------------------------------------
__global__ __launch_bounds__(256) void chunk_out_k(
    const bf16* __restrict__ Qm, const bf16* __restrict__ Km,
    const bf16* __restrict__ VF, const bf16* __restrict__ GKm,
    const bf16* __restrict__ HF, bf16* GO)
{
    __shared__ __align__(16) short qs[64][72];   // q*e^g   (bf16)
    __shared__ __align__(16) short ks[64][72];   // k*e^-g  (bf16)
    __shared__ __align__(16) short ab[64][72];   // causal A (bf16)
    __shared__ float cpart[4][64];

    const int blk = blockIdx.x;
    const int chunk = blk & 255;
    const int bh = blk >> 8;
    const int bi = bh >> 2, h = bh & 3;
    const int rowbase = bi * 16384 + chunk * 64;
    const int tid = threadIdx.x;
    const int k = tid & 63, tg = tid >> 6;

    float g[16];
    {
        float run = 0.f;
#pragma unroll
        for (int j = 0; j < 16; ++j) {
            run += ldf(&GKm[(size_t)(rowbase + tg * 16 + j) * 256 + h * 64 + k]);
            g[j] = run;
        }
        cpart[tg][k] = run;
    }
    __syncthreads();
    float off = 0.f;
#pragma unroll
    for (int s = 0; s < 3; ++s) if (s < tg) off += cpart[s][k];

#pragma unroll
    for (int j = 0; j < 16; ++j) {
        const int t = tg * 16 + j;
        const size_t idx = (size_t)(rowbase + t) * 256 + h * 64 + k;
        const float gc = g[j] + off;
        const float eg = __expf(gc);
        qs[t][k] = f2bs(ldf(&Qm[idx]) * eg);
        ks[t][k] = f2bs(ldf(&Km[idx]) * fast_rcp(eg));
    }
    __syncthreads();

    const int lane = tid & 63, wid = tid >> 6;
    const int al = lane & 15, kg = lane >> 4;
    const int w16 = wid * 16, kg8 = kg * 8;

    short8 xq[2];
    xq[0] = *(const short8*)&qs[w16 + al][kg8];
    xq[1] = *(const short8*)&qs[w16 + al][32 + kg8];

    f32x4 aacc[4];
#pragma unroll
    for (int n = 0; n < 4; ++n)
#pragma unroll
        for (int r = 0; r < 4; ++r) aacc[n][r] = 0.f;
#pragma unroll
    for (int ksb = 0; ksb < 2; ++ksb)
#pragma unroll
        for (int n = 0; n < 4; ++n) {
            const short8 y = *(const short8*)&ks[n * 16 + al][ksb * 32 + kg8];
            aacc[n] = mfma_bf(xq[ksb], y, aacc[n]);
        }
#pragma unroll
    for (int n = 0; n < 4; ++n)
#pragma unroll
        for (int r = 0; r < 4; ++r) {
            const int tt = w16 + kg * 4 + r;
            const int ii = n * 16 + al;
            ab[tt][ii] = (ii <= tt) ? f2bs(aacc[n][r]) : (short)0;
        }
    short8 xa[2];
    xa[0] = *(const short8*)&ab[w16 + al][kg8];
    xa[1] = *(const short8*)&ab[w16 + al][32 + kg8];

    const bf16* Vtb = VF + (size_t)blk * 8192;
    const bf16* Hb = HF + (size_t)blk * 8192;
    f32x4 oacc[8];
#pragma unroll
    for (int n = 0; n < 8; ++n)
#pragma unroll
        for (int r = 0; r < 4; ++r) oacc[n][r] = 0.f;
#pragma unroll
    for (int n = 0; n < 8; ++n) {
        const size_t f0 = (size_t)((n * 2 + 0) * 64 + lane) * 8;
        const size_t f1 = (size_t)((n * 2 + 1) * 64 + lane) * 8;
        const short8 yv0 = *(const short8*)&Vtb[f0];
        const short8 yv1 = *(const short8*)&Vtb[f1];
        const short8 yh0 = *(const short8*)&Hb[f0];
        const short8 yh1 = *(const short8*)&Hb[f1];
        oacc[n] = mfma_bf(xa[0], yv0, oacc[n]);
        oacc[n] = mfma_bf(xa[1], yv1, oacc[n]);
        oacc[n] = mfma_bf(xq[0], yh0, oacc[n]);
        oacc[n] = mfma_bf(xq[1], yh1, oacc[n]);
    }

    float psum[4] = {0.f, 0.f, 0.f, 0.f}, psq[4] = {0.f, 0.f, 0.f, 0.f};
#pragma unroll
    for (int n = 0; n < 8; ++n)
#pragma unroll
        for (int r = 0; r < 4; ++r) {
            const float v = oacc[n][r];
            psum[r] += v; psq[r] = fmaf(v, v, psq[r]);
        }
#pragma unroll
    for (int offx = 1; offx < 16; offx <<= 1)
#pragma unroll
        for (int r = 0; r < 4; ++r) {
            psum[r] += __shfl_xor(psum[r], offx);
            psq[r] += __shfl_xor(psq[r], offx);
        }
#pragma unroll
    for (int r = 0; r < 4; ++r) {
        const float mu = psum[r] * (1.f / 128.f);
        const float var = psq[r] * (1.f / 128.f) - mu * mu;
        const float rstd = rsqrtf(fmaxf(var, 0.f) + 1e-5f);
        const int row = rowbase + w16 + kg * 4 + r;
        short* gop = (short*)(GO + (size_t)row * 512 + h * 128 + al);
#pragma unroll
        for (int n = 0; n < 8; ++n) {
            const bf16 gb = *(const bf16*)&gop[n * 16];
            const float sil = b2f(gb);                  // silu(g), precomputed
            gop[n * 16] = f2hs((oacc[n][r] - mu) * rstd * sil);  // OL as f16
        }
    }
}

__global__ __launch_bounds__(256) void zero_k(float* out, int n) {
    const int i = blockIdx.x * 256 + threadIdx.x;
    if (i < n) out[i] = 0.f;
}

// ---------------------------------------------------------------------------
static void run_all(const float* x, const float* Wq, const float* Wk,
                    const float* Wv, const float* Wg, const float* Wgk1,
                    const float* Wgk2, const float* bgk2, const float* Wo,
                    float* out, char* ws, hipStream_t stream)
{
    const int M = 32768;  // B*S
    auto aln = [](size_t v) { return (v + 255) & ~(size_t)255; };
    char* cur = ws;
    bf16* Qb = (bf16*)cur;  cur += aln((size_t)M * 256 * 2);
    bf16* Kb = (bf16*)cur;  cur += aln((size_t)M * 256 * 2);
    bf16* Vfb = (bf16*)cur; cur += aln((size_t)M * 512 * 2);   // fragment-major V
    bf16* GOb = (bf16*)cur; cur += aln((size_t)M * 512 * 2);   // silu(g) bf16, then OL f16
    bf16* Hfb = (bf16*)cur; cur += aln((size_t)2048 * 8192 * 2); // fragment-major H
    float* DDb = (float*)cur; cur += aln((size_t)2048 * 64 * 4);
    f16* Wfb = (f16*)cur;   cur += aln((size_t)2048 * 512 * 2);  // weights f16 frag-major
    bf16* GKb = (bf16*)cur; cur += aln((size_t)M * 256 * 2);
    bf16* CSb = (bf16*)cur;                                     // 32 MB (S, bf16)
    f16* xh = (f16*)CSb;    // aliases CS: dead until chunk_state_k writes it

    const dim3 blk(256);
    cvt_xh_k<<<dim3(8192), blk, 0, stream>>>(x, xh);
    cvt_wt_k<<<dim3(32), blk, 0, stream>>>(Wq, Wk, Wv, Wg, Wo, Wfb);
    proj_gemm_k<<<dim3(3072), blk, 0, stream>>>(xh, Wfb, Qb, Kb, Vfb, GOb);
    gate_mfma_k<<<dim3(M / 128), blk, 0, stream>>>(xh, Wgk1, Wgk2, bgk2, GKb);
    chunk_state_k<<<dim3(2048), blk, 0, stream>>>(Kb, Vfb, GKb, CSb, DDb);
    scan_k<<<dim3(256), blk, 0, stream>>>(CSb, DDb, Hfb);
    chunk_out_k<<<dim3(2048), blk, 0, stream>>>(Qb, Kb, Vfb, GKb, Hfb, GOb);
    gemm_bt_k<<<dim3(1024), blk, 0, stream>>>((const f16*)GOb, Wfb, out);
}

extern "C" void kernel_launch(void* const* d_in, const int* in_sizes, int n_in,
                              void* d_out, int out_size, void* d_ws, size_t ws_size,
                              hipStream_t stream)
{
    const float* x    = (const float*)d_in[0];
    const float* Wq   = (const float*)d_in[1];
    const float* Wk   = (const float*)d_in[2];
    const float* Wv   = (const float*)d_in[3];
    const float* Wg   = (const float*)d_in[4];
    const float* Wgk1 = (const float*)d_in[5];
    const float* Wgk2 = (const float*)d_in[6];
    const float* bgk2 = (const float*)d_in[7];
    const float* Wo   = (const float*)d_in[8];
    float* out = (float*)d_out;

    const size_t M = 32768;
    const size_t slack = 8192;
    // Q,K + Vf + GO + Hf + DD + Wf + GK(bf16) + CS(bf16) ~ 179 MB
    const size_t need = 2 * M * 256 * 2 + 2 * M * 512 * 2
                      + (size_t)2048 * 8192 * 2 + 2048 * 64 * 4
                      + (size_t)2048 * 512 * 2 + M * 256 * 2
                      + (size_t)2048 * 8192 * 2 + slack;

    if (ws_size >= need) {
        run_all(x, Wq, Wk, Wv, Wg, Wgk1, Wgk2, bgk2, Wo,
                out, (char*)d_ws, stream);
    } else {
        zero_k<<<dim3((out_size + 255) / 256), dim3(256), 0, stream>>>(out, out_size);
    }
}